// Round 1
// baseline (595.951 us; speedup 1.0000x reference)
//
#include <hip/hip_runtime.h>
#include <math.h>

// Problem constants (B=2, T=1024, C=1024, H=16, D=64; NG=64, BS=16, SQ=32)
constexpr int T_ = 1024;
constexpr int C_ = 1024;
constexpr int H_ = 16;
constexpr int D_ = 64;
#define SCALE 0.125f

__device__ __forceinline__ float elu1(float x) {  // elu(x)+1
    return x > 0.f ? x + 1.f : expf(x);
}

// ---------------------------------------------------------------------------
// K1: qkv = x @ W^T + b   (M=2048, N=3072, K=1024), scatter to q/k/v in
// (B,H,T,D) layout. 64x64 tile, 16x16 threads, 4x4 micro-tile, K-slab 16.
// ---------------------------------------------------------------------------
__global__ __launch_bounds__(256) void k1_qkv(
    const float* __restrict__ x, const float* __restrict__ w,
    const float* __restrict__ bias,
    float* __restrict__ qb, float* __restrict__ kb, float* __restrict__ vb)
{
    __shared__ float As[16][66];  // [k][m]
    __shared__ float Bs[16][66];  // [k][n]
    const int tid = threadIdx.x;
    const int m0 = blockIdx.y << 6;
    const int n0 = blockIdx.x << 6;
    const int ty = tid >> 4, tx = tid & 15;
    const int lr = tid >> 4, lk = tid & 15;
    float acc[4][4] = {};
    for (int k0 = 0; k0 < 1024; k0 += 16) {
#pragma unroll
        for (int i = 0; i < 4; i++) {
            As[lk][lr + 16 * i] = x[(size_t)(m0 + lr + 16 * i) * 1024 + k0 + lk];
            Bs[lk][lr + 16 * i] = w[(size_t)(n0 + lr + 16 * i) * 1024 + k0 + lk];
        }
        __syncthreads();
#pragma unroll
        for (int kk = 0; kk < 16; kk++) {
            float a[4], b[4];
#pragma unroll
            for (int i = 0; i < 4; i++) a[i] = As[kk][ty * 4 + i];
#pragma unroll
            for (int j = 0; j < 4; j++) b[j] = Bs[kk][tx * 4 + j];
#pragma unroll
            for (int i = 0; i < 4; i++)
#pragma unroll
                for (int j = 0; j < 4; j++) acc[i][j] += a[i] * b[j];
        }
        __syncthreads();
    }
    // epilogue: route columns to q/k/v, (B,H,T,D) layout
    const int which = n0 >> 10;           // uniform per block
    const int h = (n0 & 1023) >> 6;       // uniform per block
    float* dst = (which == 0) ? qb : (which == 1) ? kb : vb;
#pragma unroll
    for (int i = 0; i < 4; i++) {
        int m = m0 + ty * 4 + i;
        int bi = m >> 10, t = m & 1023;
        float4 o;
        o.x = acc[i][0] + bias[n0 + tx * 4 + 0];
        o.y = acc[i][1] + bias[n0 + tx * 4 + 1];
        o.z = acc[i][2] + bias[n0 + tx * 4 + 2];
        o.w = acc[i][3] + bias[n0 + tx * 4 + 3];
        *reinterpret_cast<float4*>(
            &dst[((size_t)(bi * H_ + h) * T_ + t) * D_ + tx * 4]) = o;
    }
}

// ---------------------------------------------------------------------------
// K2a: per-(bh,chunk) KV state: S_c[d][e] = sum_{t in chunk} Kp[t][d]*V[t][e]
// and svec_c[d] = sum Kp[t][d].  (Kp = elu(k*scale)+1)
// ---------------------------------------------------------------------------
__global__ __launch_bounds__(256) void k2a_chunkkv(
    const float* __restrict__ kb, const float* __restrict__ vb,
    float* __restrict__ Sg, float* __restrict__ svg)
{
    const int chunk = blockIdx.x, bh = blockIdx.y;
    const int t0 = chunk << 6;
    __shared__ float Ks[64][65];  // [t][d]  (Kp)
    __shared__ float Vs[64][65];  // [t][e]
    const int tid = threadIdx.x;
    const float* kp = kb + (size_t)bh * T_ * D_;
    const float* vp = vb + (size_t)bh * T_ * D_;
#pragma unroll
    for (int ii = 0; ii < 16; ii++) {
        int idx = tid + (ii << 8);
        int row = idx >> 6, col = idx & 63;
        Ks[row][col] = elu1(kp[(size_t)(t0 + row) * D_ + col] * SCALE);
        Vs[row][col] = vp[(size_t)(t0 + row) * D_ + col];
    }
    __syncthreads();
    const int tr = tid >> 4, tc = tid & 15;
    const int d0 = tr * 4, e0 = tc * 4;
    float acc[4][4] = {};
    for (int c = 0; c < 64; c++) {
        float a[4], b[4];
#pragma unroll
        for (int i = 0; i < 4; i++) a[i] = Ks[c][d0 + i];
#pragma unroll
        for (int j = 0; j < 4; j++) b[j] = Vs[c][e0 + j];
#pragma unroll
        for (int i = 0; i < 4; i++)
#pragma unroll
            for (int j = 0; j < 4; j++) acc[i][j] += a[i] * b[j];
    }
    float* so = Sg + ((size_t)bh * 16 + chunk) * 4096;
#pragma unroll
    for (int i = 0; i < 4; i++) {
        float4 o = {acc[i][0], acc[i][1], acc[i][2], acc[i][3]};
        *reinterpret_cast<float4*>(&so[(d0 + i) * 64 + e0]) = o;
    }
    if (tc == 0) {
#pragma unroll
        for (int i = 0; i < 4; i++) {
            float s = 0.f;
            for (int c = 0; c < 64; c++) s += Ks[c][d0 + i];
            svg[((size_t)bh * 16 + chunk) * 64 + d0 + i] = s;
        }
    }
}

// ---------------------------------------------------------------------------
// K2b: per-(bh,chunk) linear attention: exclusive-prefix state + intra-chunk
// causal part, then y_lin = numer/(denom+1e-4) and per-head layernorm over D.
// LDS buffers are reused (S->V, Qp->P) to stay under 64 KB.
// ---------------------------------------------------------------------------
__global__ __launch_bounds__(256) void k2b_lin(
    const float* __restrict__ qb, const float* __restrict__ kb,
    const float* __restrict__ vb,
    const float* __restrict__ Sg, const float* __restrict__ svg,
    const float* __restrict__ ang, const float* __restrict__ anb,
    float* __restrict__ ylin)
{
    const int chunk = blockIdx.x, bh = blockIdx.y;
    const int t0 = chunk << 6;
    __shared__ float bufA[64][65];  // S[d][e], then V[t][e]
    __shared__ float bufQ[64][65];  // QpT[d][r], then PT[c][r]
    __shared__ float bufK[64][65];  // KpT[d][c]
    __shared__ float svec[64];
    const int tid = threadIdx.x;
    const float* qp = qb + (size_t)bh * T_ * D_;
    const float* kp = kb + (size_t)bh * T_ * D_;
    const float* vp = vb + (size_t)bh * T_ * D_;
    // exclusive-prefix state
#pragma unroll
    for (int ii = 0; ii < 16; ii++) {
        int idx = tid + (ii << 8);
        int dd = idx >> 6, e = idx & 63;
        float s = 0.f;
        for (int c = 0; c < chunk; c++)
            s += Sg[(((size_t)bh * 16 + c) << 12) + (dd << 6) + e];
        bufA[dd][e] = s;
    }
    if (tid < 64) {
        float s = 0.f;
        for (int c = 0; c < chunk; c++)
            s += svg[(((size_t)bh * 16 + c) << 6) + tid];
        svec[tid] = s;
    }
    // Qp transposed into LDS
#pragma unroll
    for (int ii = 0; ii < 16; ii++) {
        int idx = tid + (ii << 8);
        int row = idx >> 6, col = idx & 63;
        bufQ[col][row] = elu1(qp[(size_t)(t0 + row) * D_ + col] * SCALE);
    }
    __syncthreads();
    const int tr = tid >> 4, tc = tid & 15;
    const int r0 = tr * 4, c0 = tc * 4;
    float N[4][4] = {};
    float pden[4];
    // inter: N += Qp @ S  ;  pden_inter partial
    for (int dd = 0; dd < 64; dd++) {
        float a[4], b[4];
#pragma unroll
        for (int i = 0; i < 4; i++) a[i] = bufQ[dd][r0 + i];
#pragma unroll
        for (int j = 0; j < 4; j++) b[j] = bufA[dd][c0 + j];
#pragma unroll
        for (int i = 0; i < 4; i++)
#pragma unroll
            for (int j = 0; j < 4; j++) N[i][j] += a[i] * b[j];
    }
#pragma unroll
    for (int i = 0; i < 4; i++) {
        float s = 0.f;
#pragma unroll
        for (int j = 0; j < 4; j++) s += bufQ[c0 + j][r0 + i] * svec[c0 + j];
        pden[i] = s;
    }
    __syncthreads();  // S reads done -> reuse bufA for V
#pragma unroll
    for (int ii = 0; ii < 16; ii++) {
        int idx = tid + (ii << 8);
        int row = idx >> 6, col = idx & 63;
        bufK[col][row] = elu1(kp[(size_t)(t0 + row) * D_ + col] * SCALE);
        bufA[row][col] = vp[(size_t)(t0 + row) * D_ + col];
    }
    __syncthreads();
    // intra scores: w[r][c] = Qp[r].Kp[c]
    float sc[4][4] = {};
    for (int dd = 0; dd < 64; dd++) {
        float a[4], b[4];
#pragma unroll
        for (int i = 0; i < 4; i++) a[i] = bufQ[dd][r0 + i];
#pragma unroll
        for (int j = 0; j < 4; j++) b[j] = bufK[dd][c0 + j];
#pragma unroll
        for (int i = 0; i < 4; i++)
#pragma unroll
            for (int j = 0; j < 4; j++) sc[i][j] += a[i] * b[j];
    }
    __syncthreads();  // all bufQ reads done -> reuse for PT
#pragma unroll
    for (int i = 0; i < 4; i++) {
        float s = 0.f;
#pragma unroll
        for (int j = 0; j < 4; j++) {
            float pv = ((c0 + j) <= (r0 + i)) ? sc[i][j] : 0.f;
            bufQ[c0 + j][r0 + i] = pv;
            s += pv;
        }
        pden[i] += s;
    }
#pragma unroll
    for (int i = 0; i < 4; i++) {
#pragma unroll
        for (int off = 1; off < 16; off <<= 1)
            pden[i] += __shfl_xor(pden[i], off);
    }
    __syncthreads();  // PT visible
    // PV: N += P @ V
    for (int c = 0; c < 64; c++) {
        float a[4], b[4];
#pragma unroll
        for (int i = 0; i < 4; i++) a[i] = bufQ[c][r0 + i];
#pragma unroll
        for (int j = 0; j < 4; j++) b[j] = bufA[c][c0 + j];
#pragma unroll
        for (int i = 0; i < 4; i++)
#pragma unroll
            for (int j = 0; j < 4; j++) N[i][j] += a[i] * b[j];
    }
    // y = N/(den+1e-4); layernorm over D with attn_norm_g/b
    float yv[4][4], s1[4], s2[4];
#pragma unroll
    for (int i = 0; i < 4; i++) {
        float inv = 1.f / (pden[i] + 1e-4f);
        s1[i] = 0.f; s2[i] = 0.f;
#pragma unroll
        for (int j = 0; j < 4; j++) {
            float t = N[i][j] * inv;
            yv[i][j] = t; s1[i] += t; s2[i] += t * t;
        }
    }
#pragma unroll
    for (int i = 0; i < 4; i++) {
#pragma unroll
        for (int off = 1; off < 16; off <<= 1) {
            s1[i] += __shfl_xor(s1[i], off);
            s2[i] += __shfl_xor(s2[i], off);
        }
    }
#pragma unroll
    for (int i = 0; i < 4; i++) {
        float mean = s1[i] * (1.f / 64.f);
        float var = s2[i] * (1.f / 64.f) - mean * mean;
        float rstd = rsqrtf(var + 1e-5f);
        float4 o;
        o.x = (yv[i][0] - mean) * rstd * ang[c0 + 0] + anb[c0 + 0];
        o.y = (yv[i][1] - mean) * rstd * ang[c0 + 1] + anb[c0 + 1];
        o.z = (yv[i][2] - mean) * rstd * ang[c0 + 2] + anb[c0 + 2];
        o.w = (yv[i][3] - mean) * rstd * ang[c0 + 3] + anb[c0 + 3];
        *reinterpret_cast<float4*>(
            &ylin[((size_t)bh * T_ + t0 + r0 + i) * D_ + c0]) = o;
    }
}

// ---------------------------------------------------------------------------
// K3: flash-style causal softmax attention, 64-row Q tile per block; combines
// with y_lin: y = a*y_sharp + (1-a)*y_lin, written to (B,T,C) layout.
// ---------------------------------------------------------------------------
__global__ __launch_bounds__(256) void k3_sharp(
    const float* __restrict__ qb, const float* __restrict__ kb,
    const float* __restrict__ vb,
    const float* __restrict__ ylin, const float* __restrict__ fg,
    float* __restrict__ ycomb)
{
    const int qi = blockIdx.x, bh = blockIdx.y;
    __shared__ float QsT[64][65];  // [d][r]
    __shared__ float KP[64][65];   // KT[d][c], then PT[c][r]
    __shared__ float Vs[64][64];   // [c][d]
    const int tid = threadIdx.x;
    const float* qp = qb + (size_t)bh * T_ * D_;
    const float* kp = kb + (size_t)bh * T_ * D_;
    const float* vp = vb + (size_t)bh * T_ * D_;
#pragma unroll
    for (int ii = 0; ii < 16; ii++) {
        int idx = tid + (ii << 8);
        int row = idx >> 6, col = idx & 63;
        QsT[col][row] = qp[(size_t)((qi << 6) + row) * D_ + col];
    }
    const int tr = tid >> 4, tc = tid & 15;
    const int r0 = tr * 4, c0 = tc * 4;
    float O[4][4] = {};
    float m_run[4], l_run[4];
#pragma unroll
    for (int i = 0; i < 4; i++) { m_run[i] = -INFINITY; l_run[i] = 0.f; }
    for (int ki = 0; ki <= qi; ki++) {
        __syncthreads();  // prev-iter PV reads of KP/Vs done
#pragma unroll
        for (int ii = 0; ii < 16; ii++) {
            int idx = tid + (ii << 8);
            int row = idx >> 6, col = idx & 63;
            KP[col][row] = kp[(size_t)((ki << 6) + row) * D_ + col];
            Vs[row][col] = vp[(size_t)((ki << 6) + row) * D_ + col];
        }
        __syncthreads();
        float sc[4][4] = {};
        for (int dd = 0; dd < 64; dd++) {
            float a[4], b[4];
#pragma unroll
            for (int i = 0; i < 4; i++) a[i] = QsT[dd][r0 + i];
#pragma unroll
            for (int j = 0; j < 4; j++) b[j] = KP[dd][c0 + j];
#pragma unroll
            for (int i = 0; i < 4; i++)
#pragma unroll
                for (int j = 0; j < 4; j++) sc[i][j] += a[i] * b[j];
        }
        const bool diag = (ki == qi);
        float mloc[4];
#pragma unroll
        for (int i = 0; i < 4; i++) {
            mloc[i] = -INFINITY;
#pragma unroll
            for (int j = 0; j < 4; j++) {
                float s = sc[i][j] * SCALE;
                if (diag && (c0 + j) > (r0 + i)) s = -INFINITY;
                sc[i][j] = s;
                mloc[i] = fmaxf(mloc[i], s);
            }
        }
#pragma unroll
        for (int i = 0; i < 4; i++) {
#pragma unroll
            for (int off = 1; off < 16; off <<= 1)
                mloc[i] = fmaxf(mloc[i], __shfl_xor(mloc[i], off));
        }
        float corr[4];
#pragma unroll
        for (int i = 0; i < 4; i++) {
            float mn = fmaxf(m_run[i], mloc[i]);  // finite after first tile
            corr[i] = expf(m_run[i] - mn);
            m_run[i] = mn;
        }
        __syncthreads();  // KP (K^T) score reads done -> reuse for PT
        float rs[4];
#pragma unroll
        for (int i = 0; i < 4; i++) {
            float s = 0.f;
#pragma unroll
            for (int j = 0; j < 4; j++) {
                float pv = expf(sc[i][j] - m_run[i]);  // masked -> exp(-inf)=0
                KP[c0 + j][r0 + i] = pv;
                s += pv;
            }
            rs[i] = s;
        }
#pragma unroll
        for (int i = 0; i < 4; i++) {
#pragma unroll
            for (int off = 1; off < 16; off <<= 1)
                rs[i] += __shfl_xor(rs[i], off);
            l_run[i] = l_run[i] * corr[i] + rs[i];
#pragma unroll
            for (int j = 0; j < 4; j++) O[i][j] *= corr[i];
        }
        __syncthreads();  // PT visible
        for (int c = 0; c < 64; c++) {
            float a[4], b[4];
#pragma unroll
            for (int i = 0; i < 4; i++) a[i] = KP[c][r0 + i];
#pragma unroll
            for (int j = 0; j < 4; j++) b[j] = Vs[c][c0 + j];
#pragma unroll
            for (int i = 0; i < 4; i++)
#pragma unroll
                for (int j = 0; j < 4; j++) O[i][j] += a[i] * b[j];
        }
    }
    const float al = 1.f / (1.f + expf(-fg[0]));
    const int bi = bh >> 4, h = bh & 15;
#pragma unroll
    for (int i = 0; i < 4; i++) {
        int t = (qi << 6) + r0 + i;
        float inv = 1.f / l_run[i];
        const float4 yl = *reinterpret_cast<const float4*>(
            &ylin[((size_t)bh * T_ + t) * D_ + c0]);
        float4 o;
        o.x = al * (O[i][0] * inv) + (1.f - al) * yl.x;
        o.y = al * (O[i][1] * inv) + (1.f - al) * yl.y;
        o.z = al * (O[i][2] * inv) + (1.f - al) * yl.z;
        o.w = al * (O[i][3] * inv) + (1.f - al) * yl.w;
        *reinterpret_cast<float4*>(
            &ycomb[((size_t)(bi * T_ + t)) * C_ + (h << 6) + c0]) = o;
    }
}

// ---------------------------------------------------------------------------
// K4: out-LN -> pre-LN -> block-diag mix (reversed) + 32x32 bilinear + bias.
// One block (256 thr) per token; each thread owns 4 consecutive channels.
// ---------------------------------------------------------------------------
__global__ __launch_bounds__(256) void k4_proj(
    const float* __restrict__ ycomb,
    const float* __restrict__ og, const float* __restrict__ ob,
    const float* __restrict__ pg, const float* __restrict__ pb,
    const float* __restrict__ bw, const float* __restrict__ wrow,
    const float* __restrict__ wcol, const float* __restrict__ palpha,
    const float* __restrict__ pbias, float* __restrict__ out)
{
    const int tok = blockIdx.x;
    __shared__ float xb[1024];    // xn (after both LNs)
    __shared__ float ymix[1024];
    __shared__ float zs[1024];    // z1
    __shared__ float red[8];
    const int tid = threadIdx.x;
    const int c0 = tid << 2;
    const float* yrow = ycomb + ((size_t)tok << 10);
    float4 v4 = *reinterpret_cast<const float4*>(yrow + c0);
    float v[4] = {v4.x, v4.y, v4.z, v4.w};
    // --- LN1 (out_norm) ---
    float s1 = v[0] + v[1] + v[2] + v[3];
    float s2 = v[0]*v[0] + v[1]*v[1] + v[2]*v[2] + v[3]*v[3];
#pragma unroll
    for (int off = 1; off < 64; off <<= 1) {
        s1 += __shfl_xor(s1, off); s2 += __shfl_xor(s2, off);
    }
    if ((tid & 63) == 0) { red[(tid >> 6) * 2] = s1; red[(tid >> 6) * 2 + 1] = s2; }
    __syncthreads();
    s1 = red[0] + red[2] + red[4] + red[6];
    s2 = red[1] + red[3] + red[5] + red[7];
    __syncthreads();
    {
        float mean = s1 * (1.f / 1024.f);
        float var = s2 * (1.f / 1024.f) - mean * mean;
        float rstd = rsqrtf(var + 1e-5f);
#pragma unroll
        for (int q = 0; q < 4; q++)
            v[q] = (v[q] - mean) * rstd * og[c0 + q] + ob[c0 + q];
    }
    // --- LN2 (proj_pre) ---
    s1 = v[0] + v[1] + v[2] + v[3];
    s2 = v[0]*v[0] + v[1]*v[1] + v[2]*v[2] + v[3]*v[3];
#pragma unroll
    for (int off = 1; off < 64; off <<= 1) {
        s1 += __shfl_xor(s1, off); s2 += __shfl_xor(s2, off);
    }
    if ((tid & 63) == 0) { red[(tid >> 6) * 2] = s1; red[(tid >> 6) * 2 + 1] = s2; }
    __syncthreads();
    s1 = red[0] + red[2] + red[4] + red[6];
    s2 = red[1] + red[3] + red[5] + red[7];
    __syncthreads();
    {
        float mean = s1 * (1.f / 1024.f);
        float var = s2 * (1.f / 1024.f) - mean * mean;
        float rstd = rsqrtf(var + 1e-5f);
#pragma unroll
        for (int q = 0; q < 4; q++)
            xb[c0 + q] = (v[q] - mean) * rstd * pg[c0 + q] + pb[c0 + q];
    }
    __syncthreads();
    // --- block-diag mix: ymix[g*16+jj] = sum_i xn[g*16+i]*bw[g,i,jj] ---
    {
        int g = tid >> 2;
        int jb = (tid & 3) << 2;
        float acc[4] = {0.f, 0.f, 0.f, 0.f};
        const float* xg = &xb[g << 4];
        const float* bwg = &bw[g << 8];
        for (int i = 0; i < 16; i++) {
            float xv = xg[i];
#pragma unroll
            for (int q = 0; q < 4; q++) acc[q] += xv * bwg[i * 16 + jb + q];
        }
#pragma unroll
        for (int q = 0; q < 4; q++) ymix[c0 + q] = acc[q];
    }
    // --- z1[i][cc] = sum_j xn[i*32+j]*wcol[j][cc] ---
    {
        int i_ = tid >> 3;
        int ccb = (tid << 2) & 31;
        float acc[4] = {0.f, 0.f, 0.f, 0.f};
        const float* xg = &xb[i_ << 5];
        for (int j = 0; j < 32; j++) {
            float xv = xg[j];
#pragma unroll
            for (int q = 0; q < 4; q++) acc[q] += xv * wcol[(j << 5) + ccb + q];
        }
#pragma unroll
        for (int q = 0; q < 4; q++) zs[c0 + q] = acc[q];
    }
    __syncthreads();
    // --- z2 + reversed block_out + bias -> out ---
    {
        int i_ = tid >> 3;
        int rb = (tid << 2) & 31;
        const float* z1row = &zs[i_ << 5];
        const float al = palpha[0];
        float vout[4];
#pragma unroll
        for (int q = 0; q < 4; q++) {
            float acc = 0.f;
            const float* wr = &wrow[(rb + q) << 5];
            for (int cc = 0; cc < 32; cc++) acc += z1row[cc] * wr[cc];
            vout[q] = ymix[1023 - (c0 + q)] + al * acc + pbias[c0 + q];
        }
        float4 o = {vout[0], vout[1], vout[2], vout[3]};
        *reinterpret_cast<float4*>(&out[((size_t)tok << 10) + c0]) = o;
    }
}

// ---------------------------------------------------------------------------
extern "C" void kernel_launch(void* const* d_in, const int* in_sizes, int n_in,
                              void* d_out, int out_size, void* d_ws, size_t ws_size,
                              hipStream_t stream) {
    const float* x   = (const float*)d_in[0];
    const float* w   = (const float*)d_in[1];
    const float* wb  = (const float*)d_in[2];
    const float* fg  = (const float*)d_in[3];
    const float* ang = (const float*)d_in[4];
    const float* anb = (const float*)d_in[5];
    const float* ong = (const float*)d_in[6];
    const float* onb = (const float*)d_in[7];
    const float* ppg = (const float*)d_in[8];
    const float* ppb = (const float*)d_in[9];
    const float* pbw = (const float*)d_in[10];
    const float* pwr = (const float*)d_in[11];
    const float* pwc = (const float*)d_in[12];
    const float* pal = (const float*)d_in[13];
    const float* pbi = (const float*)d_in[14];

    float* ws    = (float*)d_ws;
    float* qb    = ws;                    // 2 M floats each
    float* kb    = qb + 2097152;
    float* vb    = kb + 2097152;
    float* ylin  = vb + 2097152;
    float* ycomb = ylin + 2097152;
    float* Sg    = ycomb + 2097152;       // 32*16*4096
    float* svg   = Sg + 2097152;          // 32*16*64
    float* out   = (float*)d_out;

    k1_qkv    <<<dim3(48, 32), 256, 0, stream>>>(x, w, wb, qb, kb, vb);
    k2a_chunkkv<<<dim3(16, 32), 256, 0, stream>>>(kb, vb, Sg, svg);
    k2b_lin   <<<dim3(16, 32), 256, 0, stream>>>(qb, kb, vb, Sg, svg, ang, anb, ylin);
    k3_sharp  <<<dim3(16, 32), 256, 0, stream>>>(qb, kb, vb, ylin, fg, ycomb);
    k4_proj   <<<2048, 256, 0, stream>>>(ycomb, ong, onb, ppg, ppb, pbw, pwr, pwc, pal, pbi, out);
}

// Round 2
// 297.902 us; speedup vs baseline: 2.0005x; 2.0005x over previous
//
#include <hip/hip_runtime.h>
#include <math.h>

constexpr int T_ = 1024;
constexpr int C_ = 1024;
constexpr int H_ = 16;
constexpr int D_ = 64;
#define SCALE 0.125f

typedef unsigned short u16;
typedef __attribute__((ext_vector_type(8))) short short8;
typedef __attribute__((ext_vector_type(4))) float f32x4;

__device__ __forceinline__ float elu1(float x) { return x > 0.f ? x + 1.f : expf(x); }

__device__ __forceinline__ u16 f2bf(float f) {
    union { float f; unsigned u; } c; c.f = f;
    unsigned r = (c.u + 0x7fffu + ((c.u >> 16) & 1u)) >> 16;
    return (u16)r;
}
__device__ __forceinline__ float bf2f(u16 u) {
    union { unsigned u; float f; } c; c.u = (unsigned)u << 16;
    return c.f;
}

#define GLL16(g, l)                                                            \
    __builtin_amdgcn_global_load_lds(                                          \
        (const __attribute__((address_space(1))) void*)(g),                    \
        (__attribute__((address_space(3))) void*)(l), 16, 0, 0)

// ---------------------------------------------------------------------------
// K0: fp32 -> bf16 cast (x and W)
// ---------------------------------------------------------------------------
__global__ __launch_bounds__(256) void k0_cast(
    const float* __restrict__ s, u16* __restrict__ d, int n4)
{
    int i = blockIdx.x * 256 + threadIdx.x;
    if (i < n4) {
        float4 v = reinterpret_cast<const float4*>(s)[i];
        ushort4 o;
        o.x = f2bf(v.x); o.y = f2bf(v.y); o.z = f2bf(v.z); o.w = f2bf(v.w);
        reinterpret_cast<ushort4*>(d)[i] = o;
    }
}

// ---------------------------------------------------------------------------
// K1: bf16 MFMA GEMM  qkv = x @ W^T + b  (M=2048,N=3072,K=1024)
// 128x128 block tile, BK=32, global_load_lds staging, 2x2 waves x 4x4 frags.
// Outputs q/k/v as bf16 in (B,H,T,D).
// ---------------------------------------------------------------------------
__global__ __launch_bounds__(256) void k1_qkv(
    const u16* __restrict__ xbf, const u16* __restrict__ wbf,
    const float* __restrict__ bias,
    u16* __restrict__ qb, u16* __restrict__ kb, u16* __restrict__ vb)
{
    __shared__ __align__(16) u16 As[128 * 32];
    __shared__ __align__(16) u16 Bs[128 * 32];
    const int tid = threadIdx.x;
    const int wave = tid >> 6, lane = tid & 63;
    const int quad = lane >> 4, l15 = lane & 15;
    const int m0 = blockIdx.y << 7, n0 = blockIdx.x << 7;
    const int wm = (wave >> 1) << 6, wn = (wave & 1) << 6;

    const int rowS = (wave << 5) + (lane >> 2);   // staging row (issue 1)
    const int seg8 = (lane & 3) << 3;             // elem offset in row
    const u16* gA1 = xbf + (size_t)(m0 + rowS) * 1024 + seg8;
    const u16* gA2 = gA1 + (size_t)16 * 1024;
    const u16* gB1 = wbf + (size_t)(n0 + rowS) * 1024 + seg8;
    const u16* gB2 = gB1 + (size_t)16 * 1024;
    u16* lA1 = &As[(wave << 5) * 32];
    u16* lA2 = lA1 + 16 * 32;
    u16* lB1 = &Bs[(wave << 5) * 32];
    u16* lB2 = lB1 + 16 * 32;

    f32x4 zero4 = {0.f, 0.f, 0.f, 0.f};
    f32x4 acc[4][4];
#pragma unroll
    for (int i = 0; i < 4; i++)
#pragma unroll
        for (int j = 0; j < 4; j++) acc[i][j] = zero4;

    for (int k0 = 0; k0 < 1024; k0 += 32) {
        GLL16(gA1 + k0, lA1);
        GLL16(gA2 + k0, lA2);
        GLL16(gB1 + k0, lB1);
        GLL16(gB2 + k0, lB2);
        __syncthreads();
        short8 a[4], b[4];
#pragma unroll
        for (int mi = 0; mi < 4; mi++)
            a[mi] = *(const short8*)&As[(wm + mi * 16 + l15) * 32 + (quad << 3)];
#pragma unroll
        for (int ni = 0; ni < 4; ni++)
            b[ni] = *(const short8*)&Bs[(wn + ni * 16 + l15) * 32 + (quad << 3)];
#pragma unroll
        for (int mi = 0; mi < 4; mi++)
#pragma unroll
            for (int ni = 0; ni < 4; ni++)
                acc[mi][ni] = __builtin_amdgcn_mfma_f32_16x16x32_bf16(
                    a[mi], b[ni], acc[mi][ni], 0, 0, 0);
        __syncthreads();
    }
    // epilogue: + bias, bf16, scatter to q/k/v (B,H,T,D)
#pragma unroll
    for (int ni = 0; ni < 4; ni++) {
        int n_g = n0 + wn + ni * 16 + l15;
        int which = n_g >> 10;
        int h = (n_g >> 6) & 15;
        int d = n_g & 63;
        u16* dst = (which == 0) ? qb : (which == 1) ? kb : vb;
        float bz = bias[n_g];
#pragma unroll
        for (int mi = 0; mi < 4; mi++) {
#pragma unroll
            for (int reg = 0; reg < 4; reg++) {
                int m = m0 + wm + mi * 16 + (quad << 2) + reg;
                int bi = m >> 10, t = m & 1023;
                dst[((size_t)(bi * 16 + h) << 16) + ((size_t)t << 6) + d] =
                    f2bf(acc[mi][ni][reg] + bz);
            }
        }
    }
}

// ---------------------------------------------------------------------------
// K_VT: vtb[bh][d][t] = vb[bh][t][d]  (bf16 transpose, 64x64 tiles)
// ---------------------------------------------------------------------------
__global__ __launch_bounds__(256) void k_vt(
    const u16* __restrict__ vb, u16* __restrict__ vtb)
{
    const int t0 = blockIdx.x << 6, bh = blockIdx.y;
    __shared__ __align__(16) u16 Vs[64][72];
    const int tid = threadIdx.x;
#pragma unroll
    for (int u = 0; u < 2; u++) {
        int idx = (tid + (u << 8)) << 3;
        int r = idx >> 6, c = idx & 63;
        *(uint4*)&Vs[r][c] =
            *(const uint4*)&vb[((size_t)bh << 16) + ((size_t)(t0 + r) << 6) + c];
    }
    __syncthreads();
#pragma unroll
    for (int u = 0; u < 2; u++) {
        int idx = (tid + (u << 8)) << 3;
        int dd = idx >> 6, c0 = idx & 63;
        union { u16 s[8]; uint4 v; } tmp;
#pragma unroll
        for (int j = 0; j < 8; j++) tmp.s[j] = Vs[c0 + j][dd];
        *(uint4*)&vtb[((size_t)((bh << 6) + dd) << 10) + t0 + c0] = tmp.v;
    }
}

// ---------------------------------------------------------------------------
// K2a: per-(bh,chunk) KV state (fp32 VALU, bf16 inputs)
// ---------------------------------------------------------------------------
__global__ __launch_bounds__(256) void k2a_chunkkv(
    const u16* __restrict__ kb, const u16* __restrict__ vb,
    float* __restrict__ Sg, float* __restrict__ svg)
{
    const int chunk = blockIdx.x, bh = blockIdx.y;
    const int t0 = chunk << 6;
    __shared__ float Ks[64][65];
    __shared__ float Vs[64][65];
    const int tid = threadIdx.x;
    const u16* kp = kb + (size_t)bh * T_ * D_;
    const u16* vp = vb + (size_t)bh * T_ * D_;
#pragma unroll
    for (int ii = 0; ii < 16; ii++) {
        int idx = tid + (ii << 8);
        int row = idx >> 6, col = idx & 63;
        Ks[row][col] = elu1(bf2f(kp[(size_t)(t0 + row) * D_ + col]) * SCALE);
        Vs[row][col] = bf2f(vp[(size_t)(t0 + row) * D_ + col]);
    }
    __syncthreads();
    const int tr = tid >> 4, tc = tid & 15;
    const int d0 = tr * 4, e0 = tc * 4;
    float acc[4][4] = {};
    for (int c = 0; c < 64; c++) {
        float a[4], b[4];
#pragma unroll
        for (int i = 0; i < 4; i++) a[i] = Ks[c][d0 + i];
#pragma unroll
        for (int j = 0; j < 4; j++) b[j] = Vs[c][e0 + j];
#pragma unroll
        for (int i = 0; i < 4; i++)
#pragma unroll
            for (int j = 0; j < 4; j++) acc[i][j] += a[i] * b[j];
    }
    float* so = Sg + ((size_t)bh * 16 + chunk) * 4096;
#pragma unroll
    for (int i = 0; i < 4; i++) {
        float4 o = {acc[i][0], acc[i][1], acc[i][2], acc[i][3]};
        *reinterpret_cast<float4*>(&so[(d0 + i) * 64 + e0]) = o;
    }
    if (tc == 0) {
#pragma unroll
        for (int i = 0; i < 4; i++) {
            float s = 0.f;
            for (int c = 0; c < 64; c++) s += Ks[c][d0 + i];
            svg[((size_t)bh * 16 + chunk) * 64 + d0 + i] = s;
        }
    }
}

// ---------------------------------------------------------------------------
// K2b: linear attention per chunk (fp32 VALU, bf16 inputs) + head layernorm
// ---------------------------------------------------------------------------
__global__ __launch_bounds__(256) void k2b_lin(
    const u16* __restrict__ qbp, const u16* __restrict__ kbp,
    const u16* __restrict__ vbp,
    const float* __restrict__ Sg, const float* __restrict__ svg,
    const float* __restrict__ ang, const float* __restrict__ anb,
    float* __restrict__ ylin)
{
    const int chunk = blockIdx.x, bh = blockIdx.y;
    const int t0 = chunk << 6;
    __shared__ float bufA[64][65];
    __shared__ float bufQ[64][65];
    __shared__ float bufK[64][65];
    __shared__ float svec[64];
    const int tid = threadIdx.x;
    const u16* qp = qbp + (size_t)bh * T_ * D_;
    const u16* kp = kbp + (size_t)bh * T_ * D_;
    const u16* vp = vbp + (size_t)bh * T_ * D_;
#pragma unroll
    for (int ii = 0; ii < 16; ii++) {
        int idx = tid + (ii << 8);
        int dd = idx >> 6, e = idx & 63;
        float s = 0.f;
        for (int c = 0; c < chunk; c++)
            s += Sg[(((size_t)bh * 16 + c) << 12) + (dd << 6) + e];
        bufA[dd][e] = s;
    }
    if (tid < 64) {
        float s = 0.f;
        for (int c = 0; c < chunk; c++)
            s += svg[(((size_t)bh * 16 + c) << 6) + tid];
        svec[tid] = s;
    }
#pragma unroll
    for (int ii = 0; ii < 16; ii++) {
        int idx = tid + (ii << 8);
        int row = idx >> 6, col = idx & 63;
        bufQ[col][row] = elu1(bf2f(qp[(size_t)(t0 + row) * D_ + col]) * SCALE);
    }
    __syncthreads();
    const int tr = tid >> 4, tc = tid & 15;
    const int r0 = tr * 4, c0 = tc * 4;
    float N[4][4] = {};
    float pden[4];
    for (int dd = 0; dd < 64; dd++) {
        float a[4], b[4];
#pragma unroll
        for (int i = 0; i < 4; i++) a[i] = bufQ[dd][r0 + i];
#pragma unroll
        for (int j = 0; j < 4; j++) b[j] = bufA[dd][c0 + j];
#pragma unroll
        for (int i = 0; i < 4; i++)
#pragma unroll
            for (int j = 0; j < 4; j++) N[i][j] += a[i] * b[j];
    }
#pragma unroll
    for (int i = 0; i < 4; i++) {
        float s = 0.f;
#pragma unroll
        for (int j = 0; j < 4; j++) s += bufQ[c0 + j][r0 + i] * svec[c0 + j];
        pden[i] = s;
    }
    __syncthreads();
#pragma unroll
    for (int ii = 0; ii < 16; ii++) {
        int idx = tid + (ii << 8);
        int row = idx >> 6, col = idx & 63;
        bufK[col][row] = elu1(bf2f(kp[(size_t)(t0 + row) * D_ + col]) * SCALE);
        bufA[row][col] = bf2f(vp[(size_t)(t0 + row) * D_ + col]);
    }
    __syncthreads();
    float sc[4][4] = {};
    for (int dd = 0; dd < 64; dd++) {
        float a[4], b[4];
#pragma unroll
        for (int i = 0; i < 4; i++) a[i] = bufQ[dd][r0 + i];
#pragma unroll
        for (int j = 0; j < 4; j++) b[j] = bufK[dd][c0 + j];
#pragma unroll
        for (int i = 0; i < 4; i++)
#pragma unroll
            for (int j = 0; j < 4; j++) sc[i][j] += a[i] * b[j];
    }
    __syncthreads();
#pragma unroll
    for (int i = 0; i < 4; i++) {
        float s = 0.f;
#pragma unroll
        for (int j = 0; j < 4; j++) {
            float pv = ((c0 + j) <= (r0 + i)) ? sc[i][j] : 0.f;
            bufQ[c0 + j][r0 + i] = pv;
            s += pv;
        }
        pden[i] += s;
    }
#pragma unroll
    for (int i = 0; i < 4; i++) {
#pragma unroll
        for (int off = 1; off < 16; off <<= 1)
            pden[i] += __shfl_xor(pden[i], off);
    }
    __syncthreads();
    for (int c = 0; c < 64; c++) {
        float a[4], b[4];
#pragma unroll
        for (int i = 0; i < 4; i++) a[i] = bufQ[c][r0 + i];
#pragma unroll
        for (int j = 0; j < 4; j++) b[j] = bufA[c][c0 + j];
#pragma unroll
        for (int i = 0; i < 4; i++)
#pragma unroll
            for (int j = 0; j < 4; j++) N[i][j] += a[i] * b[j];
    }
    float yv[4][4], s1[4], s2[4];
#pragma unroll
    for (int i = 0; i < 4; i++) {
        float inv = 1.f / (pden[i] + 1e-4f);
        s1[i] = 0.f; s2[i] = 0.f;
#pragma unroll
        for (int j = 0; j < 4; j++) {
            float t = N[i][j] * inv;
            yv[i][j] = t; s1[i] += t; s2[i] += t * t;
        }
    }
#pragma unroll
    for (int i = 0; i < 4; i++) {
#pragma unroll
        for (int off = 1; off < 16; off <<= 1) {
            s1[i] += __shfl_xor(s1[i], off);
            s2[i] += __shfl_xor(s2[i], off);
        }
    }
#pragma unroll
    for (int i = 0; i < 4; i++) {
        float mean = s1[i] * (1.f / 64.f);
        float var = s2[i] * (1.f / 64.f) - mean * mean;
        float rstd = rsqrtf(var + 1e-5f);
        float4 o;
        o.x = (yv[i][0] - mean) * rstd * ang[c0 + 0] + anb[c0 + 0];
        o.y = (yv[i][1] - mean) * rstd * ang[c0 + 1] + anb[c0 + 1];
        o.z = (yv[i][2] - mean) * rstd * ang[c0 + 2] + anb[c0 + 2];
        o.w = (yv[i][3] - mean) * rstd * ang[c0 + 3] + anb[c0 + 3];
        *reinterpret_cast<float4*>(
            &ylin[((size_t)bh * T_ + t0 + r0 + i) * D_ + c0]) = o;
    }
}

// ---------------------------------------------------------------------------
// K3: MFMA flash attention. S^T = K.Q^T so P lands A-operand-friendly.
// Each block: qi = blockIdx.x then 15-blockIdx.x  (17 K-tiles, balanced).
// ---------------------------------------------------------------------------
__global__ __launch_bounds__(256) void k3_sharp(
    const u16* __restrict__ qbp, const u16* __restrict__ kbp,
    const u16* __restrict__ vtb,
    const float* __restrict__ ylin, const float* __restrict__ fg,
    float* __restrict__ ycomb)
{
    const int bh = blockIdx.y;
    __shared__ __align__(16) u16 Qs[64][72];
    __shared__ __align__(16) u16 Ks[64][72];
    __shared__ __align__(16) u16 Vt[64][72];
    __shared__ __align__(16) u16 Pa[64][72];
    const int tid = threadIdx.x;
    const int wave = tid >> 6, lane = tid & 63;
    const int quad = lane >> 4, l15 = lane & 15;
    const float al = 1.f / (1.f + expf(-fg[0]));
    const int bi = bh >> 4, h = bh & 15;
    const f32x4 zero4 = {0.f, 0.f, 0.f, 0.f};

    for (int phase = 0; phase < 2; phase++) {
        const int qi = phase == 0 ? (int)blockIdx.x : 15 - (int)blockIdx.x;
        __syncthreads();
#pragma unroll
        for (int u = 0; u < 2; u++) {
            int idx = (tid + (u << 8)) << 3;
            int r = idx >> 6, c = idx & 63;
            *(uint4*)&Qs[r][c] = *(const uint4*)
                &qbp[((size_t)bh << 16) + ((size_t)((qi << 6) + r) << 6) + c];
        }
        __syncthreads();
        short8 bq[2];
        bq[0] = *(const short8*)&Qs[(wave << 4) + l15][(quad << 3)];
        bq[1] = *(const short8*)&Qs[(wave << 4) + l15][32 + (quad << 3)];
        f32x4 O[4];
#pragma unroll
        for (int dt = 0; dt < 4; dt++) O[dt] = zero4;
        float m_run = -INFINITY, l_run = 0.f;
        const int r_g = (qi << 6) + (wave << 4) + l15;

        for (int ki = 0; ki <= qi; ki++) {
            __syncthreads();
#pragma unroll
            for (int u = 0; u < 2; u++) {
                int idx = (tid + (u << 8)) << 3;
                int r = idx >> 6, c = idx & 63;
                *(uint4*)&Ks[r][c] = *(const uint4*)
                    &kbp[((size_t)bh << 16) + ((size_t)((ki << 6) + r) << 6) + c];
                *(uint4*)&Vt[r][c] = *(const uint4*)
                    &vtb[((size_t)((bh << 6) + r) << 10) + (ki << 6) + c];
            }
            __syncthreads();
            f32x4 st[4];
#pragma unroll
            for (int ct = 0; ct < 4; ct++) st[ct] = zero4;
#pragma unroll
            for (int ks = 0; ks < 2; ks++) {
#pragma unroll
                for (int ct = 0; ct < 4; ct++) {
                    short8 a = *(const short8*)
                        &Ks[(ct << 4) + l15][(ks << 5) + (quad << 3)];
                    st[ct] = __builtin_amdgcn_mfma_f32_16x16x32_bf16(
                        a, bq[ks], st[ct], 0, 0, 0);
                }
            }
            float mloc = -INFINITY;
#pragma unroll
            for (int ct = 0; ct < 4; ct++)
#pragma unroll
                for (int reg = 0; reg < 4; reg++) {
                    int c_g = (ki << 6) + (ct << 4) + (quad << 2) + reg;
                    float s = st[ct][reg] * SCALE;
                    if (c_g > r_g) s = -INFINITY;
                    st[ct][reg] = s;
                    mloc = fmaxf(mloc, s);
                }
            mloc = fmaxf(mloc, __shfl_xor(mloc, 16));
            mloc = fmaxf(mloc, __shfl_xor(mloc, 32));
            float mnew = fmaxf(m_run, mloc);
            float corr = __expf(m_run - mnew);
            m_run = mnew;
            float rsum = 0.f;
#pragma unroll
            for (int ct = 0; ct < 4; ct++) {
                u16 pk[4];
#pragma unroll
                for (int reg = 0; reg < 4; reg++) {
                    float pv = __expf(st[ct][reg] - mnew);
                    rsum += pv;
                    pk[reg] = f2bf(pv);
                }
                unsigned lo = (unsigned)pk[0] | ((unsigned)pk[1] << 16);
                unsigned hi = (unsigned)pk[2] | ((unsigned)pk[3] << 16);
                uint2 pkv; pkv.x = lo; pkv.y = hi;
                *(uint2*)&Pa[(wave << 4) + l15][(ct << 4) + (quad << 2)] = pkv;
            }
            rsum += __shfl_xor(rsum, 16);
            rsum += __shfl_xor(rsum, 32);
            l_run = l_run * corr + rsum;
            float co[4];
#pragma unroll
            for (int reg = 0; reg < 4; reg++)
                co[reg] = __shfl(corr, ((lane >> 4) << 2) + reg);
#pragma unroll
            for (int dt = 0; dt < 4; dt++)
#pragma unroll
                for (int reg = 0; reg < 4; reg++) O[dt][reg] *= co[reg];
#pragma unroll
            for (int ks = 0; ks < 2; ks++) {
                short8 ap = *(const short8*)
                    &Pa[(wave << 4) + l15][(ks << 5) + (quad << 3)];
#pragma unroll
                for (int dt = 0; dt < 4; dt++) {
                    short8 bv = *(const short8*)
                        &Vt[(dt << 4) + l15][(ks << 5) + (quad << 3)];
                    O[dt] = __builtin_amdgcn_mfma_f32_16x16x32_bf16(
                        ap, bv, O[dt], 0, 0, 0);
                }
            }
        }
        float lo4[4];
#pragma unroll
        for (int reg = 0; reg < 4; reg++)
            lo4[reg] = __shfl(l_run, ((lane >> 4) << 2) + reg);
#pragma unroll
        for (int reg = 0; reg < 4; reg++) {
            int t = (qi << 6) + (wave << 4) + (quad << 2) + reg;
            float inv = al / lo4[reg];
#pragma unroll
            for (int dt = 0; dt < 4; dt++) {
                int d = (dt << 4) + l15;
                float yl = ylin[(((size_t)bh << 10) + t) * 64 + d];
                ycomb[((size_t)((bi << 10) + t) << 10) + (h << 6) + d] =
                    O[dt][reg] * inv + (1.f - al) * yl;
            }
        }
    }
}

// ---------------------------------------------------------------------------
// K4: out-LN -> pre-LN -> block-diag mix (reversed) + 32x32 bilinear + bias
// ---------------------------------------------------------------------------
__global__ __launch_bounds__(256) void k4_proj(
    const float* __restrict__ ycomb,
    const float* __restrict__ og, const float* __restrict__ ob,
    const float* __restrict__ pg, const float* __restrict__ pb,
    const float* __restrict__ bw, const float* __restrict__ wrow,
    const float* __restrict__ wcol, const float* __restrict__ palpha,
    const float* __restrict__ pbias, float* __restrict__ out)
{
    const int tok = blockIdx.x;
    __shared__ float xb[1024];
    __shared__ float ymix[1024];
    __shared__ float zs[1024];
    __shared__ float red[8];
    const int tid = threadIdx.x;
    const int c0 = tid << 2;
    const float* yrow = ycomb + ((size_t)tok << 10);
    float4 v4 = *reinterpret_cast<const float4*>(yrow + c0);
    float v[4] = {v4.x, v4.y, v4.z, v4.w};
    float s1 = v[0] + v[1] + v[2] + v[3];
    float s2 = v[0]*v[0] + v[1]*v[1] + v[2]*v[2] + v[3]*v[3];
#pragma unroll
    for (int off = 1; off < 64; off <<= 1) {
        s1 += __shfl_xor(s1, off); s2 += __shfl_xor(s2, off);
    }
    if ((tid & 63) == 0) { red[(tid >> 6) * 2] = s1; red[(tid >> 6) * 2 + 1] = s2; }
    __syncthreads();
    s1 = red[0] + red[2] + red[4] + red[6];
    s2 = red[1] + red[3] + red[5] + red[7];
    __syncthreads();
    {
        float mean = s1 * (1.f / 1024.f);
        float var = s2 * (1.f / 1024.f) - mean * mean;
        float rstd = rsqrtf(var + 1e-5f);
#pragma unroll
        for (int q = 0; q < 4; q++)
            v[q] = (v[q] - mean) * rstd * og[c0 + q] + ob[c0 + q];
    }
    s1 = v[0] + v[1] + v[2] + v[3];
    s2 = v[0]*v[0] + v[1]*v[1] + v[2]*v[2] + v[3]*v[3];
#pragma unroll
    for (int off = 1; off < 64; off <<= 1) {
        s1 += __shfl_xor(s1, off); s2 += __shfl_xor(s2, off);
    }
    if ((tid & 63) == 0) { red[(tid >> 6) * 2] = s1; red[(tid >> 6) * 2 + 1] = s2; }
    __syncthreads();
    s1 = red[0] + red[2] + red[4] + red[6];
    s2 = red[1] + red[3] + red[5] + red[7];
    __syncthreads();
    {
        float mean = s1 * (1.f / 1024.f);
        float var = s2 * (1.f / 1024.f) - mean * mean;
        float rstd = rsqrtf(var + 1e-5f);
#pragma unroll
        for (int q = 0; q < 4; q++)
            xb[c0 + q] = (v[q] - mean) * rstd * pg[c0 + q] + pb[c0 + q];
    }
    __syncthreads();
    {
        int g = tid >> 2;
        int jb = (tid & 3) << 2;
        float acc[4] = {0.f, 0.f, 0.f, 0.f};
        const float* xg = &xb[g << 4];
        const float* bwg = &bw[g << 8];
        for (int i = 0; i < 16; i++) {
            float xv = xg[i];
#pragma unroll
            for (int q = 0; q < 4; q++) acc[q] += xv * bwg[i * 16 + jb + q];
        }
#pragma unroll
        for (int q = 0; q < 4; q++) ymix[(g << 4) + jb + q] = acc[q];
    }
    {
        int i_ = tid >> 3;
        int ccb = (tid << 2) & 31;
        float acc[4] = {0.f, 0.f, 0.f, 0.f};
        const float* xg = &xb[i_ << 5];
        for (int j = 0; j < 32; j++) {
            float xv = xg[j];
#pragma unroll
            for (int q = 0; q < 4; q++) acc[q] += xv * wcol[(j << 5) + ccb + q];
        }
#pragma unroll
        for (int q = 0; q < 4; q++) zs[(i_ << 5) + ccb + q] = acc[q];
    }
    __syncthreads();
    {
        int i_ = tid >> 3;
        int rb = (tid << 2) & 31;
        const float* z1row = &zs[i_ << 5];
        const float al = palpha[0];
        float vout[4];
#pragma unroll
        for (int q = 0; q < 4; q++) {
            float acc = 0.f;
            const float* wr = &wrow[(rb + q) << 5];
            for (int cc = 0; cc < 32; cc++) acc += z1row[cc] * wr[cc];
            int ch = (i_ << 5) + rb + q;
            vout[q] = ymix[1023 - ch] + al * acc + pbias[ch];
        }
        float4 o = {vout[0], vout[1], vout[2], vout[3]};
        *reinterpret_cast<float4*>(&out[((size_t)tok << 10) + (i_ << 5) + rb]) = o;
    }
}

// ---------------------------------------------------------------------------
extern "C" void kernel_launch(void* const* d_in, const int* in_sizes, int n_in,
                              void* d_out, int out_size, void* d_ws, size_t ws_size,
                              hipStream_t stream) {
    const float* x   = (const float*)d_in[0];
    const float* w   = (const float*)d_in[1];
    const float* wb  = (const float*)d_in[2];
    const float* fg  = (const float*)d_in[3];
    const float* ang = (const float*)d_in[4];
    const float* anb = (const float*)d_in[5];
    const float* ong = (const float*)d_in[6];
    const float* onb = (const float*)d_in[7];
    const float* ppg = (const float*)d_in[8];
    const float* ppb = (const float*)d_in[9];
    const float* pbw = (const float*)d_in[10];
    const float* pwr = (const float*)d_in[11];
    const float* pwc = (const float*)d_in[12];
    const float* pal = (const float*)d_in[13];
    const float* pbi = (const float*)d_in[14];

    uint8_t* p = (uint8_t*)d_ws;
    u16* xbf = (u16*)p;  p += (size_t)2048 * 1024 * 2;
    u16* wbf = (u16*)p;  p += (size_t)3072 * 1024 * 2;
    u16* qb  = (u16*)p;  p += (size_t)32 * 1024 * 64 * 2;
    u16* kb  = (u16*)p;  p += (size_t)32 * 1024 * 64 * 2;
    u16* vb  = (u16*)p;  p += (size_t)32 * 1024 * 64 * 2;
    u16* vtb = (u16*)p;  p += (size_t)32 * 1024 * 64 * 2;
    float* ylin  = (float*)p;  p += (size_t)32 * 1024 * 64 * 4;
    float* ycomb = (float*)p;  p += (size_t)32 * 1024 * 64 * 4;
    float* Sg    = (float*)p;  p += (size_t)32 * 16 * 4096 * 4;
    float* svg   = (float*)p;  p += (size_t)32 * 16 * 64 * 4;
    float* out   = (float*)d_out;

    k0_cast<<<2048, 256, 0, stream>>>(x, xbf, 524288);
    k0_cast<<<3072, 256, 0, stream>>>(w, wbf, 786432);
    k1_qkv<<<dim3(24, 16), 256, 0, stream>>>(xbf, wbf, wb, qb, kb, vb);
    k_vt<<<dim3(16, 32), 256, 0, stream>>>(vb, vtb);
    k2a_chunkkv<<<dim3(16, 32), 256, 0, stream>>>(kb, vb, Sg, svg);
    k2b_lin<<<dim3(16, 32), 256, 0, stream>>>(qb, kb, vb, Sg, svg, ang, anb, ylin);
    k3_sharp<<<dim3(8, 32), 256, 0, stream>>>(qb, kb, vtb, ylin, fg, ycomb);
    k4_proj<<<2048, 256, 0, stream>>>(ycomb, ong, onb, ppg, ppb, pbw, pwr, pwc, pal, pbi, out);
}

// Round 3
// 247.512 us; speedup vs baseline: 2.4078x; 1.2036x over previous
//
#include <hip/hip_runtime.h>
#include <math.h>

constexpr int T_ = 1024;
constexpr int C_ = 1024;
constexpr int H_ = 16;
constexpr int D_ = 64;
#define SCALE 0.125f

typedef unsigned short u16;
typedef __attribute__((ext_vector_type(8))) short short8;
typedef __attribute__((ext_vector_type(4))) float f32x4;

__device__ __forceinline__ float elu1(float x) { return x > 0.f ? x + 1.f : expf(x); }

__device__ __forceinline__ u16 f2bf(float f) {
    union { float f; unsigned u; } c; c.f = f;
    unsigned r = (c.u + 0x7fffu + ((c.u >> 16) & 1u)) >> 16;
    return (u16)r;
}
__device__ __forceinline__ float bf2f(u16 u) {
    union { unsigned u; float f; } c; c.u = (unsigned)u << 16;
    return c.f;
}

#define GLL16(g, l)                                                            \
    __builtin_amdgcn_global_load_lds(                                          \
        (const __attribute__((address_space(1))) void*)(g),                    \
        (__attribute__((address_space(3))) void*)(l), 16, 0, 0)

// ---------------------------------------------------------------------------
// K0: fp32 -> bf16 cast
// ---------------------------------------------------------------------------
__global__ __launch_bounds__(256) void k0_cast(
    const float* __restrict__ s, u16* __restrict__ d, int n4)
{
    int i = blockIdx.x * 256 + threadIdx.x;
    if (i < n4) {
        float4 v = reinterpret_cast<const float4*>(s)[i];
        ushort4 o;
        o.x = f2bf(v.x); o.y = f2bf(v.y); o.z = f2bf(v.z); o.w = f2bf(v.w);
        reinterpret_cast<ushort4*>(d)[i] = o;
    }
}

// ---------------------------------------------------------------------------
// K1: bf16 MFMA GEMM  qkv = x @ W^T + b  (M=2048,N=3072,K=1024)
// ---------------------------------------------------------------------------
__global__ __launch_bounds__(256) void k1_qkv(
    const u16* __restrict__ xbf, const u16* __restrict__ wbf,
    const float* __restrict__ bias,
    u16* __restrict__ qb, u16* __restrict__ kb, u16* __restrict__ vb)
{
    __shared__ __align__(16) u16 As[128 * 32];
    __shared__ __align__(16) u16 Bs[128 * 32];
    const int tid = threadIdx.x;
    const int wave = tid >> 6, lane = tid & 63;
    const int quad = lane >> 4, l15 = lane & 15;
    const int m0 = blockIdx.y << 7, n0 = blockIdx.x << 7;
    const int wm = (wave >> 1) << 6, wn = (wave & 1) << 6;

    const int rowS = (wave << 5) + (lane >> 2);
    const int seg8 = (lane & 3) << 3;
    const u16* gA1 = xbf + (size_t)(m0 + rowS) * 1024 + seg8;
    const u16* gA2 = gA1 + (size_t)16 * 1024;
    const u16* gB1 = wbf + (size_t)(n0 + rowS) * 1024 + seg8;
    const u16* gB2 = gB1 + (size_t)16 * 1024;
    u16* lA1 = &As[(wave << 5) * 32];
    u16* lA2 = lA1 + 16 * 32;
    u16* lB1 = &Bs[(wave << 5) * 32];
    u16* lB2 = lB1 + 16 * 32;

    f32x4 zero4 = {0.f, 0.f, 0.f, 0.f};
    f32x4 acc[4][4];
#pragma unroll
    for (int i = 0; i < 4; i++)
#pragma unroll
        for (int j = 0; j < 4; j++) acc[i][j] = zero4;

    for (int k0 = 0; k0 < 1024; k0 += 32) {
        GLL16(gA1 + k0, lA1);
        GLL16(gA2 + k0, lA2);
        GLL16(gB1 + k0, lB1);
        GLL16(gB2 + k0, lB2);
        __syncthreads();
        short8 a[4], b[4];
#pragma unroll
        for (int mi = 0; mi < 4; mi++)
            a[mi] = *(const short8*)&As[(wm + mi * 16 + l15) * 32 + (quad << 3)];
#pragma unroll
        for (int ni = 0; ni < 4; ni++)
            b[ni] = *(const short8*)&Bs[(wn + ni * 16 + l15) * 32 + (quad << 3)];
#pragma unroll
        for (int mi = 0; mi < 4; mi++)
#pragma unroll
            for (int ni = 0; ni < 4; ni++)
                acc[mi][ni] = __builtin_amdgcn_mfma_f32_16x16x32_bf16(
                    a[mi], b[ni], acc[mi][ni], 0, 0, 0);
        __syncthreads();
    }
#pragma unroll
    for (int ni = 0; ni < 4; ni++) {
        int n_g = n0 + wn + ni * 16 + l15;
        int which = n_g >> 10;
        int h = (n_g >> 6) & 15;
        int d = n_g & 63;
        u16* dst = (which == 0) ? qb : (which == 1) ? kb : vb;
        float bz = bias[n_g];
#pragma unroll
        for (int mi = 0; mi < 4; mi++) {
#pragma unroll
            for (int reg = 0; reg < 4; reg++) {
                int m = m0 + wm + mi * 16 + (quad << 2) + reg;
                int bi = m >> 10, t = m & 1023;
                dst[((size_t)(bi * 16 + h) << 16) + ((size_t)t << 6) + d] =
                    f2bf(acc[mi][ni][reg] + bz);
            }
        }
    }
}

// ---------------------------------------------------------------------------
// K_VT: vtb[bh][d][t] = vb[bh][t][d]
// ---------------------------------------------------------------------------
__global__ __launch_bounds__(256) void k_vt(
    const u16* __restrict__ vb, u16* __restrict__ vtb)
{
    const int t0 = blockIdx.x << 6, bh = blockIdx.y;
    __shared__ __align__(16) u16 Vs[64][72];
    const int tid = threadIdx.x;
#pragma unroll
    for (int u = 0; u < 2; u++) {
        int idx = (tid + (u << 8)) << 3;
        int r = idx >> 6, c = idx & 63;
        *(uint4*)&Vs[r][c] =
            *(const uint4*)&vb[((size_t)bh << 16) + ((size_t)(t0 + r) << 6) + c];
    }
    __syncthreads();
#pragma unroll
    for (int u = 0; u < 2; u++) {
        int idx = (tid + (u << 8)) << 3;
        int dd = idx >> 6, c0 = idx & 63;
        union { u16 s[8]; uint4 v; } tmp;
#pragma unroll
        for (int j = 0; j < 8; j++) tmp.s[j] = Vs[c0 + j][dd];
        *(uint4*)&vtb[((size_t)((bh << 6) + dd) << 10) + t0 + c0] = tmp.v;
    }
}

// ---------------------------------------------------------------------------
// K2a: per-(bh,chunk) KV state
// ---------------------------------------------------------------------------
__global__ __launch_bounds__(256) void k2a_chunkkv(
    const u16* __restrict__ kb, const u16* __restrict__ vb,
    float* __restrict__ Sg, float* __restrict__ svg)
{
    const int chunk = blockIdx.x, bh = blockIdx.y;
    const int t0 = chunk << 6;
    __shared__ float Ks[64][65];
    __shared__ float Vs[64][65];
    const int tid = threadIdx.x;
    const u16* kp = kb + (size_t)bh * T_ * D_;
    const u16* vp = vb + (size_t)bh * T_ * D_;
#pragma unroll
    for (int ii = 0; ii < 16; ii++) {
        int idx = tid + (ii << 8);
        int row = idx >> 6, col = idx & 63;
        Ks[row][col] = elu1(bf2f(kp[(size_t)(t0 + row) * D_ + col]) * SCALE);
        Vs[row][col] = bf2f(vp[(size_t)(t0 + row) * D_ + col]);
    }
    __syncthreads();
    const int tr = tid >> 4, tc = tid & 15;
    const int d0 = tr * 4, e0 = tc * 4;
    float acc[4][4] = {};
    for (int c = 0; c < 64; c++) {
        float a[4], b[4];
#pragma unroll
        for (int i = 0; i < 4; i++) a[i] = Ks[c][d0 + i];
#pragma unroll
        for (int j = 0; j < 4; j++) b[j] = Vs[c][e0 + j];
#pragma unroll
        for (int i = 0; i < 4; i++)
#pragma unroll
            for (int j = 0; j < 4; j++) acc[i][j] += a[i] * b[j];
    }
    float* so = Sg + ((size_t)bh * 16 + chunk) * 4096;
#pragma unroll
    for (int i = 0; i < 4; i++) {
        float4 o = {acc[i][0], acc[i][1], acc[i][2], acc[i][3]};
        *reinterpret_cast<float4*>(&so[(d0 + i) * 64 + e0]) = o;
    }
    if (tc == 0) {
#pragma unroll
        for (int i = 0; i < 4; i++) {
            float s = 0.f;
            for (int c = 0; c < 64; c++) s += Ks[c][d0 + i];
            svg[((size_t)bh * 16 + chunk) * 64 + d0 + i] = s;
        }
    }
}

// ---------------------------------------------------------------------------
// K2s: in-place exclusive prefix scan over the chunk dim of Sg (and svg).
// 131072 lanes of len 16 (Sg) + 2048 lanes (svg); all loads/stores coalesced.
// ---------------------------------------------------------------------------
__global__ __launch_bounds__(256) void k2s_scan(
    float* __restrict__ Sg, float* __restrict__ svg)
{
    int gid = blockIdx.x * 256 + threadIdx.x;
    if (gid < 131072) {
        int bh = gid >> 12, e = gid & 4095;
        float* base = Sg + ((size_t)bh << 16) + e;
        float v[16];
#pragma unroll
        for (int c = 0; c < 16; c++) v[c] = base[(size_t)c << 12];
        float run = 0.f;
#pragma unroll
        for (int c = 0; c < 16; c++) {
            base[(size_t)c << 12] = run;
            run += v[c];
        }
    } else if (gid < 131072 + 2048) {
        int g2 = gid - 131072;
        int bh = g2 >> 6, d = g2 & 63;
        float* base = svg + ((size_t)bh << 10) + d;
        float v[16];
#pragma unroll
        for (int c = 0; c < 16; c++) v[c] = base[c << 6];
        float run = 0.f;
#pragma unroll
        for (int c = 0; c < 16; c++) {
            base[c << 6] = run;
            run += v[c];
        }
    }
}

// ---------------------------------------------------------------------------
// K2b: linear attention per chunk; prefix state now a direct float4 load.
// ---------------------------------------------------------------------------
__global__ __launch_bounds__(256) void k2b_lin(
    const u16* __restrict__ qbp, const u16* __restrict__ kbp,
    const u16* __restrict__ vbp,
    const float* __restrict__ Sg, const float* __restrict__ svg,
    const float* __restrict__ ang, const float* __restrict__ anb,
    float* __restrict__ ylin)
{
    const int chunk = blockIdx.x, bh = blockIdx.y;
    const int t0 = chunk << 6;
    __shared__ __align__(16) float bufA[64][68];  // S[d][e], then V[t][e]
    __shared__ float bufQ[64][65];                // QpT, then PT
    __shared__ float bufK[64][65];                // KpT
    __shared__ float svec[64];
    const int tid = threadIdx.x;
    const u16* qp = qbp + (size_t)bh * T_ * D_;
    const u16* kp = kbp + (size_t)bh * T_ * D_;
    const u16* vp = vbp + (size_t)bh * T_ * D_;
    // exclusive-prefix state: direct vector load
    const float* sp = Sg + (((size_t)bh * 16 + chunk) << 12);
#pragma unroll
    for (int u = 0; u < 4; u++) {
        int idx = (tid + (u << 8)) << 2;
        int dd = idx >> 6, e = idx & 63;
        *(float4*)&bufA[dd][e] = *(const float4*)&sp[idx];
    }
    if (tid < 64) svec[tid] = svg[(((size_t)bh * 16 + chunk) << 6) + tid];
#pragma unroll
    for (int ii = 0; ii < 16; ii++) {
        int idx = tid + (ii << 8);
        int row = idx >> 6, col = idx & 63;
        bufQ[col][row] = elu1(bf2f(qp[(size_t)(t0 + row) * D_ + col]) * SCALE);
    }
    __syncthreads();
    const int tr = tid >> 4, tc = tid & 15;
    const int r0 = tr * 4, c0 = tc * 4;
    float N[4][4] = {};
    float pden[4];
    for (int dd = 0; dd < 64; dd++) {
        float a[4], b[4];
#pragma unroll
        for (int i = 0; i < 4; i++) a[i] = bufQ[dd][r0 + i];
#pragma unroll
        for (int j = 0; j < 4; j++) b[j] = bufA[dd][c0 + j];
#pragma unroll
        for (int i = 0; i < 4; i++)
#pragma unroll
            for (int j = 0; j < 4; j++) N[i][j] += a[i] * b[j];
    }
#pragma unroll
    for (int i = 0; i < 4; i++) {
        float s = 0.f;
#pragma unroll
        for (int j = 0; j < 4; j++) s += bufQ[c0 + j][r0 + i] * svec[c0 + j];
        pden[i] = s;
    }
    __syncthreads();
#pragma unroll
    for (int ii = 0; ii < 16; ii++) {
        int idx = tid + (ii << 8);
        int row = idx >> 6, col = idx & 63;
        bufK[col][row] = elu1(bf2f(kp[(size_t)(t0 + row) * D_ + col]) * SCALE);
        bufA[row][col] = bf2f(vp[(size_t)(t0 + row) * D_ + col]);
    }
    __syncthreads();
    float sc[4][4] = {};
    for (int dd = 0; dd < 64; dd++) {
        float a[4], b[4];
#pragma unroll
        for (int i = 0; i < 4; i++) a[i] = bufQ[dd][r0 + i];
#pragma unroll
        for (int j = 0; j < 4; j++) b[j] = bufK[dd][c0 + j];
#pragma unroll
        for (int i = 0; i < 4; i++)
#pragma unroll
            for (int j = 0; j < 4; j++) sc[i][j] += a[i] * b[j];
    }
    __syncthreads();
#pragma unroll
    for (int i = 0; i < 4; i++) {
        float s = 0.f;
#pragma unroll
        for (int j = 0; j < 4; j++) {
            float pv = ((c0 + j) <= (r0 + i)) ? sc[i][j] : 0.f;
            bufQ[c0 + j][r0 + i] = pv;
            s += pv;
        }
        pden[i] += s;
    }
#pragma unroll
    for (int i = 0; i < 4; i++) {
#pragma unroll
        for (int off = 1; off < 16; off <<= 1)
            pden[i] += __shfl_xor(pden[i], off);
    }
    __syncthreads();
    for (int c = 0; c < 64; c++) {
        float a[4], b[4];
#pragma unroll
        for (int i = 0; i < 4; i++) a[i] = bufQ[c][r0 + i];
#pragma unroll
        for (int j = 0; j < 4; j++) b[j] = bufA[c][c0 + j];
#pragma unroll
        for (int i = 0; i < 4; i++)
#pragma unroll
            for (int j = 0; j < 4; j++) N[i][j] += a[i] * b[j];
    }
    float yv[4][4], s1[4], s2[4];
#pragma unroll
    for (int i = 0; i < 4; i++) {
        float inv = 1.f / (pden[i] + 1e-4f);
        s1[i] = 0.f; s2[i] = 0.f;
#pragma unroll
        for (int j = 0; j < 4; j++) {
            float t = N[i][j] * inv;
            yv[i][j] = t; s1[i] += t; s2[i] += t * t;
        }
    }
#pragma unroll
    for (int i = 0; i < 4; i++) {
#pragma unroll
        for (int off = 1; off < 16; off <<= 1) {
            s1[i] += __shfl_xor(s1[i], off);
            s2[i] += __shfl_xor(s2[i], off);
        }
    }
#pragma unroll
    for (int i = 0; i < 4; i++) {
        float mean = s1[i] * (1.f / 64.f);
        float var = s2[i] * (1.f / 64.f) - mean * mean;
        float rstd = rsqrtf(var + 1e-5f);
        float4 o;
        o.x = (yv[i][0] - mean) * rstd * ang[c0 + 0] + anb[c0 + 0];
        o.y = (yv[i][1] - mean) * rstd * ang[c0 + 1] + anb[c0 + 1];
        o.z = (yv[i][2] - mean) * rstd * ang[c0 + 2] + anb[c0 + 2];
        o.w = (yv[i][3] - mean) * rstd * ang[c0 + 3] + anb[c0 + 3];
        *reinterpret_cast<float4*>(
            &ylin[((size_t)bh * T_ + t0 + r0 + i) * D_ + c0]) = o;
    }
}

// ---------------------------------------------------------------------------
// K3: MFMA flash attention (S^T = K.Q^T trick)
// ---------------------------------------------------------------------------
__global__ __launch_bounds__(256) void k3_sharp(
    const u16* __restrict__ qbp, const u16* __restrict__ kbp,
    const u16* __restrict__ vtb,
    const float* __restrict__ ylin, const float* __restrict__ fg,
    float* __restrict__ ycomb)
{
    const int bh = blockIdx.y;
    __shared__ __align__(16) u16 Qs[64][72];
    __shared__ __align__(16) u16 Ks[64][72];
    __shared__ __align__(16) u16 Vt[64][72];
    __shared__ __align__(16) u16 Pa[64][72];
    const int tid = threadIdx.x;
    const int wave = tid >> 6, lane = tid & 63;
    const int quad = lane >> 4, l15 = lane & 15;
    const float al = 1.f / (1.f + expf(-fg[0]));
    const int bi = bh >> 4, h = bh & 15;
    const f32x4 zero4 = {0.f, 0.f, 0.f, 0.f};

    for (int phase = 0; phase < 2; phase++) {
        const int qi = phase == 0 ? (int)blockIdx.x : 15 - (int)blockIdx.x;
        __syncthreads();
#pragma unroll
        for (int u = 0; u < 2; u++) {
            int idx = (tid + (u << 8)) << 3;
            int r = idx >> 6, c = idx & 63;
            *(uint4*)&Qs[r][c] = *(const uint4*)
                &qbp[((size_t)bh << 16) + ((size_t)((qi << 6) + r) << 6) + c];
        }
        __syncthreads();
        short8 bq[2];
        bq[0] = *(const short8*)&Qs[(wave << 4) + l15][(quad << 3)];
        bq[1] = *(const short8*)&Qs[(wave << 4) + l15][32 + (quad << 3)];
        f32x4 O[4];
#pragma unroll
        for (int dt = 0; dt < 4; dt++) O[dt] = zero4;
        float m_run = -INFINITY, l_run = 0.f;
        const int r_g = (qi << 6) + (wave << 4) + l15;

        for (int ki = 0; ki <= qi; ki++) {
            __syncthreads();
#pragma unroll
            for (int u = 0; u < 2; u++) {
                int idx = (tid + (u << 8)) << 3;
                int r = idx >> 6, c = idx & 63;
                *(uint4*)&Ks[r][c] = *(const uint4*)
                    &kbp[((size_t)bh << 16) + ((size_t)((ki << 6) + r) << 6) + c];
                *(uint4*)&Vt[r][c] = *(const uint4*)
                    &vtb[((size_t)((bh << 6) + r) << 10) + (ki << 6) + c];
            }
            __syncthreads();
            f32x4 st[4];
#pragma unroll
            for (int ct = 0; ct < 4; ct++) st[ct] = zero4;
#pragma unroll
            for (int ks = 0; ks < 2; ks++) {
#pragma unroll
                for (int ct = 0; ct < 4; ct++) {
                    short8 a = *(const short8*)
                        &Ks[(ct << 4) + l15][(ks << 5) + (quad << 3)];
                    st[ct] = __builtin_amdgcn_mfma_f32_16x16x32_bf16(
                        a, bq[ks], st[ct], 0, 0, 0);
                }
            }
            float mloc = -INFINITY;
#pragma unroll
            for (int ct = 0; ct < 4; ct++)
#pragma unroll
                for (int reg = 0; reg < 4; reg++) {
                    int c_g = (ki << 6) + (ct << 4) + (quad << 2) + reg;
                    float s = st[ct][reg] * SCALE;
                    if (c_g > r_g) s = -INFINITY;
                    st[ct][reg] = s;
                    mloc = fmaxf(mloc, s);
                }
            mloc = fmaxf(mloc, __shfl_xor(mloc, 16));
            mloc = fmaxf(mloc, __shfl_xor(mloc, 32));
            float mnew = fmaxf(m_run, mloc);
            float corr = __expf(m_run - mnew);
            m_run = mnew;
            float rsum = 0.f;
#pragma unroll
            for (int ct = 0; ct < 4; ct++) {
                u16 pk[4];
#pragma unroll
                for (int reg = 0; reg < 4; reg++) {
                    float pv = __expf(st[ct][reg] - mnew);
                    rsum += pv;
                    pk[reg] = f2bf(pv);
                }
                unsigned lo = (unsigned)pk[0] | ((unsigned)pk[1] << 16);
                unsigned hi = (unsigned)pk[2] | ((unsigned)pk[3] << 16);
                uint2 pkv; pkv.x = lo; pkv.y = hi;
                *(uint2*)&Pa[(wave << 4) + l15][(ct << 4) + (quad << 2)] = pkv;
            }
            rsum += __shfl_xor(rsum, 16);
            rsum += __shfl_xor(rsum, 32);
            l_run = l_run * corr + rsum;
            float co[4];
#pragma unroll
            for (int reg = 0; reg < 4; reg++)
                co[reg] = __shfl(corr, ((lane >> 4) << 2) + reg);
#pragma unroll
            for (int dt = 0; dt < 4; dt++)
#pragma unroll
                for (int reg = 0; reg < 4; reg++) O[dt][reg] *= co[reg];
#pragma unroll
            for (int ks = 0; ks < 2; ks++) {
                short8 ap = *(const short8*)
                    &Pa[(wave << 4) + l15][(ks << 5) + (quad << 3)];
#pragma unroll
                for (int dt = 0; dt < 4; dt++) {
                    short8 bv = *(const short8*)
                        &Vt[(dt << 4) + l15][(ks << 5) + (quad << 3)];
                    O[dt] = __builtin_amdgcn_mfma_f32_16x16x32_bf16(
                        ap, bv, O[dt], 0, 0, 0);
                }
            }
        }
        float lo4[4];
#pragma unroll
        for (int reg = 0; reg < 4; reg++)
            lo4[reg] = __shfl(l_run, ((lane >> 4) << 2) + reg);
#pragma unroll
        for (int reg = 0; reg < 4; reg++) {
            int t = (qi << 6) + (wave << 4) + (quad << 2) + reg;
            float inv = al / lo4[reg];
#pragma unroll
            for (int dt = 0; dt < 4; dt++) {
                int d = (dt << 4) + l15;
                float yl = ylin[(((size_t)bh << 10) + t) * 64 + d];
                ycomb[((size_t)((bi << 10) + t) << 10) + (h << 6) + d] =
                    O[dt][reg] * inv + (1.f - al) * yl;
            }
        }
    }
}

// ---------------------------------------------------------------------------
// K4: out-LN -> pre-LN -> block-diag mix (reversed) + 32x32 bilinear + bias
// ---------------------------------------------------------------------------
__global__ __launch_bounds__(256) void k4_proj(
    const float* __restrict__ ycomb,
    const float* __restrict__ og, const float* __restrict__ ob,
    const float* __restrict__ pg, const float* __restrict__ pb,
    const float* __restrict__ bw, const float* __restrict__ wrow,
    const float* __restrict__ wcol, const float* __restrict__ palpha,
    const float* __restrict__ pbias, float* __restrict__ out)
{
    const int tok = blockIdx.x;
    __shared__ float xb[1024];
    __shared__ float ymix[1024];
    __shared__ float zs[1024];
    __shared__ float red[8];
    const int tid = threadIdx.x;
    const int c0 = tid << 2;
    const float* yrow = ycomb + ((size_t)tok << 10);
    float4 v4 = *reinterpret_cast<const float4*>(yrow + c0);
    float v[4] = {v4.x, v4.y, v4.z, v4.w};
    float s1 = v[0] + v[1] + v[2] + v[3];
    float s2 = v[0]*v[0] + v[1]*v[1] + v[2]*v[2] + v[3]*v[3];
#pragma unroll
    for (int off = 1; off < 64; off <<= 1) {
        s1 += __shfl_xor(s1, off); s2 += __shfl_xor(s2, off);
    }
    if ((tid & 63) == 0) { red[(tid >> 6) * 2] = s1; red[(tid >> 6) * 2 + 1] = s2; }
    __syncthreads();
    s1 = red[0] + red[2] + red[4] + red[6];
    s2 = red[1] + red[3] + red[5] + red[7];
    __syncthreads();
    {
        float mean = s1 * (1.f / 1024.f);
        float var = s2 * (1.f / 1024.f) - mean * mean;
        float rstd = rsqrtf(var + 1e-5f);
#pragma unroll
        for (int q = 0; q < 4; q++)
            v[q] = (v[q] - mean) * rstd * og[c0 + q] + ob[c0 + q];
    }
    s1 = v[0] + v[1] + v[2] + v[3];
    s2 = v[0]*v[0] + v[1]*v[1] + v[2]*v[2] + v[3]*v[3];
#pragma unroll
    for (int off = 1; off < 64; off <<= 1) {
        s1 += __shfl_xor(s1, off); s2 += __shfl_xor(s2, off);
    }
    if ((tid & 63) == 0) { red[(tid >> 6) * 2] = s1; red[(tid >> 6) * 2 + 1] = s2; }
    __syncthreads();
    s1 = red[0] + red[2] + red[4] + red[6];
    s2 = red[1] + red[3] + red[5] + red[7];
    __syncthreads();
    {
        float mean = s1 * (1.f / 1024.f);
        float var = s2 * (1.f / 1024.f) - mean * mean;
        float rstd = rsqrtf(var + 1e-5f);
#pragma unroll
        for (int q = 0; q < 4; q++)
            xb[c0 + q] = (v[q] - mean) * rstd * pg[c0 + q] + pb[c0 + q];
    }
    __syncthreads();
    {
        int g = tid >> 2;
        int jb = (tid & 3) << 2;
        float acc[4] = {0.f, 0.f, 0.f, 0.f};
        const float* xg = &xb[g << 4];
        const float* bwg = &bw[g << 8];
        for (int i = 0; i < 16; i++) {
            float xv = xg[i];
#pragma unroll
            for (int q = 0; q < 4; q++) acc[q] += xv * bwg[i * 16 + jb + q];
        }
#pragma unroll
        for (int q = 0; q < 4; q++) ymix[(g << 4) + jb + q] = acc[q];
    }
    {
        int i_ = tid >> 3;
        int ccb = (tid << 2) & 31;
        float acc[4] = {0.f, 0.f, 0.f, 0.f};
        const float* xg = &xb[i_ << 5];
        for (int j = 0; j < 32; j++) {
            float xv = xg[j];
#pragma unroll
            for (int q = 0; q < 4; q++) acc[q] += xv * wcol[(j << 5) + ccb + q];
        }
#pragma unroll
        for (int q = 0; q < 4; q++) zs[(i_ << 5) + ccb + q] = acc[q];
    }
    __syncthreads();
    {
        int i_ = tid >> 3;
        int rb = (tid << 2) & 31;
        const float* z1row = &zs[i_ << 5];
        const float al = palpha[0];
        float vout[4];
#pragma unroll
        for (int q = 0; q < 4; q++) {
            float acc = 0.f;
            const float* wr = &wrow[(rb + q) << 5];
            for (int cc = 0; cc < 32; cc++) acc += z1row[cc] * wr[cc];
            int ch = (i_ << 5) + rb + q;
            vout[q] = ymix[1023 - ch] + al * acc + pbias[ch];
        }
        float4 o = {vout[0], vout[1], vout[2], vout[3]};
        *reinterpret_cast<float4*>(&out[((size_t)tok << 10) + (i_ << 5) + rb]) = o;
    }
}

// ---------------------------------------------------------------------------
extern "C" void kernel_launch(void* const* d_in, const int* in_sizes, int n_in,
                              void* d_out, int out_size, void* d_ws, size_t ws_size,
                              hipStream_t stream) {
    const float* x   = (const float*)d_in[0];
    const float* w   = (const float*)d_in[1];
    const float* wb  = (const float*)d_in[2];
    const float* fg  = (const float*)d_in[3];
    const float* ang = (const float*)d_in[4];
    const float* anb = (const float*)d_in[5];
    const float* ong = (const float*)d_in[6];
    const float* onb = (const float*)d_in[7];
    const float* ppg = (const float*)d_in[8];
    const float* ppb = (const float*)d_in[9];
    const float* pbw = (const float*)d_in[10];
    const float* pwr = (const float*)d_in[11];
    const float* pwc = (const float*)d_in[12];
    const float* pal = (const float*)d_in[13];
    const float* pbi = (const float*)d_in[14];

    uint8_t* p = (uint8_t*)d_ws;
    u16* xbf = (u16*)p;  p += (size_t)2048 * 1024 * 2;
    u16* wbf = (u16*)p;  p += (size_t)3072 * 1024 * 2;
    u16* qb  = (u16*)p;  p += (size_t)32 * 1024 * 64 * 2;
    u16* kb  = (u16*)p;  p += (size_t)32 * 1024 * 64 * 2;
    u16* vb  = (u16*)p;  p += (size_t)32 * 1024 * 64 * 2;
    u16* vtb = (u16*)p;  p += (size_t)32 * 1024 * 64 * 2;
    float* ylin  = (float*)p;  p += (size_t)32 * 1024 * 64 * 4;
    float* ycomb = (float*)p;  p += (size_t)32 * 1024 * 64 * 4;
    float* Sg    = (float*)p;  p += (size_t)32 * 16 * 4096 * 4;
    float* svg   = (float*)p;  p += (size_t)32 * 16 * 64 * 4;
    float* out   = (float*)d_out;

    k0_cast<<<2048, 256, 0, stream>>>(x, xbf, 524288);
    k0_cast<<<3072, 256, 0, stream>>>(w, wbf, 786432);
    k1_qkv<<<dim3(24, 16), 256, 0, stream>>>(xbf, wbf, wb, qb, kb, vb);
    k_vt<<<dim3(16, 32), 256, 0, stream>>>(vb, vtb);
    k2a_chunkkv<<<dim3(16, 32), 256, 0, stream>>>(kb, vb, Sg, svg);
    k2s_scan<<<521, 256, 0, stream>>>(Sg, svg);
    k2b_lin<<<dim3(16, 32), 256, 0, stream>>>(qb, kb, vb, Sg, svg, ang, anb, ylin);
    k3_sharp<<<dim3(8, 32), 256, 0, stream>>>(qb, kb, vtb, ylin, fg, ycomb);
    k4_proj<<<2048, 256, 0, stream>>>(ycomb, ong, onb, ppg, ppb, pbw, pwr, pwc, pal, pbi, out);
}

// Round 4
// 225.481 us; speedup vs baseline: 2.6430x; 1.0977x over previous
//
#include <hip/hip_runtime.h>
#include <math.h>

constexpr int T_ = 1024;
constexpr int C_ = 1024;
constexpr int H_ = 16;
constexpr int D_ = 64;
#define SCALE 0.125f

typedef unsigned short u16;
typedef __attribute__((ext_vector_type(8))) short short8;
typedef __attribute__((ext_vector_type(4))) float f32x4;

__device__ __forceinline__ float elu1(float x) { return x > 0.f ? x + 1.f : expf(x); }

__device__ __forceinline__ u16 f2bf(float f) {
    union { float f; unsigned u; } c; c.f = f;
    unsigned r = (c.u + 0x7fffu + ((c.u >> 16) & 1u)) >> 16;
    return (u16)r;
}
__device__ __forceinline__ float bf2f(u16 u) {
    union { unsigned u; float f; } c; c.u = (unsigned)u << 16;
    return c.f;
}

#define GLL16(g, l)                                                            \
    __builtin_amdgcn_global_load_lds(                                          \
        (const __attribute__((address_space(1))) void*)(g),                    \
        (__attribute__((address_space(3))) void*)(l), 16, 0, 0)

// ---------------------------------------------------------------------------
// K0: fp32 -> bf16 cast
// ---------------------------------------------------------------------------
__global__ __launch_bounds__(256) void k0_cast(
    const float* __restrict__ s, u16* __restrict__ d, int n4)
{
    int i = blockIdx.x * 256 + threadIdx.x;
    if (i < n4) {
        float4 v = reinterpret_cast<const float4*>(s)[i];
        ushort4 o;
        o.x = f2bf(v.x); o.y = f2bf(v.y); o.z = f2bf(v.z); o.w = f2bf(v.w);
        reinterpret_cast<ushort4*>(d)[i] = o;
    }
}

// ---------------------------------------------------------------------------
// K1: bf16 MFMA GEMM  qkv = x @ W^T + b  (M=2048,N=3072,K=1024)
// ---------------------------------------------------------------------------
__global__ __launch_bounds__(256) void k1_qkv(
    const u16* __restrict__ xbf, const u16* __restrict__ wbf,
    const float* __restrict__ bias,
    u16* __restrict__ qb, u16* __restrict__ kb, u16* __restrict__ vb)
{
    __shared__ __align__(16) u16 As[128 * 32];
    __shared__ __align__(16) u16 Bs[128 * 32];
    const int tid = threadIdx.x;
    const int wave = tid >> 6, lane = tid & 63;
    const int quad = lane >> 4, l15 = lane & 15;
    const int m0 = blockIdx.y << 7, n0 = blockIdx.x << 7;
    const int wm = (wave >> 1) << 6, wn = (wave & 1) << 6;

    const int rowS = (wave << 5) + (lane >> 2);
    const int seg8 = (lane & 3) << 3;
    const u16* gA1 = xbf + (size_t)(m0 + rowS) * 1024 + seg8;
    const u16* gA2 = gA1 + (size_t)16 * 1024;
    const u16* gB1 = wbf + (size_t)(n0 + rowS) * 1024 + seg8;
    const u16* gB2 = gB1 + (size_t)16 * 1024;
    u16* lA1 = &As[(wave << 5) * 32];
    u16* lA2 = lA1 + 16 * 32;
    u16* lB1 = &Bs[(wave << 5) * 32];
    u16* lB2 = lB1 + 16 * 32;

    f32x4 zero4 = {0.f, 0.f, 0.f, 0.f};
    f32x4 acc[4][4];
#pragma unroll
    for (int i = 0; i < 4; i++)
#pragma unroll
        for (int j = 0; j < 4; j++) acc[i][j] = zero4;

    for (int k0 = 0; k0 < 1024; k0 += 32) {
        GLL16(gA1 + k0, lA1);
        GLL16(gA2 + k0, lA2);
        GLL16(gB1 + k0, lB1);
        GLL16(gB2 + k0, lB2);
        __syncthreads();
        short8 a[4], b[4];
#pragma unroll
        for (int mi = 0; mi < 4; mi++)
            a[mi] = *(const short8*)&As[(wm + mi * 16 + l15) * 32 + (quad << 3)];
#pragma unroll
        for (int ni = 0; ni < 4; ni++)
            b[ni] = *(const short8*)&Bs[(wn + ni * 16 + l15) * 32 + (quad << 3)];
#pragma unroll
        for (int mi = 0; mi < 4; mi++)
#pragma unroll
            for (int ni = 0; ni < 4; ni++)
                acc[mi][ni] = __builtin_amdgcn_mfma_f32_16x16x32_bf16(
                    a[mi], b[ni], acc[mi][ni], 0, 0, 0);
        __syncthreads();
    }
#pragma unroll
    for (int ni = 0; ni < 4; ni++) {
        int n_g = n0 + wn + ni * 16 + l15;
        int which = n_g >> 10;
        int h = (n_g >> 6) & 15;
        int d = n_g & 63;
        u16* dst = (which == 0) ? qb : (which == 1) ? kb : vb;
        float bz = bias[n_g];
#pragma unroll
        for (int mi = 0; mi < 4; mi++) {
#pragma unroll
            for (int reg = 0; reg < 4; reg++) {
                int m = m0 + wm + mi * 16 + (quad << 2) + reg;
                int bi = m >> 10, t = m & 1023;
                dst[((size_t)(bi * 16 + h) << 16) + ((size_t)t << 6) + d] =
                    f2bf(acc[mi][ni][reg] + bz);
            }
        }
    }
}

// ---------------------------------------------------------------------------
// K_VT: vtb[bh][d][t] = vb[bh][t][d]
// ---------------------------------------------------------------------------
__global__ __launch_bounds__(256) void k_vt(
    const u16* __restrict__ vb, u16* __restrict__ vtb)
{
    const int t0 = blockIdx.x << 6, bh = blockIdx.y;
    __shared__ __align__(16) u16 Vs[64][72];
    const int tid = threadIdx.x;
#pragma unroll
    for (int u = 0; u < 2; u++) {
        int idx = (tid + (u << 8)) << 3;
        int r = idx >> 6, c = idx & 63;
        *(uint4*)&Vs[r][c] =
            *(const uint4*)&vb[((size_t)bh << 16) + ((size_t)(t0 + r) << 6) + c];
    }
    __syncthreads();
#pragma unroll
    for (int u = 0; u < 2; u++) {
        int idx = (tid + (u << 8)) << 3;
        int dd = idx >> 6, c0 = idx & 63;
        union { u16 s[8]; uint4 v; } tmp;
#pragma unroll
        for (int j = 0; j < 8; j++) tmp.s[j] = Vs[c0 + j][dd];
        *(uint4*)&vtb[((size_t)((bh << 6) + dd) << 10) + t0 + c0] = tmp.v;
    }
}

// ---------------------------------------------------------------------------
// K2a: per-(bh,chunk) KV state
// ---------------------------------------------------------------------------
__global__ __launch_bounds__(256) void k2a_chunkkv(
    const u16* __restrict__ kb, const u16* __restrict__ vb,
    float* __restrict__ Sg, float* __restrict__ svg)
{
    const int chunk = blockIdx.x, bh = blockIdx.y;
    const int t0 = chunk << 6;
    __shared__ float Ks[64][65];
    __shared__ float Vs[64][65];
    const int tid = threadIdx.x;
    const u16* kp = kb + (size_t)bh * T_ * D_;
    const u16* vp = vb + (size_t)bh * T_ * D_;
#pragma unroll
    for (int ii = 0; ii < 16; ii++) {
        int idx = tid + (ii << 8);
        int row = idx >> 6, col = idx & 63;
        Ks[row][col] = elu1(bf2f(kp[(size_t)(t0 + row) * D_ + col]) * SCALE);
        Vs[row][col] = bf2f(vp[(size_t)(t0 + row) * D_ + col]);
    }
    __syncthreads();
    const int tr = tid >> 4, tc = tid & 15;
    const int d0 = tr * 4, e0 = tc * 4;
    float acc[4][4] = {};
    for (int c = 0; c < 64; c++) {
        float a[4], b[4];
#pragma unroll
        for (int i = 0; i < 4; i++) a[i] = Ks[c][d0 + i];
#pragma unroll
        for (int j = 0; j < 4; j++) b[j] = Vs[c][e0 + j];
#pragma unroll
        for (int i = 0; i < 4; i++)
#pragma unroll
            for (int j = 0; j < 4; j++) acc[i][j] += a[i] * b[j];
    }
    float* so = Sg + ((size_t)bh * 16 + chunk) * 4096;
#pragma unroll
    for (int i = 0; i < 4; i++) {
        float4 o = {acc[i][0], acc[i][1], acc[i][2], acc[i][3]};
        *reinterpret_cast<float4*>(&so[(d0 + i) * 64 + e0]) = o;
    }
    if (tc == 0) {
#pragma unroll
        for (int i = 0; i < 4; i++) {
            float s = 0.f;
            for (int c = 0; c < 64; c++) s += Ks[c][d0 + i];
            svg[((size_t)bh * 16 + chunk) * 64 + d0 + i] = s;
        }
    }
}

// ---------------------------------------------------------------------------
// K2s: in-place exclusive prefix scan over the chunk dim of Sg (and svg).
// ---------------------------------------------------------------------------
__global__ __launch_bounds__(256) void k2s_scan(
    float* __restrict__ Sg, float* __restrict__ svg)
{
    int gid = blockIdx.x * 256 + threadIdx.x;
    if (gid < 131072) {
        int bh = gid >> 12, e = gid & 4095;
        float* base = Sg + ((size_t)bh << 16) + e;
        float v[16];
#pragma unroll
        for (int c = 0; c < 16; c++) v[c] = base[(size_t)c << 12];
        float run = 0.f;
#pragma unroll
        for (int c = 0; c < 16; c++) {
            base[(size_t)c << 12] = run;
            run += v[c];
        }
    } else if (gid < 131072 + 2048) {
        int g2 = gid - 131072;
        int bh = g2 >> 6, d = g2 & 63;
        float* base = svg + ((size_t)bh << 10) + d;
        float v[16];
#pragma unroll
        for (int c = 0; c < 16; c++) v[c] = base[c << 6];
        float run = 0.f;
#pragma unroll
        for (int c = 0; c < 16; c++) {
            base[c << 6] = run;
            run += v[c];
        }
    }
}

// ---------------------------------------------------------------------------
// K2b: linear attention per chunk; prefix state direct float4 load.
// ---------------------------------------------------------------------------
__global__ __launch_bounds__(256) void k2b_lin(
    const u16* __restrict__ qbp, const u16* __restrict__ kbp,
    const u16* __restrict__ vbp,
    const float* __restrict__ Sg, const float* __restrict__ svg,
    const float* __restrict__ ang, const float* __restrict__ anb,
    float* __restrict__ ylin)
{
    const int chunk = blockIdx.x, bh = blockIdx.y;
    const int t0 = chunk << 6;
    __shared__ __align__(16) float bufA[64][68];
    __shared__ float bufQ[64][65];
    __shared__ float bufK[64][65];
    __shared__ float svec[64];
    const int tid = threadIdx.x;
    const u16* qp = qbp + (size_t)bh * T_ * D_;
    const u16* kp = kbp + (size_t)bh * T_ * D_;
    const u16* vp = vbp + (size_t)bh * T_ * D_;
    const float* sp = Sg + (((size_t)bh * 16 + chunk) << 12);
#pragma unroll
    for (int u = 0; u < 4; u++) {
        int idx = (tid + (u << 8)) << 2;
        int dd = idx >> 6, e = idx & 63;
        *(float4*)&bufA[dd][e] = *(const float4*)&sp[idx];
    }
    if (tid < 64) svec[tid] = svg[(((size_t)bh * 16 + chunk) << 6) + tid];
#pragma unroll
    for (int ii = 0; ii < 16; ii++) {
        int idx = tid + (ii << 8);
        int row = idx >> 6, col = idx & 63;
        bufQ[col][row] = elu1(bf2f(qp[(size_t)(t0 + row) * D_ + col]) * SCALE);
    }
    __syncthreads();
    const int tr = tid >> 4, tc = tid & 15;
    const int r0 = tr * 4, c0 = tc * 4;
    float N[4][4] = {};
    float pden[4];
    for (int dd = 0; dd < 64; dd++) {
        float a[4], b[4];
#pragma unroll
        for (int i = 0; i < 4; i++) a[i] = bufQ[dd][r0 + i];
#pragma unroll
        for (int j = 0; j < 4; j++) b[j] = bufA[dd][c0 + j];
#pragma unroll
        for (int i = 0; i < 4; i++)
#pragma unroll
            for (int j = 0; j < 4; j++) N[i][j] += a[i] * b[j];
    }
#pragma unroll
    for (int i = 0; i < 4; i++) {
        float s = 0.f;
#pragma unroll
        for (int j = 0; j < 4; j++) s += bufQ[c0 + j][r0 + i] * svec[c0 + j];
        pden[i] = s;
    }
    __syncthreads();
#pragma unroll
    for (int ii = 0; ii < 16; ii++) {
        int idx = tid + (ii << 8);
        int row = idx >> 6, col = idx & 63;
        bufK[col][row] = elu1(bf2f(kp[(size_t)(t0 + row) * D_ + col]) * SCALE);
        bufA[row][col] = bf2f(vp[(size_t)(t0 + row) * D_ + col]);
    }
    __syncthreads();
    float sc[4][4] = {};
    for (int dd = 0; dd < 64; dd++) {
        float a[4], b[4];
#pragma unroll
        for (int i = 0; i < 4; i++) a[i] = bufQ[dd][r0 + i];
#pragma unroll
        for (int j = 0; j < 4; j++) b[j] = bufK[dd][c0 + j];
#pragma unroll
        for (int i = 0; i < 4; i++)
#pragma unroll
            for (int j = 0; j < 4; j++) sc[i][j] += a[i] * b[j];
    }
    __syncthreads();
#pragma unroll
    for (int i = 0; i < 4; i++) {
        float s = 0.f;
#pragma unroll
        for (int j = 0; j < 4; j++) {
            float pv = ((c0 + j) <= (r0 + i)) ? sc[i][j] : 0.f;
            bufQ[c0 + j][r0 + i] = pv;
            s += pv;
        }
        pden[i] += s;
    }
#pragma unroll
    for (int i = 0; i < 4; i++) {
#pragma unroll
        for (int off = 1; off < 16; off <<= 1)
            pden[i] += __shfl_xor(pden[i], off);
    }
    __syncthreads();
    for (int c = 0; c < 64; c++) {
        float a[4], b[4];
#pragma unroll
        for (int i = 0; i < 4; i++) a[i] = bufQ[c][r0 + i];
#pragma unroll
        for (int j = 0; j < 4; j++) b[j] = bufA[c][c0 + j];
#pragma unroll
        for (int i = 0; i < 4; i++)
#pragma unroll
            for (int j = 0; j < 4; j++) N[i][j] += a[i] * b[j];
    }
    float yv[4][4], s1[4], s2[4];
#pragma unroll
    for (int i = 0; i < 4; i++) {
        float inv = 1.f / (pden[i] + 1e-4f);
        s1[i] = 0.f; s2[i] = 0.f;
#pragma unroll
        for (int j = 0; j < 4; j++) {
            float t = N[i][j] * inv;
            yv[i][j] = t; s1[i] += t; s2[i] += t * t;
        }
    }
#pragma unroll
    for (int i = 0; i < 4; i++) {
#pragma unroll
        for (int off = 1; off < 16; off <<= 1) {
            s1[i] += __shfl_xor(s1[i], off);
            s2[i] += __shfl_xor(s2[i], off);
        }
    }
#pragma unroll
    for (int i = 0; i < 4; i++) {
        float mean = s1[i] * (1.f / 64.f);
        float var = s2[i] * (1.f / 64.f) - mean * mean;
        float rstd = rsqrtf(var + 1e-5f);
        float4 o;
        o.x = (yv[i][0] - mean) * rstd * ang[c0 + 0] + anb[c0 + 0];
        o.y = (yv[i][1] - mean) * rstd * ang[c0 + 1] + anb[c0 + 1];
        o.z = (yv[i][2] - mean) * rstd * ang[c0 + 2] + anb[c0 + 2];
        o.w = (yv[i][3] - mean) * rstd * ang[c0 + 3] + anb[c0 + 3];
        *reinterpret_cast<float4*>(
            &ylin[((size_t)bh * T_ + t0 + r0 + i) * D_ + c0]) = o;
    }
}

// ---------------------------------------------------------------------------
// K3: MFMA flash attention (S^T = K.Q^T trick)
// ---------------------------------------------------------------------------
__global__ __launch_bounds__(256) void k3_sharp(
    const u16* __restrict__ qbp, const u16* __restrict__ kbp,
    const u16* __restrict__ vtb,
    const float* __restrict__ ylin, const float* __restrict__ fg,
    float* __restrict__ ycomb)
{
    const int bh = blockIdx.y;
    __shared__ __align__(16) u16 Qs[64][72];
    __shared__ __align__(16) u16 Ks[64][72];
    __shared__ __align__(16) u16 Vt[64][72];
    __shared__ __align__(16) u16 Pa[64][72];
    const int tid = threadIdx.x;
    const int wave = tid >> 6, lane = tid & 63;
    const int quad = lane >> 4, l15 = lane & 15;
    const float al = 1.f / (1.f + expf(-fg[0]));
    const int bi = bh >> 4, h = bh & 15;
    const f32x4 zero4 = {0.f, 0.f, 0.f, 0.f};

    for (int phase = 0; phase < 2; phase++) {
        const int qi = phase == 0 ? (int)blockIdx.x : 15 - (int)blockIdx.x;
        __syncthreads();
#pragma unroll
        for (int u = 0; u < 2; u++) {
            int idx = (tid + (u << 8)) << 3;
            int r = idx >> 6, c = idx & 63;
            *(uint4*)&Qs[r][c] = *(const uint4*)
                &qbp[((size_t)bh << 16) + ((size_t)((qi << 6) + r) << 6) + c];
        }
        __syncthreads();
        short8 bq[2];
        bq[0] = *(const short8*)&Qs[(wave << 4) + l15][(quad << 3)];
        bq[1] = *(const short8*)&Qs[(wave << 4) + l15][32 + (quad << 3)];
        f32x4 O[4];
#pragma unroll
        for (int dt = 0; dt < 4; dt++) O[dt] = zero4;
        float m_run = -INFINITY, l_run = 0.f;
        const int r_g = (qi << 6) + (wave << 4) + l15;

        for (int ki = 0; ki <= qi; ki++) {
            __syncthreads();
#pragma unroll
            for (int u = 0; u < 2; u++) {
                int idx = (tid + (u << 8)) << 3;
                int r = idx >> 6, c = idx & 63;
                *(uint4*)&Ks[r][c] = *(const uint4*)
                    &kbp[((size_t)bh << 16) + ((size_t)((ki << 6) + r) << 6) + c];
                *(uint4*)&Vt[r][c] = *(const uint4*)
                    &vtb[((size_t)((bh << 6) + r) << 10) + (ki << 6) + c];
            }
            __syncthreads();
            f32x4 st[4];
#pragma unroll
            for (int ct = 0; ct < 4; ct++) st[ct] = zero4;
#pragma unroll
            for (int ks = 0; ks < 2; ks++) {
#pragma unroll
                for (int ct = 0; ct < 4; ct++) {
                    short8 a = *(const short8*)
                        &Ks[(ct << 4) + l15][(ks << 5) + (quad << 3)];
                    st[ct] = __builtin_amdgcn_mfma_f32_16x16x32_bf16(
                        a, bq[ks], st[ct], 0, 0, 0);
                }
            }
            float mloc = -INFINITY;
#pragma unroll
            for (int ct = 0; ct < 4; ct++)
#pragma unroll
                for (int reg = 0; reg < 4; reg++) {
                    int c_g = (ki << 6) + (ct << 4) + (quad << 2) + reg;
                    float s = st[ct][reg] * SCALE;
                    if (c_g > r_g) s = -INFINITY;
                    st[ct][reg] = s;
                    mloc = fmaxf(mloc, s);
                }
            mloc = fmaxf(mloc, __shfl_xor(mloc, 16));
            mloc = fmaxf(mloc, __shfl_xor(mloc, 32));
            float mnew = fmaxf(m_run, mloc);
            float corr = __expf(m_run - mnew);
            m_run = mnew;
            float rsum = 0.f;
#pragma unroll
            for (int ct = 0; ct < 4; ct++) {
                u16 pk[4];
#pragma unroll
                for (int reg = 0; reg < 4; reg++) {
                    float pv = __expf(st[ct][reg] - mnew);
                    rsum += pv;
                    pk[reg] = f2bf(pv);
                }
                unsigned lo = (unsigned)pk[0] | ((unsigned)pk[1] << 16);
                unsigned hi = (unsigned)pk[2] | ((unsigned)pk[3] << 16);
                uint2 pkv; pkv.x = lo; pkv.y = hi;
                *(uint2*)&Pa[(wave << 4) + l15][(ct << 4) + (quad << 2)] = pkv;
            }
            rsum += __shfl_xor(rsum, 16);
            rsum += __shfl_xor(rsum, 32);
            l_run = l_run * corr + rsum;
            float co[4];
#pragma unroll
            for (int reg = 0; reg < 4; reg++)
                co[reg] = __shfl(corr, ((lane >> 4) << 2) + reg);
#pragma unroll
            for (int dt = 0; dt < 4; dt++)
#pragma unroll
                for (int reg = 0; reg < 4; reg++) O[dt][reg] *= co[reg];
#pragma unroll
            for (int ks = 0; ks < 2; ks++) {
                short8 ap = *(const short8*)
                    &Pa[(wave << 4) + l15][(ks << 5) + (quad << 3)];
#pragma unroll
                for (int dt = 0; dt < 4; dt++) {
                    short8 bv = *(const short8*)
                        &Vt[(dt << 4) + l15][(ks << 5) + (quad << 3)];
                    O[dt] = __builtin_amdgcn_mfma_f32_16x16x32_bf16(
                        ap, bv, O[dt], 0, 0, 0);
                }
            }
        }
        float lo4[4];
#pragma unroll
        for (int reg = 0; reg < 4; reg++)
            lo4[reg] = __shfl(l_run, ((lane >> 4) << 2) + reg);
#pragma unroll
        for (int reg = 0; reg < 4; reg++) {
            int t = (qi << 6) + (wave << 4) + (quad << 2) + reg;
            float inv = al / lo4[reg];
#pragma unroll
            for (int dt = 0; dt < 4; dt++) {
                int d = (dt << 4) + l15;
                float yl = ylin[(((size_t)bh << 10) + t) * 64 + d];
                ycomb[((size_t)((bi << 10) + t) << 10) + (h << 6) + d] =
                    O[dt][reg] * inv + (1.f - al) * yl;
            }
        }
    }
}

// ---------------------------------------------------------------------------
// K4m: Mg[j][r] = alpha * sum_c wcol[j][c]*wrow[r][c]   (one block)
// ---------------------------------------------------------------------------
__global__ __launch_bounds__(256) void k4m(
    const float* __restrict__ wcol, const float* __restrict__ wrow,
    const float* __restrict__ palpha, float* __restrict__ Mg)
{
    const int tid = threadIdx.x;
    const int j = tid >> 3, r0 = (tid & 7) << 2;
    const float al = palpha[0];
    float acc[4] = {0.f, 0.f, 0.f, 0.f};
    for (int c = 0; c < 32; c++) {
        float wc = wcol[(j << 5) + c];
#pragma unroll
        for (int q = 0; q < 4; q++) acc[q] += wc * wrow[((r0 + q) << 5) + c];
    }
    float4 o = {al * acc[0], al * acc[1], al * acc[2], al * acc[3]};
    *reinterpret_cast<float4*>(&Mg[(j << 5) + r0]) = o;
}

// ---------------------------------------------------------------------------
// K4: out-LN -> pre-LN -> block-diag mix (reversed) + folded bilinear + bias.
// wcol@wrow^T folded into Mg (alpha included). Each thread produces its 4
// output channels directly; no ymix/zs LDS arrays. All weight loads float4.
// ---------------------------------------------------------------------------
__global__ __launch_bounds__(256) void k4_proj(
    const float* __restrict__ ycomb,
    const float* __restrict__ og, const float* __restrict__ ob,
    const float* __restrict__ pg, const float* __restrict__ pb,
    const float* __restrict__ bw, const float* __restrict__ Mg,
    const float* __restrict__ pbias, float* __restrict__ out)
{
    const int tok = blockIdx.x;
    __shared__ float xb[1024];
    __shared__ float red[8];
    const int tid = threadIdx.x;
    const int c0 = tid << 2;
    const float* yrow = ycomb + ((size_t)tok << 10);
    float4 v4 = *reinterpret_cast<const float4*>(yrow + c0);
    float v[4] = {v4.x, v4.y, v4.z, v4.w};
    // LN1 (out_norm)
    float s1 = v[0] + v[1] + v[2] + v[3];
    float s2 = v[0]*v[0] + v[1]*v[1] + v[2]*v[2] + v[3]*v[3];
#pragma unroll
    for (int off = 1; off < 64; off <<= 1) {
        s1 += __shfl_xor(s1, off); s2 += __shfl_xor(s2, off);
    }
    if ((tid & 63) == 0) { red[(tid >> 6) * 2] = s1; red[(tid >> 6) * 2 + 1] = s2; }
    __syncthreads();
    s1 = red[0] + red[2] + red[4] + red[6];
    s2 = red[1] + red[3] + red[5] + red[7];
    __syncthreads();
    {
        float mean = s1 * (1.f / 1024.f);
        float var = s2 * (1.f / 1024.f) - mean * mean;
        float rstd = rsqrtf(var + 1e-5f);
#pragma unroll
        for (int q = 0; q < 4; q++)
            v[q] = (v[q] - mean) * rstd * og[c0 + q] + ob[c0 + q];
    }
    // LN2 (proj_pre)
    s1 = v[0] + v[1] + v[2] + v[3];
    s2 = v[0]*v[0] + v[1]*v[1] + v[2]*v[2] + v[3]*v[3];
#pragma unroll
    for (int off = 1; off < 64; off <<= 1) {
        s1 += __shfl_xor(s1, off); s2 += __shfl_xor(s2, off);
    }
    if ((tid & 63) == 0) { red[(tid >> 6) * 2] = s1; red[(tid >> 6) * 2 + 1] = s2; }
    __syncthreads();
    s1 = red[0] + red[2] + red[4] + red[6];
    s2 = red[1] + red[3] + red[5] + red[7];
    {
        float mean = s1 * (1.f / 1024.f);
        float var = s2 * (1.f / 1024.f) - mean * mean;
        float rstd = rsqrtf(var + 1e-5f);
#pragma unroll
        for (int q = 0; q < 4; q++)
            xb[c0 + q] = (v[q] - mean) * rstd * pg[c0 + q] + pb[c0 + q];
    }
    __syncthreads();
    // block-diag mix: thread owns ymix[g*16 + jb + 0..3]
    const int g = tid >> 2;
    const int jb = (tid & 3) << 2;
    float acc[4] = {0.f, 0.f, 0.f, 0.f};
    {
        const float* xg = &xb[g << 4];
        const float* bwg = &bw[(g << 8) + jb];
        for (int i = 0; i < 16; i++) {
            float xv = xg[i];
            float4 wv = *reinterpret_cast<const float4*>(&bwg[i << 4]);
            acc[0] += xv * wv.x; acc[1] += xv * wv.y;
            acc[2] += xv * wv.z; acc[3] += xv * wv.w;
        }
    }
    // output channels C0..C0+3, where C0 = (63-g)*16 + 12-jb (reversal folded)
    const int C0 = ((63 - g) << 4) + 12 - jb;
    const int i2 = C0 >> 5, r0 = C0 & 31;
    float z2[4] = {0.f, 0.f, 0.f, 0.f};
    {
        const float* xg = &xb[i2 << 5];
        const float* mg = &Mg[r0];
        for (int j = 0; j < 32; j++) {
            float xv = xg[j];
            float4 mv = *reinterpret_cast<const float4*>(&mg[j << 5]);
            z2[0] += xv * mv.x; z2[1] += xv * mv.y;
            z2[2] += xv * mv.z; z2[3] += xv * mv.w;
        }
    }
    float4 bz = *reinterpret_cast<const float4*>(&pbias[C0]);
    float4 o;
    o.x = acc[3] + z2[0] + bz.x;
    o.y = acc[2] + z2[1] + bz.y;
    o.z = acc[1] + z2[2] + bz.z;
    o.w = acc[0] + z2[3] + bz.w;
    *reinterpret_cast<float4*>(&out[((size_t)tok << 10) + C0]) = o;
}

// ---------------------------------------------------------------------------
extern "C" void kernel_launch(void* const* d_in, const int* in_sizes, int n_in,
                              void* d_out, int out_size, void* d_ws, size_t ws_size,
                              hipStream_t stream) {
    const float* x   = (const float*)d_in[0];
    const float* w   = (const float*)d_in[1];
    const float* wb  = (const float*)d_in[2];
    const float* fg  = (const float*)d_in[3];
    const float* ang = (const float*)d_in[4];
    const float* anb = (const float*)d_in[5];
    const float* ong = (const float*)d_in[6];
    const float* onb = (const float*)d_in[7];
    const float* ppg = (const float*)d_in[8];
    const float* ppb = (const float*)d_in[9];
    const float* pbw = (const float*)d_in[10];
    const float* pwr = (const float*)d_in[11];
    const float* pwc = (const float*)d_in[12];
    const float* pal = (const float*)d_in[13];
    const float* pbi = (const float*)d_in[14];

    uint8_t* p = (uint8_t*)d_ws;
    u16* xbf = (u16*)p;  p += (size_t)2048 * 1024 * 2;
    u16* wbf = (u16*)p;  p += (size_t)3072 * 1024 * 2;
    u16* qb  = (u16*)p;  p += (size_t)32 * 1024 * 64 * 2;
    u16* kb  = (u16*)p;  p += (size_t)32 * 1024 * 64 * 2;
    u16* vb  = (u16*)p;  p += (size_t)32 * 1024 * 64 * 2;
    u16* vtb = (u16*)p;  p += (size_t)32 * 1024 * 64 * 2;
    float* ylin  = (float*)p;  p += (size_t)32 * 1024 * 64 * 4;
    float* ycomb = (float*)p;  p += (size_t)32 * 1024 * 64 * 4;
    float* Sg    = (float*)p;  p += (size_t)32 * 16 * 4096 * 4;
    float* svg   = (float*)p;  p += (size_t)32 * 16 * 64 * 4;
    float* Mg    = (float*)p;  p += (size_t)32 * 32 * 4;
    float* out   = (float*)d_out;

    k0_cast<<<2048, 256, 0, stream>>>(x, xbf, 524288);
    k0_cast<<<3072, 256, 0, stream>>>(w, wbf, 786432);
    k4m<<<1, 256, 0, stream>>>(pwc, pwr, pal, Mg);
    k1_qkv<<<dim3(24, 16), 256, 0, stream>>>(xbf, wbf, wb, qb, kb, vb);
    k_vt<<<dim3(16, 32), 256, 0, stream>>>(vb, vtb);
    k2a_chunkkv<<<dim3(16, 32), 256, 0, stream>>>(kb, vb, Sg, svg);
    k2s_scan<<<521, 256, 0, stream>>>(Sg, svg);
    k2b_lin<<<dim3(16, 32), 256, 0, stream>>>(qb, kb, vb, Sg, svg, ang, anb, ylin);
    k3_sharp<<<dim3(8, 32), 256, 0, stream>>>(qb, kb, vtb, ylin, fg, ycomb);
    k4_proj<<<2048, 256, 0, stream>>>(ycomb, ong, onb, ppg, ppb, pbw, Mg, pbi, out);
}

// Round 5
// 216.385 us; speedup vs baseline: 2.7541x; 1.0420x over previous
//
#include <hip/hip_runtime.h>
#include <math.h>

constexpr int T_ = 1024;
constexpr int C_ = 1024;
constexpr int H_ = 16;
constexpr int D_ = 64;
#define SCALE 0.125f

typedef unsigned short u16;
typedef __attribute__((ext_vector_type(8))) short short8;
typedef __attribute__((ext_vector_type(4))) float f32x4;

__device__ __forceinline__ float elu1(float x) { return x > 0.f ? x + 1.f : expf(x); }

__device__ __forceinline__ u16 f2bf(float f) {
    union { float f; unsigned u; } c; c.f = f;
    unsigned r = (c.u + 0x7fffu + ((c.u >> 16) & 1u)) >> 16;
    return (u16)r;
}
__device__ __forceinline__ float bf2f(u16 u) {
    union { unsigned u; float f; } c; c.u = (unsigned)u << 16;
    return c.f;
}

#define GLL16(g, l)                                                            \
    __builtin_amdgcn_global_load_lds(                                          \
        (const __attribute__((address_space(1))) void*)(g),                    \
        (__attribute__((address_space(3))) void*)(l), 16, 0, 0)

// ---------------------------------------------------------------------------
// K0: fp32 -> bf16 cast
// ---------------------------------------------------------------------------
__global__ __launch_bounds__(256) void k0_cast(
    const float* __restrict__ s, u16* __restrict__ d, int n4)
{
    int i = blockIdx.x * 256 + threadIdx.x;
    if (i < n4) {
        float4 v = reinterpret_cast<const float4*>(s)[i];
        ushort4 o;
        o.x = f2bf(v.x); o.y = f2bf(v.y); o.z = f2bf(v.z); o.w = f2bf(v.w);
        reinterpret_cast<ushort4*>(d)[i] = o;
    }
}

// ---------------------------------------------------------------------------
// K1: bf16 MFMA GEMM  qkv = x @ W^T + b  (M=2048,N=3072,K=1024)
// ---------------------------------------------------------------------------
__global__ __launch_bounds__(256) void k1_qkv(
    const u16* __restrict__ xbf, const u16* __restrict__ wbf,
    const float* __restrict__ bias,
    u16* __restrict__ qb, u16* __restrict__ kb, u16* __restrict__ vb)
{
    __shared__ __align__(16) u16 As[128 * 32];
    __shared__ __align__(16) u16 Bs[128 * 32];
    const int tid = threadIdx.x;
    const int wave = tid >> 6, lane = tid & 63;
    const int quad = lane >> 4, l15 = lane & 15;
    const int m0 = blockIdx.y << 7, n0 = blockIdx.x << 7;
    const int wm = (wave >> 1) << 6, wn = (wave & 1) << 6;

    const int rowS = (wave << 5) + (lane >> 2);
    const int seg8 = (lane & 3) << 3;
    const u16* gA1 = xbf + (size_t)(m0 + rowS) * 1024 + seg8;
    const u16* gA2 = gA1 + (size_t)16 * 1024;
    const u16* gB1 = wbf + (size_t)(n0 + rowS) * 1024 + seg8;
    const u16* gB2 = gB1 + (size_t)16 * 1024;
    u16* lA1 = &As[(wave << 5) * 32];
    u16* lA2 = lA1 + 16 * 32;
    u16* lB1 = &Bs[(wave << 5) * 32];
    u16* lB2 = lB1 + 16 * 32;

    f32x4 zero4 = {0.f, 0.f, 0.f, 0.f};
    f32x4 acc[4][4];
#pragma unroll
    for (int i = 0; i < 4; i++)
#pragma unroll
        for (int j = 0; j < 4; j++) acc[i][j] = zero4;

    for (int k0 = 0; k0 < 1024; k0 += 32) {
        GLL16(gA1 + k0, lA1);
        GLL16(gA2 + k0, lA2);
        GLL16(gB1 + k0, lB1);
        GLL16(gB2 + k0, lB2);
        __syncthreads();
        short8 a[4], b[4];
#pragma unroll
        for (int mi = 0; mi < 4; mi++)
            a[mi] = *(const short8*)&As[(wm + mi * 16 + l15) * 32 + (quad << 3)];
#pragma unroll
        for (int ni = 0; ni < 4; ni++)
            b[ni] = *(const short8*)&Bs[(wn + ni * 16 + l15) * 32 + (quad << 3)];
#pragma unroll
        for (int mi = 0; mi < 4; mi++)
#pragma unroll
            for (int ni = 0; ni < 4; ni++)
                acc[mi][ni] = __builtin_amdgcn_mfma_f32_16x16x32_bf16(
                    a[mi], b[ni], acc[mi][ni], 0, 0, 0);
        __syncthreads();
    }
#pragma unroll
    for (int ni = 0; ni < 4; ni++) {
        int n_g = n0 + wn + ni * 16 + l15;
        int which = n_g >> 10;
        int h = (n_g >> 6) & 15;
        int d = n_g & 63;
        u16* dst = (which == 0) ? qb : (which == 1) ? kb : vb;
        float bz = bias[n_g];
#pragma unroll
        for (int mi = 0; mi < 4; mi++) {
#pragma unroll
            for (int reg = 0; reg < 4; reg++) {
                int m = m0 + wm + mi * 16 + (quad << 2) + reg;
                int bi = m >> 10, t = m & 1023;
                dst[((size_t)(bi * 16 + h) << 16) + ((size_t)t << 6) + d] =
                    f2bf(acc[mi][ni][reg] + bz);
            }
        }
    }
}

// ---------------------------------------------------------------------------
// K_VT: vtb[bh][d][t] = vb[bh][t][d]
// ---------------------------------------------------------------------------
__global__ __launch_bounds__(256) void k_vt(
    const u16* __restrict__ vb, u16* __restrict__ vtb)
{
    const int t0 = blockIdx.x << 6, bh = blockIdx.y;
    __shared__ __align__(16) u16 Vs[64][72];
    const int tid = threadIdx.x;
#pragma unroll
    for (int u = 0; u < 2; u++) {
        int idx = (tid + (u << 8)) << 3;
        int r = idx >> 6, c = idx & 63;
        *(uint4*)&Vs[r][c] =
            *(const uint4*)&vb[((size_t)bh << 16) + ((size_t)(t0 + r) << 6) + c];
    }
    __syncthreads();
#pragma unroll
    for (int u = 0; u < 2; u++) {
        int idx = (tid + (u << 8)) << 3;
        int dd = idx >> 6, c0 = idx & 63;
        union { u16 s[8]; uint4 v; } tmp;
#pragma unroll
        for (int j = 0; j < 8; j++) tmp.s[j] = Vs[c0 + j][dd];
        *(uint4*)&vtb[((size_t)((bh << 6) + dd) << 10) + t0 + c0] = tmp.v;
    }
}

// ---------------------------------------------------------------------------
// K2a: per-(bh,chunk) KV state
// ---------------------------------------------------------------------------
__global__ __launch_bounds__(256) void k2a_chunkkv(
    const u16* __restrict__ kb, const u16* __restrict__ vb,
    float* __restrict__ Sg, float* __restrict__ svg)
{
    const int chunk = blockIdx.x, bh = blockIdx.y;
    const int t0 = chunk << 6;
    __shared__ float Ks[64][65];
    __shared__ float Vs[64][65];
    const int tid = threadIdx.x;
    const u16* kp = kb + (size_t)bh * T_ * D_;
    const u16* vp = vb + (size_t)bh * T_ * D_;
#pragma unroll
    for (int ii = 0; ii < 16; ii++) {
        int idx = tid + (ii << 8);
        int row = idx >> 6, col = idx & 63;
        Ks[row][col] = elu1(bf2f(kp[(size_t)(t0 + row) * D_ + col]) * SCALE);
        Vs[row][col] = bf2f(vp[(size_t)(t0 + row) * D_ + col]);
    }
    __syncthreads();
    const int tr = tid >> 4, tc = tid & 15;
    const int d0 = tr * 4, e0 = tc * 4;
    float acc[4][4] = {};
    for (int c = 0; c < 64; c++) {
        float a[4], b[4];
#pragma unroll
        for (int i = 0; i < 4; i++) a[i] = Ks[c][d0 + i];
#pragma unroll
        for (int j = 0; j < 4; j++) b[j] = Vs[c][e0 + j];
#pragma unroll
        for (int i = 0; i < 4; i++)
#pragma unroll
            for (int j = 0; j < 4; j++) acc[i][j] += a[i] * b[j];
    }
    float* so = Sg + ((size_t)bh * 16 + chunk) * 4096;
#pragma unroll
    for (int i = 0; i < 4; i++) {
        float4 o = {acc[i][0], acc[i][1], acc[i][2], acc[i][3]};
        *reinterpret_cast<float4*>(&so[(d0 + i) * 64 + e0]) = o;
    }
    if (tc == 0) {
#pragma unroll
        for (int i = 0; i < 4; i++) {
            float s = 0.f;
            for (int c = 0; c < 64; c++) s += Ks[c][d0 + i];
            svg[((size_t)bh * 16 + chunk) * 64 + d0 + i] = s;
        }
    }
}

// ---------------------------------------------------------------------------
// K2s: in-place exclusive prefix scan over the chunk dim of Sg (and svg).
// ---------------------------------------------------------------------------
__global__ __launch_bounds__(256) void k2s_scan(
    float* __restrict__ Sg, float* __restrict__ svg)
{
    int gid = blockIdx.x * 256 + threadIdx.x;
    if (gid < 131072) {
        int bh = gid >> 12, e = gid & 4095;
        float* base = Sg + ((size_t)bh << 16) + e;
        float v[16];
#pragma unroll
        for (int c = 0; c < 16; c++) v[c] = base[(size_t)c << 12];
        float run = 0.f;
#pragma unroll
        for (int c = 0; c < 16; c++) {
            base[(size_t)c << 12] = run;
            run += v[c];
        }
    } else if (gid < 131072 + 2048) {
        int g2 = gid - 131072;
        int bh = g2 >> 6, d = g2 & 63;
        float* base = svg + ((size_t)bh << 10) + d;
        float v[16];
#pragma unroll
        for (int c = 0; c < 16; c++) v[c] = base[c << 6];
        float run = 0.f;
#pragma unroll
        for (int c = 0; c < 16; c++) {
            base[c << 6] = run;
            run += v[c];
        }
    }
}

// ---------------------------------------------------------------------------
// K2b: linear attention per chunk; prefix state direct float4 load.
// ---------------------------------------------------------------------------
__global__ __launch_bounds__(256) void k2b_lin(
    const u16* __restrict__ qbp, const u16* __restrict__ kbp,
    const u16* __restrict__ vbp,
    const float* __restrict__ Sg, const float* __restrict__ svg,
    const float* __restrict__ ang, const float* __restrict__ anb,
    float* __restrict__ ylin)
{
    const int chunk = blockIdx.x, bh = blockIdx.y;
    const int t0 = chunk << 6;
    __shared__ __align__(16) float bufA[64][68];
    __shared__ float bufQ[64][65];
    __shared__ float bufK[64][65];
    __shared__ float svec[64];
    const int tid = threadIdx.x;
    const u16* qp = qbp + (size_t)bh * T_ * D_;
    const u16* kp = kbp + (size_t)bh * T_ * D_;
    const u16* vp = vbp + (size_t)bh * T_ * D_;
    const float* sp = Sg + (((size_t)bh * 16 + chunk) << 12);
#pragma unroll
    for (int u = 0; u < 4; u++) {
        int idx = (tid + (u << 8)) << 2;
        int dd = idx >> 6, e = idx & 63;
        *(float4*)&bufA[dd][e] = *(const float4*)&sp[idx];
    }
    if (tid < 64) svec[tid] = svg[(((size_t)bh * 16 + chunk) << 6) + tid];
#pragma unroll
    for (int ii = 0; ii < 16; ii++) {
        int idx = tid + (ii << 8);
        int row = idx >> 6, col = idx & 63;
        bufQ[col][row] = elu1(bf2f(qp[(size_t)(t0 + row) * D_ + col]) * SCALE);
    }
    __syncthreads();
    const int tr = tid >> 4, tc = tid & 15;
    const int r0 = tr * 4, c0 = tc * 4;
    float N[4][4] = {};
    float pden[4];
    for (int dd = 0; dd < 64; dd++) {
        float a[4], b[4];
#pragma unroll
        for (int i = 0; i < 4; i++) a[i] = bufQ[dd][r0 + i];
#pragma unroll
        for (int j = 0; j < 4; j++) b[j] = bufA[dd][c0 + j];
#pragma unroll
        for (int i = 0; i < 4; i++)
#pragma unroll
            for (int j = 0; j < 4; j++) N[i][j] += a[i] * b[j];
    }
#pragma unroll
    for (int i = 0; i < 4; i++) {
        float s = 0.f;
#pragma unroll
        for (int j = 0; j < 4; j++) s += bufQ[c0 + j][r0 + i] * svec[c0 + j];
        pden[i] = s;
    }
    __syncthreads();
#pragma unroll
    for (int ii = 0; ii < 16; ii++) {
        int idx = tid + (ii << 8);
        int row = idx >> 6, col = idx & 63;
        bufK[col][row] = elu1(bf2f(kp[(size_t)(t0 + row) * D_ + col]) * SCALE);
        bufA[row][col] = bf2f(vp[(size_t)(t0 + row) * D_ + col]);
    }
    __syncthreads();
    float sc[4][4] = {};
    for (int dd = 0; dd < 64; dd++) {
        float a[4], b[4];
#pragma unroll
        for (int i = 0; i < 4; i++) a[i] = bufQ[dd][r0 + i];
#pragma unroll
        for (int j = 0; j < 4; j++) b[j] = bufK[dd][c0 + j];
#pragma unroll
        for (int i = 0; i < 4; i++)
#pragma unroll
            for (int j = 0; j < 4; j++) sc[i][j] += a[i] * b[j];
    }
    __syncthreads();
#pragma unroll
    for (int i = 0; i < 4; i++) {
        float s = 0.f;
#pragma unroll
        for (int j = 0; j < 4; j++) {
            float pv = ((c0 + j) <= (r0 + i)) ? sc[i][j] : 0.f;
            bufQ[c0 + j][r0 + i] = pv;
            s += pv;
        }
        pden[i] += s;
    }
#pragma unroll
    for (int i = 0; i < 4; i++) {
#pragma unroll
        for (int off = 1; off < 16; off <<= 1)
            pden[i] += __shfl_xor(pden[i], off);
    }
    __syncthreads();
    for (int c = 0; c < 64; c++) {
        float a[4], b[4];
#pragma unroll
        for (int i = 0; i < 4; i++) a[i] = bufQ[c][r0 + i];
#pragma unroll
        for (int j = 0; j < 4; j++) b[j] = bufA[c][c0 + j];
#pragma unroll
        for (int i = 0; i < 4; i++)
#pragma unroll
            for (int j = 0; j < 4; j++) N[i][j] += a[i] * b[j];
    }
    float yv[4][4], s1[4], s2[4];
#pragma unroll
    for (int i = 0; i < 4; i++) {
        float inv = 1.f / (pden[i] + 1e-4f);
        s1[i] = 0.f; s2[i] = 0.f;
#pragma unroll
        for (int j = 0; j < 4; j++) {
            float t = N[i][j] * inv;
            yv[i][j] = t; s1[i] += t; s2[i] += t * t;
        }
    }
#pragma unroll
    for (int i = 0; i < 4; i++) {
#pragma unroll
        for (int off = 1; off < 16; off <<= 1) {
            s1[i] += __shfl_xor(s1[i], off);
            s2[i] += __shfl_xor(s2[i], off);
        }
    }
#pragma unroll
    for (int i = 0; i < 4; i++) {
        float mean = s1[i] * (1.f / 64.f);
        float var = s2[i] * (1.f / 64.f) - mean * mean;
        float rstd = rsqrtf(var + 1e-5f);
        float4 o;
        o.x = (yv[i][0] - mean) * rstd * ang[c0 + 0] + anb[c0 + 0];
        o.y = (yv[i][1] - mean) * rstd * ang[c0 + 1] + anb[c0 + 1];
        o.z = (yv[i][2] - mean) * rstd * ang[c0 + 2] + anb[c0 + 2];
        o.w = (yv[i][3] - mean) * rstd * ang[c0 + 3] + anb[c0 + 3];
        *reinterpret_cast<float4*>(
            &ylin[((size_t)bh * T_ + t0 + r0 + i) * D_ + c0]) = o;
    }
}

// ---------------------------------------------------------------------------
// K3a: split-K flash attention partials. job = blockIdx.x (0..31):
// qi = job>>1, half = job&1; half0 = tiles [0, (qi+1)/2), half1 = rest.
// Writes unnormalized O partial (fp32) + per-row (m, l).
// ---------------------------------------------------------------------------
__global__ __launch_bounds__(256) void k3a_part(
    const u16* __restrict__ qbp, const u16* __restrict__ kbp,
    const u16* __restrict__ vtb,
    float* __restrict__ Op, float* __restrict__ ml)
{
    const int job = blockIdx.x, bh = blockIdx.y;
    const int qi = job >> 1, half = job & 1;
    const int n = qi + 1;
    const int csplit = n >> 1;
    const int kbeg = half ? csplit : 0;
    const int kend = half ? n : csplit;
    __shared__ __align__(16) u16 Qs[64][72];
    __shared__ __align__(16) u16 Ks[64][72];
    __shared__ __align__(16) u16 Vt[64][72];
    __shared__ __align__(16) u16 Pa[64][72];
    const int tid = threadIdx.x;
    const int wave = tid >> 6, lane = tid & 63;
    const int quad = lane >> 4, l15 = lane & 15;
    const f32x4 zero4 = {0.f, 0.f, 0.f, 0.f};

#pragma unroll
    for (int u = 0; u < 2; u++) {
        int idx = (tid + (u << 8)) << 3;
        int r = idx >> 6, c = idx & 63;
        *(uint4*)&Qs[r][c] = *(const uint4*)
            &qbp[((size_t)bh << 16) + ((size_t)((qi << 6) + r) << 6) + c];
    }
    __syncthreads();
    short8 bq[2];
    bq[0] = *(const short8*)&Qs[(wave << 4) + l15][(quad << 3)];
    bq[1] = *(const short8*)&Qs[(wave << 4) + l15][32 + (quad << 3)];
    f32x4 O[4];
#pragma unroll
    for (int dt = 0; dt < 4; dt++) O[dt] = zero4;
    float m_run = -INFINITY, l_run = 0.f;
    const int r_g = (qi << 6) + (wave << 4) + l15;

    for (int ki = kbeg; ki < kend; ki++) {
        __syncthreads();
#pragma unroll
        for (int u = 0; u < 2; u++) {
            int idx = (tid + (u << 8)) << 3;
            int r = idx >> 6, c = idx & 63;
            *(uint4*)&Ks[r][c] = *(const uint4*)
                &kbp[((size_t)bh << 16) + ((size_t)((ki << 6) + r) << 6) + c];
            *(uint4*)&Vt[r][c] = *(const uint4*)
                &vtb[((size_t)((bh << 6) + r) << 10) + (ki << 6) + c];
        }
        __syncthreads();
        f32x4 st[4];
#pragma unroll
        for (int ct = 0; ct < 4; ct++) st[ct] = zero4;
#pragma unroll
        for (int ks = 0; ks < 2; ks++) {
#pragma unroll
            for (int ct = 0; ct < 4; ct++) {
                short8 a = *(const short8*)
                    &Ks[(ct << 4) + l15][(ks << 5) + (quad << 3)];
                st[ct] = __builtin_amdgcn_mfma_f32_16x16x32_bf16(
                    a, bq[ks], st[ct], 0, 0, 0);
            }
        }
        float mloc = -INFINITY;
#pragma unroll
        for (int ct = 0; ct < 4; ct++)
#pragma unroll
            for (int reg = 0; reg < 4; reg++) {
                int c_g = (ki << 6) + (ct << 4) + (quad << 2) + reg;
                float s = st[ct][reg] * SCALE;
                if (c_g > r_g) s = -INFINITY;
                st[ct][reg] = s;
                mloc = fmaxf(mloc, s);
            }
        mloc = fmaxf(mloc, __shfl_xor(mloc, 16));
        mloc = fmaxf(mloc, __shfl_xor(mloc, 32));
        float mnew = fmaxf(m_run, mloc);
        float corr = __expf(m_run - mnew);   // exp(-inf)=0 on first tile
        m_run = mnew;
        float rsum = 0.f;
#pragma unroll
        for (int ct = 0; ct < 4; ct++) {
            u16 pk[4];
#pragma unroll
            for (int reg = 0; reg < 4; reg++) {
                float pv = __expf(st[ct][reg] - mnew);
                rsum += pv;
                pk[reg] = f2bf(pv);
            }
            unsigned lo = (unsigned)pk[0] | ((unsigned)pk[1] << 16);
            unsigned hi = (unsigned)pk[2] | ((unsigned)pk[3] << 16);
            uint2 pkv; pkv.x = lo; pkv.y = hi;
            *(uint2*)&Pa[(wave << 4) + l15][(ct << 4) + (quad << 2)] = pkv;
        }
        rsum += __shfl_xor(rsum, 16);
        rsum += __shfl_xor(rsum, 32);
        l_run = l_run * corr + rsum;
        float co[4];
#pragma unroll
        for (int reg = 0; reg < 4; reg++)
            co[reg] = __shfl(corr, ((lane >> 4) << 2) + reg);
#pragma unroll
        for (int dt = 0; dt < 4; dt++)
#pragma unroll
            for (int reg = 0; reg < 4; reg++) O[dt][reg] *= co[reg];
#pragma unroll
        for (int ks = 0; ks < 2; ks++) {
            short8 ap = *(const short8*)
                &Pa[(wave << 4) + l15][(ks << 5) + (quad << 3)];
#pragma unroll
            for (int dt = 0; dt < 4; dt++) {
                short8 bv = *(const short8*)
                    &Vt[(dt << 4) + l15][(ks << 5) + (quad << 3)];
                O[dt] = __builtin_amdgcn_mfma_f32_16x16x32_bf16(
                    ap, bv, O[dt], 0, 0, 0);
            }
        }
    }
    // epilogue: unnormalized partials
    float* ob = Op + (((size_t)bh * 32 + job) << 12);
#pragma unroll
    for (int dt = 0; dt < 4; dt++)
#pragma unroll
        for (int reg = 0; reg < 4; reg++) {
            int r = (wave << 4) + (quad << 2) + reg;
            int d = (dt << 4) + l15;
            ob[(r << 6) + d] = O[dt][reg];
        }
    if (quad == 0) {
        int r = (wave << 4) + l15;
        float* mlb = ml + (((size_t)bh * 32 + job) << 7);
        mlb[r] = m_run;
        mlb[64 + r] = l_run;
    }
}

// ---------------------------------------------------------------------------
// K3c: combine two partials per (bh, qi, row) + alpha-blend with ylin.
// ---------------------------------------------------------------------------
__global__ __launch_bounds__(256) void k3c_comb(
    const float* __restrict__ Op, const float* __restrict__ ml,
    const float* __restrict__ ylin, const float* __restrict__ fg,
    float* __restrict__ ycomb)
{
    const int qi = blockIdx.x, bh = blockIdx.y;
    const int bi = bh >> 4, h = bh & 15;
    __shared__ float sm[4][64];
    const int tid = threadIdx.x;
    const float al = 1.f / (1.f + __expf(-fg[0]));
    const size_t b0 = (((size_t)bh * 32 + (qi << 1)) << 7);
    if (tid < 64) {
        sm[0][tid] = ml[b0 + tid];
        sm[1][tid] = ml[b0 + 64 + tid];
        sm[2][tid] = ml[b0 + 128 + tid];
        sm[3][tid] = ml[b0 + 192 + tid];
    }
    __syncthreads();
    const float* o0 = Op + (((size_t)bh * 32 + (qi << 1)) << 12);
    const float* o1 = o0 + 4096;
#pragma unroll
    for (int u = 0; u < 4; u++) {
        int idx = tid + (u << 8);          // float4 index 0..1023
        int r = idx >> 4, d4 = (idx & 15) << 2;
        float m0 = sm[0][r], l0 = sm[1][r];
        float m1 = sm[2][r], l1 = sm[3][r];
        float m = fmaxf(m0, m1);
        float w0 = (m0 == -INFINITY) ? 0.f : __expf(m0 - m);
        float w1 = __expf(m1 - m);
        float inv = al / (l0 * w0 + l1 * w1);
        float4 a = *(const float4*)&o0[(r << 6) + d4];
        float4 b = *(const float4*)&o1[(r << 6) + d4];
        int t = (qi << 6) + r;
        float4 yl = *(const float4*)&ylin[((((size_t)bh << 10) + t) << 6) + d4];
        float4 o;
        o.x = (a.x * w0 + b.x * w1) * inv + (1.f - al) * yl.x;
        o.y = (a.y * w0 + b.y * w1) * inv + (1.f - al) * yl.y;
        o.z = (a.z * w0 + b.z * w1) * inv + (1.f - al) * yl.z;
        o.w = (a.w * w0 + b.w * w1) * inv + (1.f - al) * yl.w;
        *(float4*)&ycomb[((((size_t)(bi << 10) + t)) << 10) + (h << 6) + d4] = o;
    }
}

// ---------------------------------------------------------------------------
// K4m: Mg[j][r] = alpha * sum_c wcol[j][c]*wrow[r][c]   (one block)
// ---------------------------------------------------------------------------
__global__ __launch_bounds__(256) void k4m(
    const float* __restrict__ wcol, const float* __restrict__ wrow,
    const float* __restrict__ palpha, float* __restrict__ Mg)
{
    const int tid = threadIdx.x;
    const int j = tid >> 3, r0 = (tid & 7) << 2;
    const float al = palpha[0];
    float acc[4] = {0.f, 0.f, 0.f, 0.f};
    for (int c = 0; c < 32; c++) {
        float wc = wcol[(j << 5) + c];
#pragma unroll
        for (int q = 0; q < 4; q++) acc[q] += wc * wrow[((r0 + q) << 5) + c];
    }
    float4 o = {al * acc[0], al * acc[1], al * acc[2], al * acc[3]};
    *reinterpret_cast<float4*>(&Mg[(j << 5) + r0]) = o;
}

// ---------------------------------------------------------------------------
// K4: out-LN -> pre-LN -> block-diag mix (reversed) + folded bilinear + bias.
// ---------------------------------------------------------------------------
__global__ __launch_bounds__(256) void k4_proj(
    const float* __restrict__ ycomb,
    const float* __restrict__ og, const float* __restrict__ ob,
    const float* __restrict__ pg, const float* __restrict__ pb,
    const float* __restrict__ bw, const float* __restrict__ Mg,
    const float* __restrict__ pbias, float* __restrict__ out)
{
    const int tok = blockIdx.x;
    __shared__ float xb[1024];
    __shared__ float red[8];
    const int tid = threadIdx.x;
    const int c0 = tid << 2;
    const float* yrow = ycomb + ((size_t)tok << 10);
    float4 v4 = *reinterpret_cast<const float4*>(yrow + c0);
    float v[4] = {v4.x, v4.y, v4.z, v4.w};
    float s1 = v[0] + v[1] + v[2] + v[3];
    float s2 = v[0]*v[0] + v[1]*v[1] + v[2]*v[2] + v[3]*v[3];
#pragma unroll
    for (int off = 1; off < 64; off <<= 1) {
        s1 += __shfl_xor(s1, off); s2 += __shfl_xor(s2, off);
    }
    if ((tid & 63) == 0) { red[(tid >> 6) * 2] = s1; red[(tid >> 6) * 2 + 1] = s2; }
    __syncthreads();
    s1 = red[0] + red[2] + red[4] + red[6];
    s2 = red[1] + red[3] + red[5] + red[7];
    __syncthreads();
    {
        float mean = s1 * (1.f / 1024.f);
        float var = s2 * (1.f / 1024.f) - mean * mean;
        float rstd = rsqrtf(var + 1e-5f);
#pragma unroll
        for (int q = 0; q < 4; q++)
            v[q] = (v[q] - mean) * rstd * og[c0 + q] + ob[c0 + q];
    }
    s1 = v[0] + v[1] + v[2] + v[3];
    s2 = v[0]*v[0] + v[1]*v[1] + v[2]*v[2] + v[3]*v[3];
#pragma unroll
    for (int off = 1; off < 64; off <<= 1) {
        s1 += __shfl_xor(s1, off); s2 += __shfl_xor(s2, off);
    }
    if ((tid & 63) == 0) { red[(tid >> 6) * 2] = s1; red[(tid >> 6) * 2 + 1] = s2; }
    __syncthreads();
    s1 = red[0] + red[2] + red[4] + red[6];
    s2 = red[1] + red[3] + red[5] + red[7];
    {
        float mean = s1 * (1.f / 1024.f);
        float var = s2 * (1.f / 1024.f) - mean * mean;
        float rstd = rsqrtf(var + 1e-5f);
#pragma unroll
        for (int q = 0; q < 4; q++)
            xb[c0 + q] = (v[q] - mean) * rstd * pg[c0 + q] + pb[c0 + q];
    }
    __syncthreads();
    const int g = tid >> 2;
    const int jb = (tid & 3) << 2;
    float acc[4] = {0.f, 0.f, 0.f, 0.f};
    {
        const float* xg = &xb[g << 4];
        const float* bwg = &bw[(g << 8) + jb];
        for (int i = 0; i < 16; i++) {
            float xv = xg[i];
            float4 wv = *reinterpret_cast<const float4*>(&bwg[i << 4]);
            acc[0] += xv * wv.x; acc[1] += xv * wv.y;
            acc[2] += xv * wv.z; acc[3] += xv * wv.w;
        }
    }
    const int C0 = ((63 - g) << 4) + 12 - jb;
    const int i2 = C0 >> 5, r0 = C0 & 31;
    float z2[4] = {0.f, 0.f, 0.f, 0.f};
    {
        const float* xg = &xb[i2 << 5];
        const float* mg = &Mg[r0];
        for (int j = 0; j < 32; j++) {
            float xv = xg[j];
            float4 mv = *reinterpret_cast<const float4*>(&mg[j << 5]);
            z2[0] += xv * mv.x; z2[1] += xv * mv.y;
            z2[2] += xv * mv.z; z2[3] += xv * mv.w;
        }
    }
    float4 bz = *reinterpret_cast<const float4*>(&pbias[C0]);
    float4 o;
    o.x = acc[3] + z2[0] + bz.x;
    o.y = acc[2] + z2[1] + bz.y;
    o.z = acc[1] + z2[2] + bz.z;
    o.w = acc[0] + z2[3] + bz.w;
    *reinterpret_cast<float4*>(&out[((size_t)tok << 10) + C0]) = o;
}

// ---------------------------------------------------------------------------
extern "C" void kernel_launch(void* const* d_in, const int* in_sizes, int n_in,
                              void* d_out, int out_size, void* d_ws, size_t ws_size,
                              hipStream_t stream) {
    const float* x   = (const float*)d_in[0];
    const float* w   = (const float*)d_in[1];
    const float* wb  = (const float*)d_in[2];
    const float* fg  = (const float*)d_in[3];
    const float* ang = (const float*)d_in[4];
    const float* anb = (const float*)d_in[5];
    const float* ong = (const float*)d_in[6];
    const float* onb = (const float*)d_in[7];
    const float* ppg = (const float*)d_in[8];
    const float* ppb = (const float*)d_in[9];
    const float* pbw = (const float*)d_in[10];
    const float* pwr = (const float*)d_in[11];
    const float* pwc = (const float*)d_in[12];
    const float* pal = (const float*)d_in[13];
    const float* pbi = (const float*)d_in[14];

    uint8_t* p = (uint8_t*)d_ws;
    u16* xbf = (u16*)p;  p += (size_t)2048 * 1024 * 2;
    u16* wbf = (u16*)p;  p += (size_t)3072 * 1024 * 2;
    u16* qb  = (u16*)p;  p += (size_t)32 * 1024 * 64 * 2;
    u16* kb  = (u16*)p;  p += (size_t)32 * 1024 * 64 * 2;
    u16* vb  = (u16*)p;  p += (size_t)32 * 1024 * 64 * 2;
    u16* vtb = (u16*)p;  p += (size_t)32 * 1024 * 64 * 2;
    float* ylin  = (float*)p;  p += (size_t)32 * 1024 * 64 * 4;
    float* ycomb = (float*)p;  p += (size_t)32 * 1024 * 64 * 4;
    float* Sg    = (float*)p;  p += (size_t)32 * 16 * 4096 * 4;
    float* svg   = (float*)p;  p += (size_t)32 * 16 * 64 * 4;
    float* Mg    = (float*)p;  p += (size_t)32 * 32 * 4;
    float* Op    = (float*)p;  p += (size_t)32 * 32 * 4096 * 4;
    float* ml    = (float*)p;  p += (size_t)32 * 32 * 128 * 4;
    float* out   = (float*)d_out;

    k0_cast<<<2048, 256, 0, stream>>>(x, xbf, 524288);
    k0_cast<<<3072, 256, 0, stream>>>(w, wbf, 786432);
    k4m<<<1, 256, 0, stream>>>(pwc, pwr, pal, Mg);
    k1_qkv<<<dim3(24, 16), 256, 0, stream>>>(xbf, wbf, wb, qb, kb, vb);
    k_vt<<<dim3(16, 32), 256, 0, stream>>>(vb, vtb);
    k2a_chunkkv<<<dim3(16, 32), 256, 0, stream>>>(kb, vb, Sg, svg);
    k2s_scan<<<521, 256, 0, stream>>>(Sg, svg);
    k2b_lin<<<dim3(16, 32), 256, 0, stream>>>(qb, kb, vb, Sg, svg, ang, anb, ylin);
    k3a_part<<<dim3(32, 32), 256, 0, stream>>>(qb, kb, vtb, Op, ml);
    k3c_comb<<<dim3(16, 32), 256, 0, stream>>>(Op, ml, ylin, fg, ycomb);
    k4_proj<<<2048, 256, 0, stream>>>(ycomb, ong, onb, ppg, ppb, pbw, Mg, pbi, out);
}

// Round 7
// 212.312 us; speedup vs baseline: 2.8070x; 1.0192x over previous
//
#include <hip/hip_runtime.h>
#include <math.h>

constexpr int T_ = 1024;
constexpr int C_ = 1024;
constexpr int H_ = 16;
constexpr int D_ = 64;
#define SCALE 0.125f

typedef unsigned short u16;
typedef __attribute__((ext_vector_type(8))) short short8;
typedef __attribute__((ext_vector_type(4))) float f32x4;

__device__ __forceinline__ float elu1(float x) { return x > 0.f ? x + 1.f : expf(x); }

__device__ __forceinline__ u16 f2bf(float f) {
    union { float f; unsigned u; } c; c.f = f;
    unsigned r = (c.u + 0x7fffu + ((c.u >> 16) & 1u)) >> 16;
    return (u16)r;
}
__device__ __forceinline__ float bf2f(u16 u) {
    union { unsigned u; float f; } c; c.u = (unsigned)u << 16;
    return c.f;
}

#define GLL16(g, l)                                                            \
    __builtin_amdgcn_global_load_lds(                                          \
        (const __attribute__((address_space(1))) void*)(g),                    \
        (__attribute__((address_space(3))) void*)(l), 16, 0, 0)

// ---------------------------------------------------------------------------
// K0_prep: fused x-cast (blocks [0,2048)), W-cast ([2048,5120)), and
// Mg = alpha * wcol @ wrow^T (block 5120).
// ---------------------------------------------------------------------------
__global__ __launch_bounds__(256) void k0_prep(
    const float* __restrict__ x, const float* __restrict__ w,
    const float* __restrict__ wcol, const float* __restrict__ wrow,
    const float* __restrict__ palpha,
    u16* __restrict__ xbf, u16* __restrict__ wbf, float* __restrict__ Mg)
{
    const int b = blockIdx.x;
    const int tid = threadIdx.x;
    if (b < 2048) {
        int i = b * 256 + tid;
        float4 v = reinterpret_cast<const float4*>(x)[i];
        ushort4 o;
        o.x = f2bf(v.x); o.y = f2bf(v.y); o.z = f2bf(v.z); o.w = f2bf(v.w);
        reinterpret_cast<ushort4*>(xbf)[i] = o;
    } else if (b < 5120) {
        int i = (b - 2048) * 256 + tid;
        float4 v = reinterpret_cast<const float4*>(w)[i];
        ushort4 o;
        o.x = f2bf(v.x); o.y = f2bf(v.y); o.z = f2bf(v.z); o.w = f2bf(v.w);
        reinterpret_cast<ushort4*>(wbf)[i] = o;
    } else {
        const int j = tid >> 3, r0 = (tid & 7) << 2;
        const float al = palpha[0];
        float acc[4] = {0.f, 0.f, 0.f, 0.f};
        for (int c = 0; c < 32; c++) {
            float wc = wcol[(j << 5) + c];
#pragma unroll
            for (int q = 0; q < 4; q++) acc[q] += wc * wrow[((r0 + q) << 5) + c];
        }
        float4 o = {al * acc[0], al * acc[1], al * acc[2], al * acc[3]};
        *reinterpret_cast<float4*>(&Mg[(j << 5) + r0]) = o;
    }
}

// ---------------------------------------------------------------------------
// K1: bf16 MFMA GEMM  qkv = x @ W^T + b  (M=2048,N=3072,K=1024).
// v-blocks also emit the transposed copy vtb[bh][d][t] (packed uint2).
// ---------------------------------------------------------------------------
__global__ __launch_bounds__(256) void k1_qkv(
    const u16* __restrict__ xbf, const u16* __restrict__ wbf,
    const float* __restrict__ bias,
    u16* __restrict__ qb, u16* __restrict__ kb, u16* __restrict__ vb,
    u16* __restrict__ vtb)
{
    __shared__ __align__(16) u16 As[128 * 32];
    __shared__ __align__(16) u16 Bs[128 * 32];
    const int tid = threadIdx.x;
    const int wave = tid >> 6, lane = tid & 63;
    const int quad = lane >> 4, l15 = lane & 15;
    const int m0 = blockIdx.y << 7, n0 = blockIdx.x << 7;
    const int wm = (wave >> 1) << 6, wn = (wave & 1) << 6;

    const int rowS = (wave << 5) + (lane >> 2);
    const int seg8 = (lane & 3) << 3;
    const u16* gA1 = xbf + (size_t)(m0 + rowS) * 1024 + seg8;
    const u16* gA2 = gA1 + (size_t)16 * 1024;
    const u16* gB1 = wbf + (size_t)(n0 + rowS) * 1024 + seg8;
    const u16* gB2 = gB1 + (size_t)16 * 1024;
    u16* lA1 = &As[(wave << 5) * 32];
    u16* lA2 = lA1 + 16 * 32;
    u16* lB1 = &Bs[(wave << 5) * 32];
    u16* lB2 = lB1 + 16 * 32;

    f32x4 zero4 = {0.f, 0.f, 0.f, 0.f};
    f32x4 acc[4][4];
#pragma unroll
    for (int i = 0; i < 4; i++)
#pragma unroll
        for (int j = 0; j < 4; j++) acc[i][j] = zero4;

    for (int k0 = 0; k0 < 1024; k0 += 32) {
        GLL16(gA1 + k0, lA1);
        GLL16(gA2 + k0, lA2);
        GLL16(gB1 + k0, lB1);
        GLL16(gB2 + k0, lB2);
        __syncthreads();
        short8 a[4], b[4];
#pragma unroll
        for (int mi = 0; mi < 4; mi++)
            a[mi] = *(const short8*)&As[(wm + mi * 16 + l15) * 32 + (quad << 3)];
#pragma unroll
        for (int ni = 0; ni < 4; ni++)
            b[ni] = *(const short8*)&Bs[(wn + ni * 16 + l15) * 32 + (quad << 3)];
#pragma unroll
        for (int mi = 0; mi < 4; mi++)
#pragma unroll
            for (int ni = 0; ni < 4; ni++)
                acc[mi][ni] = __builtin_amdgcn_mfma_f32_16x16x32_bf16(
                    a[mi], b[ni], acc[mi][ni], 0, 0, 0);
        __syncthreads();
    }
#pragma unroll
    for (int ni = 0; ni < 4; ni++) {
        int n_g = n0 + wn + ni * 16 + l15;
        int which = n_g >> 10;
        int h = (n_g >> 6) & 15;
        int d = n_g & 63;
        u16* dst = (which == 0) ? qb : (which == 1) ? kb : vb;
        float bz = bias[n_g];
#pragma unroll
        for (int mi = 0; mi < 4; mi++) {
            int m_base = m0 + wm + mi * 16 + (quad << 2);
            int bi = m_base >> 10, t_base = m_base & 1023;
            u16 o4[4];
#pragma unroll
            for (int reg = 0; reg < 4; reg++) {
                o4[reg] = f2bf(acc[mi][ni][reg] + bz);
                dst[((size_t)(bi * 16 + h) << 16) + ((size_t)(t_base + reg) << 6)
                    + d] = o4[reg];
            }
            if (which == 2) {
                *(uint2*)&vtb[(((size_t)((bi * 16 + h) << 6) + d) << 10) +
                              t_base] = *(uint2*)o4;
            }
        }
    }
}

// ---------------------------------------------------------------------------
// K2a: per-(bh,chunk) KV state (fp32 VALU, bf16 inputs)
// ---------------------------------------------------------------------------
__global__ __launch_bounds__(256) void k2a_chunkkv(
    const u16* __restrict__ kb, const u16* __restrict__ vb,
    float* __restrict__ Sg, float* __restrict__ svg)
{
    const int chunk = blockIdx.x, bh = blockIdx.y;
    const int t0 = chunk << 6;
    __shared__ float Ks[64][65];
    __shared__ float Vs[64][65];
    const int tid = threadIdx.x;
    const u16* kp = kb + (size_t)bh * T_ * D_;
    const u16* vp = vb + (size_t)bh * T_ * D_;
#pragma unroll
    for (int ii = 0; ii < 16; ii++) {
        int idx = tid + (ii << 8);
        int row = idx >> 6, col = idx & 63;
        Ks[row][col] = elu1(bf2f(kp[(size_t)(t0 + row) * D_ + col]) * SCALE);
        Vs[row][col] = bf2f(vp[(size_t)(t0 + row) * D_ + col]);
    }
    __syncthreads();
    const int tr = tid >> 4, tc = tid & 15;
    const int d0 = tr * 4, e0 = tc * 4;
    float acc[4][4] = {};
    for (int c = 0; c < 64; c++) {
        float a[4], b[4];
#pragma unroll
        for (int i = 0; i < 4; i++) a[i] = Ks[c][d0 + i];
#pragma unroll
        for (int j = 0; j < 4; j++) b[j] = Vs[c][e0 + j];
#pragma unroll
        for (int i = 0; i < 4; i++)
#pragma unroll
            for (int j = 0; j < 4; j++) acc[i][j] += a[i] * b[j];
    }
    float* so = Sg + ((size_t)bh * 16 + chunk) * 4096;
#pragma unroll
    for (int i = 0; i < 4; i++) {
        float4 o = {acc[i][0], acc[i][1], acc[i][2], acc[i][3]};
        *reinterpret_cast<float4*>(&so[(d0 + i) * 64 + e0]) = o;
    }
    if (tc == 0) {
#pragma unroll
        for (int i = 0; i < 4; i++) {
            float s = 0.f;
            for (int c = 0; c < 64; c++) s += Ks[c][d0 + i];
            svg[((size_t)bh * 16 + chunk) * 64 + d0 + i] = s;
        }
    }
}

// ---------------------------------------------------------------------------
// K2s: in-place exclusive prefix scan over the chunk dim of Sg (and svg).
// ---------------------------------------------------------------------------
__global__ __launch_bounds__(256) void k2s_scan(
    float* __restrict__ Sg, float* __restrict__ svg)
{
    int gid = blockIdx.x * 256 + threadIdx.x;
    if (gid < 131072) {
        int bh = gid >> 12, e = gid & 4095;
        float* base = Sg + ((size_t)bh << 16) + e;
        float v[16];
#pragma unroll
        for (int c = 0; c < 16; c++) v[c] = base[(size_t)c << 12];
        float run = 0.f;
#pragma unroll
        for (int c = 0; c < 16; c++) {
            base[(size_t)c << 12] = run;
            run += v[c];
        }
    } else if (gid < 131072 + 2048) {
        int g2 = gid - 131072;
        int bh = g2 >> 6, d = g2 & 63;
        float* base = svg + ((size_t)bh << 10) + d;
        float v[16];
#pragma unroll
        for (int c = 0; c < 16; c++) v[c] = base[c << 6];
        float run = 0.f;
#pragma unroll
        for (int c = 0; c < 16; c++) {
            base[c << 6] = run;
            run += v[c];
        }
    }
}

// ---------------------------------------------------------------------------
// K2b: linear attention per chunk (fp32 VALU); prefix state float4 load.
// ---------------------------------------------------------------------------
__global__ __launch_bounds__(256) void k2b_lin(
    const u16* __restrict__ qbp, const u16* __restrict__ kbp,
    const u16* __restrict__ vbp,
    const float* __restrict__ Sg, const float* __restrict__ svg,
    const float* __restrict__ ang, const float* __restrict__ anb,
    float* __restrict__ ylin)
{
    const int chunk = blockIdx.x, bh = blockIdx.y;
    const int t0 = chunk << 6;
    __shared__ __align__(16) float bufA[64][68];
    __shared__ float bufQ[64][65];
    __shared__ float bufK[64][65];
    __shared__ float svec[64];
    const int tid = threadIdx.x;
    const u16* qp = qbp + (size_t)bh * T_ * D_;
    const u16* kp = kbp + (size_t)bh * T_ * D_;
    const u16* vp = vbp + (size_t)bh * T_ * D_;
    const float* sp = Sg + (((size_t)bh * 16 + chunk) << 12);
#pragma unroll
    for (int u = 0; u < 4; u++) {
        int idx = (tid + (u << 8)) << 2;
        int dd = idx >> 6, e = idx & 63;
        *(float4*)&bufA[dd][e] = *(const float4*)&sp[idx];
    }
    if (tid < 64) svec[tid] = svg[(((size_t)bh * 16 + chunk) << 6) + tid];
#pragma unroll
    for (int ii = 0; ii < 16; ii++) {
        int idx = tid + (ii << 8);
        int row = idx >> 6, col = idx & 63;
        bufQ[col][row] = elu1(bf2f(qp[(size_t)(t0 + row) * D_ + col]) * SCALE);
    }
    __syncthreads();
    const int tr = tid >> 4, tc = tid & 15;
    const int r0 = tr * 4, c0 = tc * 4;
    float N[4][4] = {};
    float pden[4];
    for (int dd = 0; dd < 64; dd++) {
        float a[4], b[4];
#pragma unroll
        for (int i = 0; i < 4; i++) a[i] = bufQ[dd][r0 + i];
#pragma unroll
        for (int j = 0; j < 4; j++) b[j] = bufA[dd][c0 + j];
#pragma unroll
        for (int i = 0; i < 4; i++)
#pragma unroll
            for (int j = 0; j < 4; j++) N[i][j] += a[i] * b[j];
    }
#pragma unroll
    for (int i = 0; i < 4; i++) {
        float s = 0.f;
#pragma unroll
        for (int j = 0; j < 4; j++) s += bufQ[c0 + j][r0 + i] * svec[c0 + j];
        pden[i] = s;
    }
    __syncthreads();
#pragma unroll
    for (int ii = 0; ii < 16; ii++) {
        int idx = tid + (ii << 8);
        int row = idx >> 6, col = idx & 63;
        bufK[col][row] = elu1(bf2f(kp[(size_t)(t0 + row) * D_ + col]) * SCALE);
        bufA[row][col] = bf2f(vp[(size_t)(t0 + row) * D_ + col]);
    }
    __syncthreads();
    float sc[4][4] = {};
    for (int dd = 0; dd < 64; dd++) {
        float a[4], b[4];
#pragma unroll
        for (int i = 0; i < 4; i++) a[i] = bufQ[dd][r0 + i];
#pragma unroll
        for (int j = 0; j < 4; j++) b[j] = bufK[dd][c0 + j];
#pragma unroll
        for (int i = 0; i < 4; i++)
#pragma unroll
            for (int j = 0; j < 4; j++) sc[i][j] += a[i] * b[j];
    }
    __syncthreads();
#pragma unroll
    for (int i = 0; i < 4; i++) {
        float s = 0.f;
#pragma unroll
        for (int j = 0; j < 4; j++) {
            float pv = ((c0 + j) <= (r0 + i)) ? sc[i][j] : 0.f;
            bufQ[c0 + j][r0 + i] = pv;
            s += pv;
        }
        pden[i] += s;
    }
#pragma unroll
    for (int i = 0; i < 4; i++) {
#pragma unroll
        for (int off = 1; off < 16; off <<= 1)
            pden[i] += __shfl_xor(pden[i], off);
    }
    __syncthreads();
    for (int c = 0; c < 64; c++) {
        float a[4], b[4];
#pragma unroll
        for (int i = 0; i < 4; i++) a[i] = bufQ[c][r0 + i];
#pragma unroll
        for (int j = 0; j < 4; j++) b[j] = bufA[c][c0 + j];
#pragma unroll
        for (int i = 0; i < 4; i++)
#pragma unroll
            for (int j = 0; j < 4; j++) N[i][j] += a[i] * b[j];
    }
    float yv[4][4], s1[4], s2[4];
#pragma unroll
    for (int i = 0; i < 4; i++) {
        float inv = 1.f / (pden[i] + 1e-4f);
        s1[i] = 0.f; s2[i] = 0.f;
#pragma unroll
        for (int j = 0; j < 4; j++) {
            float t = N[i][j] * inv;
            yv[i][j] = t; s1[i] += t; s2[i] += t * t;
        }
    }
#pragma unroll
    for (int i = 0; i < 4; i++) {
#pragma unroll
        for (int off = 1; off < 16; off <<= 1) {
            s1[i] += __shfl_xor(s1[i], off);
            s2[i] += __shfl_xor(s2[i], off);
        }
    }
#pragma unroll
    for (int i = 0; i < 4; i++) {
        float mean = s1[i] * (1.f / 64.f);
        float var = s2[i] * (1.f / 64.f) - mean * mean;
        float rstd = rsqrtf(var + 1e-5f);
        float4 o;
        o.x = (yv[i][0] - mean) * rstd * ang[c0 + 0] + anb[c0 + 0];
        o.y = (yv[i][1] - mean) * rstd * ang[c0 + 1] + anb[c0 + 1];
        o.z = (yv[i][2] - mean) * rstd * ang[c0 + 2] + anb[c0 + 2];
        o.w = (yv[i][3] - mean) * rstd * ang[c0 + 3] + anb[c0 + 3];
        *reinterpret_cast<float4*>(
            &ylin[((size_t)bh * T_ + t0 + r0 + i) * D_ + c0]) = o;
    }
}

// ---------------------------------------------------------------------------
// K3a: split-K flash attention partials (unnormalized O + per-row m,l).
// ---------------------------------------------------------------------------
__global__ __launch_bounds__(256) void k3a_part(
    const u16* __restrict__ qbp, const u16* __restrict__ kbp,
    const u16* __restrict__ vtb,
    float* __restrict__ Op, float* __restrict__ ml)
{
    const int job = blockIdx.x, bh = blockIdx.y;
    const int qi = job >> 1, half = job & 1;
    const int n = qi + 1;
    const int csplit = n >> 1;
    const int kbeg = half ? csplit : 0;
    const int kend = half ? n : csplit;
    __shared__ __align__(16) u16 Qs[64][72];
    __shared__ __align__(16) u16 Ks[64][72];
    __shared__ __align__(16) u16 Vt[64][72];
    __shared__ __align__(16) u16 Pa[64][72];
    const int tid = threadIdx.x;
    const int wave = tid >> 6, lane = tid & 63;
    const int quad = lane >> 4, l15 = lane & 15;
    const f32x4 zero4 = {0.f, 0.f, 0.f, 0.f};

#pragma unroll
    for (int u = 0; u < 2; u++) {
        int idx = (tid + (u << 8)) << 3;
        int r = idx >> 6, c = idx & 63;
        *(uint4*)&Qs[r][c] = *(const uint4*)
            &qbp[((size_t)bh << 16) + ((size_t)((qi << 6) + r) << 6) + c];
    }
    __syncthreads();
    short8 bq[2];
    bq[0] = *(const short8*)&Qs[(wave << 4) + l15][(quad << 3)];
    bq[1] = *(const short8*)&Qs[(wave << 4) + l15][32 + (quad << 3)];
    f32x4 O[4];
#pragma unroll
    for (int dt = 0; dt < 4; dt++) O[dt] = zero4;
    float m_run = -INFINITY, l_run = 0.f;
    const int r_g = (qi << 6) + (wave << 4) + l15;

    for (int ki = kbeg; ki < kend; ki++) {
        __syncthreads();
#pragma unroll
        for (int u = 0; u < 2; u++) {
            int idx = (tid + (u << 8)) << 3;
            int r = idx >> 6, c = idx & 63;
            *(uint4*)&Ks[r][c] = *(const uint4*)
                &kbp[((size_t)bh << 16) + ((size_t)((ki << 6) + r) << 6) + c];
            *(uint4*)&Vt[r][c] = *(const uint4*)
                &vtb[((size_t)((bh << 6) + r) << 10) + (ki << 6) + c];
        }
        __syncthreads();
        f32x4 st[4];
#pragma unroll
        for (int ct = 0; ct < 4; ct++) st[ct] = zero4;
#pragma unroll
        for (int ks = 0; ks < 2; ks++) {
#pragma unroll
            for (int ct = 0; ct < 4; ct++) {
                short8 a = *(const short8*)
                    &Ks[(ct << 4) + l15][(ks << 5) + (quad << 3)];
                st[ct] = __builtin_amdgcn_mfma_f32_16x16x32_bf16(
                    a, bq[ks], st[ct], 0, 0, 0);
            }
        }
        float mloc = -INFINITY;
#pragma unroll
        for (int ct = 0; ct < 4; ct++)
#pragma unroll
            for (int reg = 0; reg < 4; reg++) {
                int c_g = (ki << 6) + (ct << 4) + (quad << 2) + reg;
                float s = st[ct][reg] * SCALE;
                if (c_g > r_g) s = -INFINITY;
                st[ct][reg] = s;
                mloc = fmaxf(mloc, s);
            }
        mloc = fmaxf(mloc, __shfl_xor(mloc, 16));
        mloc = fmaxf(mloc, __shfl_xor(mloc, 32));
        float mnew = fmaxf(m_run, mloc);
        float corr = __expf(m_run - mnew);
        m_run = mnew;
        float rsum = 0.f;
#pragma unroll
        for (int ct = 0; ct < 4; ct++) {
            u16 pk[4];
#pragma unroll
            for (int reg = 0; reg < 4; reg++) {
                float pv = __expf(st[ct][reg] - mnew);
                rsum += pv;
                pk[reg] = f2bf(pv);
            }
            unsigned lo = (unsigned)pk[0] | ((unsigned)pk[1] << 16);
            unsigned hi = (unsigned)pk[2] | ((unsigned)pk[3] << 16);
            uint2 pkv; pkv.x = lo; pkv.y = hi;
            *(uint2*)&Pa[(wave << 4) + l15][(ct << 4) + (quad << 2)] = pkv;
        }
        rsum += __shfl_xor(rsum, 16);
        rsum += __shfl_xor(rsum, 32);
        l_run = l_run * corr + rsum;
        float co[4];
#pragma unroll
        for (int reg = 0; reg < 4; reg++)
            co[reg] = __shfl(corr, ((lane >> 4) << 2) + reg);
#pragma unroll
        for (int dt = 0; dt < 4; dt++)
#pragma unroll
            for (int reg = 0; reg < 4; reg++) O[dt][reg] *= co[reg];
#pragma unroll
        for (int ks = 0; ks < 2; ks++) {
            short8 ap = *(const short8*)
                &Pa[(wave << 4) + l15][(ks << 5) + (quad << 3)];
#pragma unroll
            for (int dt = 0; dt < 4; dt++) {
                short8 bv = *(const short8*)
                    &Vt[(dt << 4) + l15][(ks << 5) + (quad << 3)];
                O[dt] = __builtin_amdgcn_mfma_f32_16x16x32_bf16(
                    ap, bv, O[dt], 0, 0, 0);
            }
        }
    }
    float* ob = Op + (((size_t)bh * 32 + job) << 12);
#pragma unroll
    for (int dt = 0; dt < 4; dt++)
#pragma unroll
        for (int reg = 0; reg < 4; reg++) {
            int r = (wave << 4) + (quad << 2) + reg;
            int d = (dt << 4) + l15;
            ob[(r << 6) + d] = O[dt][reg];
        }
    if (quad == 0) {
        int r = (wave << 4) + l15;
        float* mlb = ml + (((size_t)bh * 32 + job) << 7);
        mlb[r] = m_run;
        mlb[64 + r] = l_run;
    }
}

// ---------------------------------------------------------------------------
// K3c: combine two partials per (bh, qi, row) + alpha-blend with ylin.
// ---------------------------------------------------------------------------
__global__ __launch_bounds__(256) void k3c_comb(
    const float* __restrict__ Op, const float* __restrict__ ml,
    const float* __restrict__ ylin, const float* __restrict__ fg,
    float* __restrict__ ycomb)
{
    const int qi = blockIdx.x, bh = blockIdx.y;
    const int bi = bh >> 4, h = bh & 15;
    __shared__ float sm[4][64];
    const int tid = threadIdx.x;
    const float al = 1.f / (1.f + __expf(-fg[0]));
    const size_t b0 = (((size_t)bh * 32 + (qi << 1)) << 7);
    if (tid < 64) {
        sm[0][tid] = ml[b0 + tid];
        sm[1][tid] = ml[b0 + 64 + tid];
        sm[2][tid] = ml[b0 + 128 + tid];
        sm[3][tid] = ml[b0 + 192 + tid];
    }
    __syncthreads();
    const float* o0 = Op + (((size_t)bh * 32 + (qi << 1)) << 12);
    const float* o1 = o0 + 4096;
#pragma unroll
    for (int u = 0; u < 4; u++) {
        int idx = tid + (u << 8);
        int r = idx >> 4, d4 = (idx & 15) << 2;
        float m0 = sm[0][r], l0 = sm[1][r];
        float m1 = sm[2][r], l1 = sm[3][r];
        float m = fmaxf(m0, m1);
        float w0 = (m0 == -INFINITY) ? 0.f : __expf(m0 - m);
        float w1 = __expf(m1 - m);
        float inv = al / (l0 * w0 + l1 * w1);
        float4 a = *(const float4*)&o0[(r << 6) + d4];
        float4 b = *(const float4*)&o1[(r << 6) + d4];
        int t = (qi << 6) + r;
        float4 yl = *(const float4*)&ylin[((((size_t)bh << 10) + t) << 6) + d4];
        float4 o;
        o.x = (a.x * w0 + b.x * w1) * inv + (1.f - al) * yl.x;
        o.y = (a.y * w0 + b.y * w1) * inv + (1.f - al) * yl.y;
        o.z = (a.z * w0 + b.z * w1) * inv + (1.f - al) * yl.z;
        o.w = (a.w * w0 + b.w * w1) * inv + (1.f - al) * yl.w;
        *(float4*)&ycomb[((((size_t)(bi << 10) + t)) << 10) + (h << 6) + d4] = o;
    }
}

// ---------------------------------------------------------------------------
// K4: out-LN -> pre-LN -> block-diag mix (reversed) + folded bilinear + bias.
// ---------------------------------------------------------------------------
__global__ __launch_bounds__(256) void k4_proj(
    const float* __restrict__ ycomb,
    const float* __restrict__ og, const float* __restrict__ ob,
    const float* __restrict__ pg, const float* __restrict__ pb,
    const float* __restrict__ bw, const float* __restrict__ Mg,
    const float* __restrict__ pbias, float* __restrict__ out)
{
    const int tok = blockIdx.x;
    __shared__ float xb[1024];
    __shared__ float red[8];
    const int tid = threadIdx.x;
    const int c0 = tid << 2;
    const float* yrow = ycomb + ((size_t)tok << 10);
    float4 v4 = *reinterpret_cast<const float4*>(yrow + c0);
    float v[4] = {v4.x, v4.y, v4.z, v4.w};
    float s1 = v[0] + v[1] + v[2] + v[3];
    float s2 = v[0]*v[0] + v[1]*v[1] + v[2]*v[2] + v[3]*v[3];
#pragma unroll
    for (int off = 1; off < 64; off <<= 1) {
        s1 += __shfl_xor(s1, off); s2 += __shfl_xor(s2, off);
    }
    if ((tid & 63) == 0) { red[(tid >> 6) * 2] = s1; red[(tid >> 6) * 2 + 1] = s2; }
    __syncthreads();
    s1 = red[0] + red[2] + red[4] + red[6];
    s2 = red[1] + red[3] + red[5] + red[7];
    __syncthreads();
    {
        float mean = s1 * (1.f / 1024.f);
        float var = s2 * (1.f / 1024.f) - mean * mean;
        float rstd = rsqrtf(var + 1e-5f);
#pragma unroll
        for (int q = 0; q < 4; q++)
            v[q] = (v[q] - mean) * rstd * og[c0 + q] + ob[c0 + q];
    }
    s1 = v[0] + v[1] + v[2] + v[3];
    s2 = v[0]*v[0] + v[1]*v[1] + v[2]*v[2] + v[3]*v[3];
#pragma unroll
    for (int off = 1; off < 64; off <<= 1) {
        s1 += __shfl_xor(s1, off); s2 += __shfl_xor(s2, off);
    }
    if ((tid & 63) == 0) { red[(tid >> 6) * 2] = s1; red[(tid >> 6) * 2 + 1] = s2; }
    __syncthreads();
    s1 = red[0] + red[2] + red[4] + red[6];
    s2 = red[1] + red[3] + red[5] + red[7];
    {
        float mean = s1 * (1.f / 1024.f);
        float var = s2 * (1.f / 1024.f) - mean * mean;
        float rstd = rsqrtf(var + 1e-5f);
#pragma unroll
        for (int q = 0; q < 4; q++)
            xb[c0 + q] = (v[q] - mean) * rstd * pg[c0 + q] + pb[c0 + q];
    }
    __syncthreads();
    const int g = tid >> 2;
    const int jb = (tid & 3) << 2;
    float acc[4] = {0.f, 0.f, 0.f, 0.f};
    {
        const float* xg = &xb[g << 4];
        const float* bwg = &bw[(g << 8) + jb];
        for (int i = 0; i < 16; i++) {
            float xv = xg[i];
            float4 wv = *reinterpret_cast<const float4*>(&bwg[i << 4]);
            acc[0] += xv * wv.x; acc[1] += xv * wv.y;
            acc[2] += xv * wv.z; acc[3] += xv * wv.w;
        }
    }
    const int C0 = ((63 - g) << 4) + 12 - jb;
    const int i2 = C0 >> 5, r0 = C0 & 31;
    float z2[4] = {0.f, 0.f, 0.f, 0.f};
    {
        const float* xg = &xb[i2 << 5];
        const float* mg = &Mg[r0];
        for (int j = 0; j < 32; j++) {
            float xv = xg[j];
            float4 mv = *reinterpret_cast<const float4*>(&mg[j << 5]);
            z2[0] += xv * mv.x; z2[1] += xv * mv.y;
            z2[2] += xv * mv.z; z2[3] += xv * mv.w;
        }
    }
    float4 bz = *reinterpret_cast<const float4*>(&pbias[C0]);
    float4 o;
    o.x = acc[3] + z2[0] + bz.x;
    o.y = acc[2] + z2[1] + bz.y;
    o.z = acc[1] + z2[2] + bz.z;
    o.w = acc[0] + z2[3] + bz.w;
    *reinterpret_cast<float4*>(&out[((size_t)tok << 10) + C0]) = o;
}

// ---------------------------------------------------------------------------
extern "C" void kernel_launch(void* const* d_in, const int* in_sizes, int n_in,
                              void* d_out, int out_size, void* d_ws, size_t ws_size,
                              hipStream_t stream) {
    const float* x   = (const float*)d_in[0];
    const float* w   = (const float*)d_in[1];
    const float* wb  = (const float*)d_in[2];
    const float* fg  = (const float*)d_in[3];
    const float* ang = (const float*)d_in[4];
    const float* anb = (const float*)d_in[5];
    const float* ong = (const float*)d_in[6];
    const float* onb = (const float*)d_in[7];
    const float* ppg = (const float*)d_in[8];
    const float* ppb = (const float*)d_in[9];
    const float* pbw = (const float*)d_in[10];
    const float* pwr = (const float*)d_in[11];
    const float* pwc = (const float*)d_in[12];
    const float* pal = (const float*)d_in[13];
    const float* pbi = (const float*)d_in[14];

    uint8_t* p = (uint8_t*)d_ws;
    u16* xbf = (u16*)p;  p += (size_t)2048 * 1024 * 2;
    u16* wbf = (u16*)p;  p += (size_t)3072 * 1024 * 2;
    u16* qb  = (u16*)p;  p += (size_t)32 * 1024 * 64 * 2;
    u16* kb  = (u16*)p;  p += (size_t)32 * 1024 * 64 * 2;
    u16* vb  = (u16*)p;  p += (size_t)32 * 1024 * 64 * 2;
    u16* vtb = (u16*)p;  p += (size_t)32 * 1024 * 64 * 2;
    float* ylin  = (float*)p;  p += (size_t)32 * 1024 * 64 * 4;
    float* ycomb = (float*)p;  p += (size_t)32 * 1024 * 64 * 4;
    float* Sg    = (float*)p;  p += (size_t)32 * 16 * 4096 * 4;
    float* svg   = (float*)p;  p += (size_t)32 * 16 * 64 * 4;
    float* Mg    = (float*)p;  p += (size_t)32 * 32 * 4;
    float* Op    = (float*)p;  p += (size_t)32 * 32 * 4096 * 4;
    float* ml    = (float*)p;  p += (size_t)32 * 32 * 128 * 4;
    float* out   = (float*)d_out;

    k0_prep<<<5121, 256, 0, stream>>>(x, w, pwc, pwr, pal, xbf, wbf, Mg);
    k1_qkv<<<dim3(24, 16), 256, 0, stream>>>(xbf, wbf, wb, qb, kb, vb, vtb);
    k2a_chunkkv<<<dim3(16, 32), 256, 0, stream>>>(kb, vb, Sg, svg);
    k2s_scan<<<521, 256, 0, stream>>>(Sg, svg);
    k2b_lin<<<dim3(16, 32), 256, 0, stream>>>(qb, kb, vb, Sg, svg, ang, anb, ylin);
    k3a_part<<<dim3(32, 32), 256, 0, stream>>>(qb, kb, vtb, Op, ml);
    k3c_comb<<<dim3(16, 32), 256, 0, stream>>>(Op, ml, ylin, fg, ycomb);
    k4_proj<<<2048, 256, 0, stream>>>(ycomb, ong, onb, ppg, ppb, pbw, Mg, pbi, out);
}

// Round 8
// 211.478 us; speedup vs baseline: 2.8180x; 1.0039x over previous
//
#include <hip/hip_runtime.h>
#include <math.h>

constexpr int T_ = 1024;
constexpr int C_ = 1024;
constexpr int H_ = 16;
constexpr int D_ = 64;
#define SCALE 0.125f

typedef unsigned short u16;
typedef __attribute__((ext_vector_type(8))) short short8;
typedef __attribute__((ext_vector_type(4))) float f32x4;

__device__ __forceinline__ float elu1(float x) { return x > 0.f ? x + 1.f : expf(x); }

__device__ __forceinline__ u16 f2bf(float f) {
    union { float f; unsigned u; } c; c.f = f;
    unsigned r = (c.u + 0x7fffu + ((c.u >> 16) & 1u)) >> 16;
    return (u16)r;
}
__device__ __forceinline__ float bf2f(u16 u) {
    union { unsigned u; float f; } c; c.u = (unsigned)u << 16;
    return c.f;
}

#define GLL16(g, l)                                                            \
    __builtin_amdgcn_global_load_lds(                                          \
        (const __attribute__((address_space(1))) void*)(g),                    \
        (__attribute__((address_space(3))) void*)(l), 16, 0, 0)

// ---------------------------------------------------------------------------
// K0_prep: fused x-cast (blocks [0,2048)), W-cast ([2048,5120)), and
// Mg = alpha * wcol @ wrow^T (block 5120).
// ---------------------------------------------------------------------------
__global__ __launch_bounds__(256) void k0_prep(
    const float* __restrict__ x, const float* __restrict__ w,
    const float* __restrict__ wcol, const float* __restrict__ wrow,
    const float* __restrict__ palpha,
    u16* __restrict__ xbf, u16* __restrict__ wbf, float* __restrict__ Mg)
{
    const int b = blockIdx.x;
    const int tid = threadIdx.x;
    if (b < 2048) {
        int i = b * 256 + tid;
        float4 v = reinterpret_cast<const float4*>(x)[i];
        ushort4 o;
        o.x = f2bf(v.x); o.y = f2bf(v.y); o.z = f2bf(v.z); o.w = f2bf(v.w);
        reinterpret_cast<ushort4*>(xbf)[i] = o;
    } else if (b < 5120) {
        int i = (b - 2048) * 256 + tid;
        float4 v = reinterpret_cast<const float4*>(w)[i];
        ushort4 o;
        o.x = f2bf(v.x); o.y = f2bf(v.y); o.z = f2bf(v.z); o.w = f2bf(v.w);
        reinterpret_cast<ushort4*>(wbf)[i] = o;
    } else {
        const int j = tid >> 3, r0 = (tid & 7) << 2;
        const float al = palpha[0];
        float acc[4] = {0.f, 0.f, 0.f, 0.f};
        for (int c = 0; c < 32; c++) {
            float wc = wcol[(j << 5) + c];
#pragma unroll
            for (int q = 0; q < 4; q++) acc[q] += wc * wrow[((r0 + q) << 5) + c];
        }
        float4 o = {al * acc[0], al * acc[1], al * acc[2], al * acc[3]};
        *reinterpret_cast<float4*>(&Mg[(j << 5) + r0]) = o;
    }
}

// ---------------------------------------------------------------------------
// K1: bf16 MFMA GEMM  qkv = x @ W^T + b  (M=2048,N=3072,K=1024).
// v-blocks also emit the transposed copy vtb[bh][d][t] (packed uint2).
// ---------------------------------------------------------------------------
__global__ __launch_bounds__(256) void k1_qkv(
    const u16* __restrict__ xbf, const u16* __restrict__ wbf,
    const float* __restrict__ bias,
    u16* __restrict__ qb, u16* __restrict__ kb, u16* __restrict__ vb,
    u16* __restrict__ vtb)
{
    __shared__ __align__(16) u16 As[128 * 32];
    __shared__ __align__(16) u16 Bs[128 * 32];
    const int tid = threadIdx.x;
    const int wave = tid >> 6, lane = tid & 63;
    const int quad = lane >> 4, l15 = lane & 15;
    const int m0 = blockIdx.y << 7, n0 = blockIdx.x << 7;
    const int wm = (wave >> 1) << 6, wn = (wave & 1) << 6;

    const int rowS = (wave << 5) + (lane >> 2);
    const int seg8 = (lane & 3) << 3;
    const u16* gA1 = xbf + (size_t)(m0 + rowS) * 1024 + seg8;
    const u16* gA2 = gA1 + (size_t)16 * 1024;
    const u16* gB1 = wbf + (size_t)(n0 + rowS) * 1024 + seg8;
    const u16* gB2 = gB1 + (size_t)16 * 1024;
    u16* lA1 = &As[(wave << 5) * 32];
    u16* lA2 = lA1 + 16 * 32;
    u16* lB1 = &Bs[(wave << 5) * 32];
    u16* lB2 = lB1 + 16 * 32;

    f32x4 zero4 = {0.f, 0.f, 0.f, 0.f};
    f32x4 acc[4][4];
#pragma unroll
    for (int i = 0; i < 4; i++)
#pragma unroll
        for (int j = 0; j < 4; j++) acc[i][j] = zero4;

    for (int k0 = 0; k0 < 1024; k0 += 32) {
        GLL16(gA1 + k0, lA1);
        GLL16(gA2 + k0, lA2);
        GLL16(gB1 + k0, lB1);
        GLL16(gB2 + k0, lB2);
        __syncthreads();
        short8 a[4], b[4];
#pragma unroll
        for (int mi = 0; mi < 4; mi++)
            a[mi] = *(const short8*)&As[(wm + mi * 16 + l15) * 32 + (quad << 3)];
#pragma unroll
        for (int ni = 0; ni < 4; ni++)
            b[ni] = *(const short8*)&Bs[(wn + ni * 16 + l15) * 32 + (quad << 3)];
#pragma unroll
        for (int mi = 0; mi < 4; mi++)
#pragma unroll
            for (int ni = 0; ni < 4; ni++)
                acc[mi][ni] = __builtin_amdgcn_mfma_f32_16x16x32_bf16(
                    a[mi], b[ni], acc[mi][ni], 0, 0, 0);
        __syncthreads();
    }
#pragma unroll
    for (int ni = 0; ni < 4; ni++) {
        int n_g = n0 + wn + ni * 16 + l15;
        int which = n_g >> 10;
        int h = (n_g >> 6) & 15;
        int d = n_g & 63;
        u16* dst = (which == 0) ? qb : (which == 1) ? kb : vb;
        float bz = bias[n_g];
#pragma unroll
        for (int mi = 0; mi < 4; mi++) {
            int m_base = m0 + wm + mi * 16 + (quad << 2);
            int bi = m_base >> 10, t_base = m_base & 1023;
            u16 o4[4];
#pragma unroll
            for (int reg = 0; reg < 4; reg++) {
                o4[reg] = f2bf(acc[mi][ni][reg] + bz);
                dst[((size_t)(bi * 16 + h) << 16) + ((size_t)(t_base + reg) << 6)
                    + d] = o4[reg];
            }
            if (which == 2) {
                *(uint2*)&vtb[(((size_t)((bi * 16 + h) << 6) + d) << 10) +
                              t_base] = *(uint2*)o4;
            }
        }
    }
}

// ---------------------------------------------------------------------------
// K23: merged k2a (chunk KV states) + k3a (split-K flash partials).
// blockIdx.x < 32: k3a job = 31 - blockIdx.x (longest first);
// blockIdx.x >= 32: k2a chunk = blockIdx.x - 32.  Shared-LDS union (36.9 KB).
// ---------------------------------------------------------------------------
__global__ __launch_bounds__(256) void k23(
    const u16* __restrict__ qbp, const u16* __restrict__ kbp,
    const u16* __restrict__ vbp, const u16* __restrict__ vtb,
    float* __restrict__ Sg, float* __restrict__ svg,
    float* __restrict__ Op, float* __restrict__ ml)
{
    __shared__ __align__(16) u16 smem[4 * 64 * 72];  // 36864 B
    const int bh = blockIdx.y;
    const int tid = threadIdx.x;

    if (blockIdx.x < 32) {
        // ----- k3a: flash attention partial -----
        const int job = 31 - (int)blockIdx.x;
        const int qi = job >> 1, half = job & 1;
        const int n = qi + 1;
        const int csplit = n >> 1;
        const int kbeg = half ? csplit : 0;
        const int kend = half ? n : csplit;
        u16 (*Qs)[72] = (u16(*)[72])smem;
        u16 (*Ks)[72] = (u16(*)[72])(smem + 4608);
        u16 (*Vt)[72] = (u16(*)[72])(smem + 9216);
        u16 (*Pa)[72] = (u16(*)[72])(smem + 13824);
        const int wave = tid >> 6, lane = tid & 63;
        const int quad = lane >> 4, l15 = lane & 15;
        const f32x4 zero4 = {0.f, 0.f, 0.f, 0.f};

#pragma unroll
        for (int u = 0; u < 2; u++) {
            int idx = (tid + (u << 8)) << 3;
            int r = idx >> 6, c = idx & 63;
            *(uint4*)&Qs[r][c] = *(const uint4*)
                &qbp[((size_t)bh << 16) + ((size_t)((qi << 6) + r) << 6) + c];
        }
        __syncthreads();
        short8 bq[2];
        bq[0] = *(const short8*)&Qs[(wave << 4) + l15][(quad << 3)];
        bq[1] = *(const short8*)&Qs[(wave << 4) + l15][32 + (quad << 3)];
        f32x4 O[4];
#pragma unroll
        for (int dt = 0; dt < 4; dt++) O[dt] = zero4;
        float m_run = -INFINITY, l_run = 0.f;
        const int r_g = (qi << 6) + (wave << 4) + l15;

        for (int ki = kbeg; ki < kend; ki++) {
            __syncthreads();
#pragma unroll
            for (int u = 0; u < 2; u++) {
                int idx = (tid + (u << 8)) << 3;
                int r = idx >> 6, c = idx & 63;
                *(uint4*)&Ks[r][c] = *(const uint4*)
                    &kbp[((size_t)bh << 16) + ((size_t)((ki << 6) + r) << 6) + c];
                *(uint4*)&Vt[r][c] = *(const uint4*)
                    &vtb[((size_t)((bh << 6) + r) << 10) + (ki << 6) + c];
            }
            __syncthreads();
            f32x4 st[4];
#pragma unroll
            for (int ct = 0; ct < 4; ct++) st[ct] = zero4;
#pragma unroll
            for (int ks = 0; ks < 2; ks++) {
#pragma unroll
                for (int ct = 0; ct < 4; ct++) {
                    short8 a = *(const short8*)
                        &Ks[(ct << 4) + l15][(ks << 5) + (quad << 3)];
                    st[ct] = __builtin_amdgcn_mfma_f32_16x16x32_bf16(
                        a, bq[ks], st[ct], 0, 0, 0);
                }
            }
            float mloc = -INFINITY;
#pragma unroll
            for (int ct = 0; ct < 4; ct++)
#pragma unroll
                for (int reg = 0; reg < 4; reg++) {
                    int c_g = (ki << 6) + (ct << 4) + (quad << 2) + reg;
                    float s = st[ct][reg] * SCALE;
                    if (c_g > r_g) s = -INFINITY;
                    st[ct][reg] = s;
                    mloc = fmaxf(mloc, s);
                }
            mloc = fmaxf(mloc, __shfl_xor(mloc, 16));
            mloc = fmaxf(mloc, __shfl_xor(mloc, 32));
            float mnew = fmaxf(m_run, mloc);
            float corr = __expf(m_run - mnew);
            m_run = mnew;
            float rsum = 0.f;
#pragma unroll
            for (int ct = 0; ct < 4; ct++) {
                u16 pk[4];
#pragma unroll
                for (int reg = 0; reg < 4; reg++) {
                    float pv = __expf(st[ct][reg] - mnew);
                    rsum += pv;
                    pk[reg] = f2bf(pv);
                }
                unsigned lo = (unsigned)pk[0] | ((unsigned)pk[1] << 16);
                unsigned hi = (unsigned)pk[2] | ((unsigned)pk[3] << 16);
                uint2 pkv; pkv.x = lo; pkv.y = hi;
                *(uint2*)&Pa[(wave << 4) + l15][(ct << 4) + (quad << 2)] = pkv;
            }
            rsum += __shfl_xor(rsum, 16);
            rsum += __shfl_xor(rsum, 32);
            l_run = l_run * corr + rsum;
            float co[4];
#pragma unroll
            for (int reg = 0; reg < 4; reg++)
                co[reg] = __shfl(corr, ((lane >> 4) << 2) + reg);
#pragma unroll
            for (int dt = 0; dt < 4; dt++)
#pragma unroll
                for (int reg = 0; reg < 4; reg++) O[dt][reg] *= co[reg];
#pragma unroll
            for (int ks = 0; ks < 2; ks++) {
                short8 ap = *(const short8*)
                    &Pa[(wave << 4) + l15][(ks << 5) + (quad << 3)];
#pragma unroll
                for (int dt = 0; dt < 4; dt++) {
                    short8 bv = *(const short8*)
                        &Vt[(dt << 4) + l15][(ks << 5) + (quad << 3)];
                    O[dt] = __builtin_amdgcn_mfma_f32_16x16x32_bf16(
                        ap, bv, O[dt], 0, 0, 0);
                }
            }
        }
        float* ob = Op + (((size_t)bh * 32 + job) << 12);
#pragma unroll
        for (int dt = 0; dt < 4; dt++)
#pragma unroll
            for (int reg = 0; reg < 4; reg++) {
                int r = (wave << 4) + (quad << 2) + reg;
                int d = (dt << 4) + l15;
                ob[(r << 6) + d] = O[dt][reg];
            }
        if (quad == 0) {
            int r = (wave << 4) + l15;
            float* mlb = ml + (((size_t)bh * 32 + job) << 7);
            mlb[r] = m_run;
            mlb[64 + r] = l_run;
        }
    } else {
        // ----- k2a: chunk KV state (fp32 VALU) -----
        const int chunk = (int)blockIdx.x - 32;
        const int t0 = chunk << 6;
        float* Ksf = (float*)smem;            // [64][65]
        float* Vsf = Ksf + 64 * 65;           // [64][65]
        const u16* kp = kbp + (size_t)bh * T_ * D_;
        const u16* vp = vbp + (size_t)bh * T_ * D_;
#pragma unroll
        for (int ii = 0; ii < 16; ii++) {
            int idx = tid + (ii << 8);
            int row = idx >> 6, col = idx & 63;
            Ksf[row * 65 + col] =
                elu1(bf2f(kp[(size_t)(t0 + row) * D_ + col]) * SCALE);
            Vsf[row * 65 + col] = bf2f(vp[(size_t)(t0 + row) * D_ + col]);
        }
        __syncthreads();
        const int tr = tid >> 4, tc = tid & 15;
        const int d0 = tr * 4, e0 = tc * 4;
        float acc[4][4] = {};
        for (int c = 0; c < 64; c++) {
            float a[4], b[4];
#pragma unroll
            for (int i = 0; i < 4; i++) a[i] = Ksf[c * 65 + d0 + i];
#pragma unroll
            for (int j = 0; j < 4; j++) b[j] = Vsf[c * 65 + e0 + j];
#pragma unroll
            for (int i = 0; i < 4; i++)
#pragma unroll
                for (int j = 0; j < 4; j++) acc[i][j] += a[i] * b[j];
        }
        float* so = Sg + ((size_t)bh * 16 + chunk) * 4096;
#pragma unroll
        for (int i = 0; i < 4; i++) {
            float4 o = {acc[i][0], acc[i][1], acc[i][2], acc[i][3]};
            *reinterpret_cast<float4*>(&so[(d0 + i) * 64 + e0]) = o;
        }
        if (tc == 0) {
#pragma unroll
            for (int i = 0; i < 4; i++) {
                float s = 0.f;
                for (int c = 0; c < 64; c++) s += Ksf[c * 65 + d0 + i];
                svg[((size_t)bh * 16 + chunk) * 64 + d0 + i] = s;
            }
        }
    }
}

// ---------------------------------------------------------------------------
// K2s: in-place exclusive prefix scan over the chunk dim of Sg (and svg).
// ---------------------------------------------------------------------------
__global__ __launch_bounds__(256) void k2s_scan(
    float* __restrict__ Sg, float* __restrict__ svg)
{
    int gid = blockIdx.x * 256 + threadIdx.x;
    if (gid < 131072) {
        int bh = gid >> 12, e = gid & 4095;
        float* base = Sg + ((size_t)bh << 16) + e;
        float v[16];
#pragma unroll
        for (int c = 0; c < 16; c++) v[c] = base[(size_t)c << 12];
        float run = 0.f;
#pragma unroll
        for (int c = 0; c < 16; c++) {
            base[(size_t)c << 12] = run;
            run += v[c];
        }
    } else if (gid < 131072 + 2048) {
        int g2 = gid - 131072;
        int bh = g2 >> 6, d = g2 & 63;
        float* base = svg + ((size_t)bh << 10) + d;
        float v[16];
#pragma unroll
        for (int c = 0; c < 16; c++) v[c] = base[c << 6];
        float run = 0.f;
#pragma unroll
        for (int c = 0; c < 16; c++) {
            base[c << 6] = run;
            run += v[c];
        }
    }
}

// ---------------------------------------------------------------------------
// K2b: linear attention per chunk (fp32 VALU); prefix state float4 load.
// ---------------------------------------------------------------------------
__global__ __launch_bounds__(256) void k2b_lin(
    const u16* __restrict__ qbp, const u16* __restrict__ kbp,
    const u16* __restrict__ vbp,
    const float* __restrict__ Sg, const float* __restrict__ svg,
    const float* __restrict__ ang, const float* __restrict__ anb,
    float* __restrict__ ylin)
{
    const int chunk = blockIdx.x, bh = blockIdx.y;
    const int t0 = chunk << 6;
    __shared__ __align__(16) float bufA[64][68];
    __shared__ float bufQ[64][65];
    __shared__ float bufK[64][65];
    __shared__ float svec[64];
    const int tid = threadIdx.x;
    const u16* qp = qbp + (size_t)bh * T_ * D_;
    const u16* kp = kbp + (size_t)bh * T_ * D_;
    const u16* vp = vbp + (size_t)bh * T_ * D_;
    const float* sp = Sg + (((size_t)bh * 16 + chunk) << 12);
#pragma unroll
    for (int u = 0; u < 4; u++) {
        int idx = (tid + (u << 8)) << 2;
        int dd = idx >> 6, e = idx & 63;
        *(float4*)&bufA[dd][e] = *(const float4*)&sp[idx];
    }
    if (tid < 64) svec[tid] = svg[(((size_t)bh * 16 + chunk) << 6) + tid];
#pragma unroll
    for (int ii = 0; ii < 16; ii++) {
        int idx = tid + (ii << 8);
        int row = idx >> 6, col = idx & 63;
        bufQ[col][row] = elu1(bf2f(qp[(size_t)(t0 + row) * D_ + col]) * SCALE);
    }
    __syncthreads();
    const int tr = tid >> 4, tc = tid & 15;
    const int r0 = tr * 4, c0 = tc * 4;
    float N[4][4] = {};
    float pden[4];
    for (int dd = 0; dd < 64; dd++) {
        float a[4], b[4];
#pragma unroll
        for (int i = 0; i < 4; i++) a[i] = bufQ[dd][r0 + i];
#pragma unroll
        for (int j = 0; j < 4; j++) b[j] = bufA[dd][c0 + j];
#pragma unroll
        for (int i = 0; i < 4; i++)
#pragma unroll
            for (int j = 0; j < 4; j++) N[i][j] += a[i] * b[j];
    }
#pragma unroll
    for (int i = 0; i < 4; i++) {
        float s = 0.f;
#pragma unroll
        for (int j = 0; j < 4; j++) s += bufQ[c0 + j][r0 + i] * svec[c0 + j];
        pden[i] = s;
    }
    __syncthreads();
#pragma unroll
    for (int ii = 0; ii < 16; ii++) {
        int idx = tid + (ii << 8);
        int row = idx >> 6, col = idx & 63;
        bufK[col][row] = elu1(bf2f(kp[(size_t)(t0 + row) * D_ + col]) * SCALE);
        bufA[row][col] = bf2f(vp[(size_t)(t0 + row) * D_ + col]);
    }
    __syncthreads();
    float sc[4][4] = {};
    for (int dd = 0; dd < 64; dd++) {
        float a[4], b[4];
#pragma unroll
        for (int i = 0; i < 4; i++) a[i] = bufQ[dd][r0 + i];
#pragma unroll
        for (int j = 0; j < 4; j++) b[j] = bufK[dd][c0 + j];
#pragma unroll
        for (int i = 0; i < 4; i++)
#pragma unroll
            for (int j = 0; j < 4; j++) sc[i][j] += a[i] * b[j];
    }
    __syncthreads();
#pragma unroll
    for (int i = 0; i < 4; i++) {
        float s = 0.f;
#pragma unroll
        for (int j = 0; j < 4; j++) {
            float pv = ((c0 + j) <= (r0 + i)) ? sc[i][j] : 0.f;
            bufQ[c0 + j][r0 + i] = pv;
            s += pv;
        }
        pden[i] += s;
    }
#pragma unroll
    for (int i = 0; i < 4; i++) {
#pragma unroll
        for (int off = 1; off < 16; off <<= 1)
            pden[i] += __shfl_xor(pden[i], off);
    }
    __syncthreads();
    for (int c = 0; c < 64; c++) {
        float a[4], b[4];
#pragma unroll
        for (int i = 0; i < 4; i++) a[i] = bufQ[c][r0 + i];
#pragma unroll
        for (int j = 0; j < 4; j++) b[j] = bufA[c][c0 + j];
#pragma unroll
        for (int i = 0; i < 4; i++)
#pragma unroll
            for (int j = 0; j < 4; j++) N[i][j] += a[i] * b[j];
    }
    float yv[4][4], s1[4], s2[4];
#pragma unroll
    for (int i = 0; i < 4; i++) {
        float inv = 1.f / (pden[i] + 1e-4f);
        s1[i] = 0.f; s2[i] = 0.f;
#pragma unroll
        for (int j = 0; j < 4; j++) {
            float t = N[i][j] * inv;
            yv[i][j] = t; s1[i] += t; s2[i] += t * t;
        }
    }
#pragma unroll
    for (int i = 0; i < 4; i++) {
#pragma unroll
        for (int off = 1; off < 16; off <<= 1) {
            s1[i] += __shfl_xor(s1[i], off);
            s2[i] += __shfl_xor(s2[i], off);
        }
    }
#pragma unroll
    for (int i = 0; i < 4; i++) {
        float mean = s1[i] * (1.f / 64.f);
        float var = s2[i] * (1.f / 64.f) - mean * mean;
        float rstd = rsqrtf(var + 1e-5f);
        float4 o;
        o.x = (yv[i][0] - mean) * rstd * ang[c0 + 0] + anb[c0 + 0];
        o.y = (yv[i][1] - mean) * rstd * ang[c0 + 1] + anb[c0 + 1];
        o.z = (yv[i][2] - mean) * rstd * ang[c0 + 2] + anb[c0 + 2];
        o.w = (yv[i][3] - mean) * rstd * ang[c0 + 3] + anb[c0 + 3];
        *reinterpret_cast<float4*>(
            &ylin[((size_t)bh * T_ + t0 + r0 + i) * D_ + c0]) = o;
    }
}

// ---------------------------------------------------------------------------
// K4: fused split-K combine + alpha-blend + out-LN + pre-LN + block-diag mix
// (reversed) + folded bilinear + bias.  One block per token.
// ---------------------------------------------------------------------------
__global__ __launch_bounds__(256) void k4_proj(
    const float* __restrict__ Op, const float* __restrict__ ml,
    const float* __restrict__ ylin, const float* __restrict__ fg,
    const float* __restrict__ og, const float* __restrict__ ob,
    const float* __restrict__ pg, const float* __restrict__ pb,
    const float* __restrict__ bw, const float* __restrict__ Mg,
    const float* __restrict__ pbias, float* __restrict__ out)
{
    const int tok = blockIdx.x;
    const int bi = tok >> 10, t = tok & 1023;
    const int qi = t >> 6, r = t & 63;
    __shared__ float ybuf[1024];
    __shared__ float xb[1024];
    __shared__ float red[8];
    const int tid = threadIdx.x;
    // --- combine partials for this token's 16 heads ---
    {
        const float al = 1.f / (1.f + __expf(-fg[0]));
        const int h = tid >> 4;
        const int d4 = (tid & 15) << 2;
        const int bh = (bi << 4) + h;
        const size_t b0 = (((size_t)bh * 32 + (qi << 1)) << 7);
        float m0 = ml[b0 + r], l0 = ml[b0 + 64 + r];
        float m1 = ml[b0 + 128 + r], l1 = ml[b0 + 192 + r];
        float m = fmaxf(m0, m1);
        float w0 = (m0 == -INFINITY) ? 0.f : __expf(m0 - m);
        float w1 = __expf(m1 - m);
        float inv = al / (l0 * w0 + l1 * w1);
        const float* o0 = Op + (((size_t)bh * 32 + (qi << 1)) << 12) + (r << 6);
        const float* o1 = o0 + 4096;
        float4 a = *(const float4*)&o0[d4];
        float4 b = *(const float4*)&o1[d4];
        float4 yl = *(const float4*)
            &ylin[((((size_t)bh << 10) + t) << 6) + d4];
        float4 o;
        o.x = (a.x * w0 + b.x * w1) * inv + (1.f - al) * yl.x;
        o.y = (a.y * w0 + b.y * w1) * inv + (1.f - al) * yl.y;
        o.z = (a.z * w0 + b.z * w1) * inv + (1.f - al) * yl.z;
        o.w = (a.w * w0 + b.w * w1) * inv + (1.f - al) * yl.w;
        *(float4*)&ybuf[(h << 6) + d4] = o;
    }
    __syncthreads();
    const int c0 = tid << 2;
    float4 v4 = *reinterpret_cast<const float4*>(&ybuf[c0]);
    float v[4] = {v4.x, v4.y, v4.z, v4.w};
    float s1 = v[0] + v[1] + v[2] + v[3];
    float s2 = v[0]*v[0] + v[1]*v[1] + v[2]*v[2] + v[3]*v[3];
#pragma unroll
    for (int off = 1; off < 64; off <<= 1) {
        s1 += __shfl_xor(s1, off); s2 += __shfl_xor(s2, off);
    }
    if ((tid & 63) == 0) { red[(tid >> 6) * 2] = s1; red[(tid >> 6) * 2 + 1] = s2; }
    __syncthreads();
    s1 = red[0] + red[2] + red[4] + red[6];
    s2 = red[1] + red[3] + red[5] + red[7];
    __syncthreads();
    {
        float mean = s1 * (1.f / 1024.f);
        float var = s2 * (1.f / 1024.f) - mean * mean;
        float rstd = rsqrtf(var + 1e-5f);
#pragma unroll
        for (int q = 0; q < 4; q++)
            v[q] = (v[q] - mean) * rstd * og[c0 + q] + ob[c0 + q];
    }
    s1 = v[0] + v[1] + v[2] + v[3];
    s2 = v[0]*v[0] + v[1]*v[1] + v[2]*v[2] + v[3]*v[3];
#pragma unroll
    for (int off = 1; off < 64; off <<= 1) {
        s1 += __shfl_xor(s1, off); s2 += __shfl_xor(s2, off);
    }
    if ((tid & 63) == 0) { red[(tid >> 6) * 2] = s1; red[(tid >> 6) * 2 + 1] = s2; }
    __syncthreads();
    s1 = red[0] + red[2] + red[4] + red[6];
    s2 = red[1] + red[3] + red[5] + red[7];
    {
        float mean = s1 * (1.f / 1024.f);
        float var = s2 * (1.f / 1024.f) - mean * mean;
        float rstd = rsqrtf(var + 1e-5f);
#pragma unroll
        for (int q = 0; q < 4; q++)
            xb[c0 + q] = (v[q] - mean) * rstd * pg[c0 + q] + pb[c0 + q];
    }
    __syncthreads();
    const int g = tid >> 2;
    const int jb = (tid & 3) << 2;
    float acc[4] = {0.f, 0.f, 0.f, 0.f};
    {
        const float* xg = &xb[g << 4];
        const float* bwg = &bw[(g << 8) + jb];
        for (int i = 0; i < 16; i++) {
            float xv = xg[i];
            float4 wv = *reinterpret_cast<const float4*>(&bwg[i << 4]);
            acc[0] += xv * wv.x; acc[1] += xv * wv.y;
            acc[2] += xv * wv.z; acc[3] += xv * wv.w;
        }
    }
    const int C0 = ((63 - g) << 4) + 12 - jb;
    const int i2 = C0 >> 5, r0 = C0 & 31;
    float z2[4] = {0.f, 0.f, 0.f, 0.f};
    {
        const float* xg = &xb[i2 << 5];
        const float* mg = &Mg[r0];
        for (int j = 0; j < 32; j++) {
            float xv = xg[j];
            float4 mv = *reinterpret_cast<const float4*>(&mg[j << 5]);
            z2[0] += xv * mv.x; z2[1] += xv * mv.y;
            z2[2] += xv * mv.z; z2[3] += xv * mv.w;
        }
    }
    float4 bz = *reinterpret_cast<const float4*>(&pbias[C0]);
    float4 o;
    o.x = acc[3] + z2[0] + bz.x;
    o.y = acc[2] + z2[1] + bz.y;
    o.z = acc[1] + z2[2] + bz.z;
    o.w = acc[0] + z2[3] + bz.w;
    *reinterpret_cast<float4*>(&out[((size_t)tok << 10) + C0]) = o;
}

// ---------------------------------------------------------------------------
extern "C" void kernel_launch(void* const* d_in, const int* in_sizes, int n_in,
                              void* d_out, int out_size, void* d_ws, size_t ws_size,
                              hipStream_t stream) {
    const float* x   = (const float*)d_in[0];
    const float* w   = (const float*)d_in[1];
    const float* wb  = (const float*)d_in[2];
    const float* fg  = (const float*)d_in[3];
    const float* ang = (const float*)d_in[4];
    const float* anb = (const float*)d_in[5];
    const float* ong = (const float*)d_in[6];
    const float* onb = (const float*)d_in[7];
    const float* ppg = (const float*)d_in[8];
    const float* ppb = (const float*)d_in[9];
    const float* pbw = (const float*)d_in[10];
    const float* pwr = (const float*)d_in[11];
    const float* pwc = (const float*)d_in[12];
    const float* pal = (const float*)d_in[13];
    const float* pbi = (const float*)d_in[14];

    uint8_t* p = (uint8_t*)d_ws;
    u16* xbf = (u16*)p;  p += (size_t)2048 * 1024 * 2;
    u16* wbf = (u16*)p;  p += (size_t)3072 * 1024 * 2;
    u16* qb  = (u16*)p;  p += (size_t)32 * 1024 * 64 * 2;
    u16* kb  = (u16*)p;  p += (size_t)32 * 1024 * 64 * 2;
    u16* vb  = (u16*)p;  p += (size_t)32 * 1024 * 64 * 2;
    u16* vtb = (u16*)p;  p += (size_t)32 * 1024 * 64 * 2;
    float* ylin  = (float*)p;  p += (size_t)32 * 1024 * 64 * 4;
    float* Sg    = (float*)p;  p += (size_t)32 * 16 * 4096 * 4;
    float* svg   = (float*)p;  p += (size_t)32 * 16 * 64 * 4;
    float* Mg    = (float*)p;  p += (size_t)32 * 32 * 4;
    float* Op    = (float*)p;  p += (size_t)32 * 32 * 4096 * 4;
    float* ml    = (float*)p;  p += (size_t)32 * 32 * 128 * 4;
    float* out   = (float*)d_out;

    k0_prep<<<5121, 256, 0, stream>>>(x, w, pwc, pwr, pal, xbf, wbf, Mg);
    k1_qkv<<<dim3(24, 16), 256, 0, stream>>>(xbf, wbf, wb, qb, kb, vb, vtb);
    k23<<<dim3(48, 32), 256, 0, stream>>>(qb, kb, vb, vtb, Sg, svg, Op, ml);
    k2s_scan<<<521, 256, 0, stream>>>(Sg, svg);
    k2b_lin<<<dim3(16, 32), 256, 0, stream>>>(qb, kb, vb, Sg, svg, ang, anb, ylin);
    k4_proj<<<2048, 256, 0, stream>>>(Op, ml, ylin, fg, ong, onb, ppg, ppb,
                                      pbw, Mg, pbi, out);
}